// Round 8
// baseline (835.526 us; speedup 1.0000x reference)
//
#include <hip/hip_runtime.h>
#include <cmath>
#include <cstddef>

#define FGK_NN   20000
#define FGK_NE   320000
#define FGK_H    128
#define FGK_P    16
#define FGK_TRI  136
#define FGK_F    152
#define FGK_EPB  32
#define FGK_YP   156          // sY row stride (>=152, 16B-aligned rows, 28 mod 32)

typedef short  s16x8 __attribute__((ext_vector_type(8)));
typedef float  f32x4 __attribute__((ext_vector_type(4)));

__device__ __forceinline__ unsigned short fgk_f2b(float f) {   // RNE f32->bf16 (native cvt)
    __bf16 b = (__bf16)f;
    return __builtin_bit_cast(unsigned short, b);
}
__device__ __forceinline__ float fgk_u2f(unsigned short u) {
    return __uint_as_float(((unsigned int)u) << 16);
}
// bank-conflict swizzles on 16B-unit index (bijective XOR of high bits into group bits)
__device__ __forceinline__ int fgk_sw(int u)  { return u ^ ((u >> 4) & 7); }  // node-kernel pattern
__device__ __forceinline__ int fgk_swL(int u) { return u ^ ((u >> 5) & 7); }  // edge-kernel pattern

__global__ void FishnetGCN_62096637165586_kernel() {}

__global__ void fgkZero(float* acc) {
    int i = blockIdx.x * blockDim.x + threadIdx.x;
    if (i < FGK_NN * (FGK_P + FGK_TRI)) acc[i] = 0.f;
}
__global__ void fgkZeroI(int* p, int n) {
    int i = blockIdx.x * blockDim.x + threadIdx.x;
    if (i < n) p[i] = 0;
}
// ---- dst-sort: histogram -> block scan -> scatter (edge_index constant) ----
__global__ void fgkHist(const int* __restrict__ dst, int* __restrict__ hist) {
    int e = blockIdx.x * blockDim.x + threadIdx.x;
    if (e < FGK_NE) atomicAdd(&hist[dst[e]], 1);
}
__global__ void fgkScan(const int* __restrict__ hist, int* __restrict__ cursor)
{
    __shared__ int sWave[16];
    __shared__ int sRun;
    int t = threadIdx.x;             // 1024
    int lane = t & 63, wv = t >> 6;
    if (t == 0) sRun = 0;
    __syncthreads();
    for (int base = 0; base < FGK_NN; base += 1024) {
        int idx = base + t;
        int v = (idx < FGK_NN) ? hist[idx] : 0;
        int sc = v;
#pragma unroll
        for (int off = 1; off < 64; off <<= 1) {
            int u = __shfl_up(sc, off);
            if (lane >= off) sc += u;
        }
        if (lane == 63) sWave[wv] = sc;
        __syncthreads();
        if (wv == 0 && lane < 16) {
            int w = sWave[lane];
#pragma unroll
            for (int off = 1; off < 16; off <<= 1) {
                int u = __shfl_up(w, off, 16);
                if (lane >= off) w += u;
            }
            sWave[lane] = w;
        }
        __syncthreads();
        int waveOff = (wv == 0) ? 0 : sWave[wv - 1];
        int run = sRun;
        if (idx < FGK_NN) cursor[idx] = run + waveOff + sc - v;   // exclusive
        __syncthreads();
        if (t == 1023) sRun = run + sWave[15];
        __syncthreads();
    }
}
__global__ void fgkScatterE(const int* __restrict__ dst, int* __restrict__ cursor,
                            int* __restrict__ perm) {
    int e = blockIdx.x * blockDim.x + threadIdx.x;
    if (e < FGK_NE) {
        int pos = atomicAdd(&cursor[dst[e]], 1);
        perm[pos] = e;
    }
}

// Generic prepack of W[K,N] (row-major) into MFMA B-fragment order, bf16 hi/lo.
__global__ void fgkPrepW(const float* __restrict__ W, int K, int N,
                         unsigned short* __restrict__ hi,
                         unsigned short* __restrict__ lo)
{
    int chunks = K >> 5;
    int b = blockIdx.x;
    int nt = b / chunks, c = b - nt * chunks;
    int lane = threadIdx.x;
    int n = nt * 16 + (lane & 15);
    int g = lane >> 4;
    size_t base = ((size_t)b * 64 + lane) * 8;
#pragma unroll
    for (int j = 0; j < 8; ++j) {
        int k = c * 32 + g * 8 + j;
        float v = (n < N) ? W[(size_t)k * N + n] : 0.f;
        unsigned short hb = fgk_f2b(v);
        unsigned short lb = fgk_f2b(v - fgk_u2f(hb));
        hi[base + j] = hb;
        lo[base + j] = lb;
    }
}

// hin = x @ W[8,128] + b   (f32 + bf16 gather copy)
__global__ void fgkEnc(const float* __restrict__ xin,
                       const float* __restrict__ wenc,
                       const float* __restrict__ benc,
                       float* __restrict__ hin,
                       unsigned short* __restrict__ hinB)
{
    int idx = blockIdx.x * blockDim.x + threadIdx.x;
    if (idx >= FGK_NN * FGK_H) return;
    int n = idx >> 7, j = idx & 127;
    float acc = benc[j];
    const float* xp = xin + (size_t)n * 8;
#pragma unroll
    for (int k = 0; k < 8; k++) acc += xp[k] * wenc[k * FGK_H + j];
    hin[idx] = acc;
    hinB[idx] = fgk_f2b(acc);
}

// edge (sorted by dst), 32 edges/block, 512 threads, 128-VGPR budget:
// bf16 hin gather -> msg -> A-frags ; y=MFMA ; L->frags ; Fe=MFMA ;
// per-slot LDS reduction ; ~152 atomics per distinct dst
__global__ void __launch_bounds__(512, 4)
fgkEdge(const float* __restrict__ eatt,
        const int* __restrict__ srcIdx,
        const int* __restrict__ dstIdx,
        const int* __restrict__ perm,
        const float* __restrict__ eew,
        const float* __restrict__ eeb,
        const unsigned short* __restrict__ bHi,
        const unsigned short* __restrict__ bLo,
        const float* __restrict__ a1b,
        const unsigned short* __restrict__ hinB,
        float* __restrict__ snAcc,
        float* __restrict__ fnAcc)
{
    __shared__ float uni[8192];                   // 32 KB: A-frags (16K), then L-frags (32K)
    __shared__ float sY[FGK_EPB][FGK_YP];         // y, later overlaid by sTri
    __shared__ int sE[FGK_EPB], sSrc[FGK_EPB], sDst[FGK_EPB];
    __shared__ int sStart[FGK_EPB], sEnd[FGK_EPB], sDstSlot[FGK_EPB];
    __shared__ int sNS;
    unsigned short* aH = (unsigned short*)uni;            // 4096 us
    unsigned short* aL = (unsigned short*)uni + 4096;     // 4096 us
    unsigned short* lH = (unsigned short*)uni;            // 8192 us (after reuse)
    unsigned short* lL = (unsigned short*)uni + 8192;     // 8192 us
    float* sTri = (float*)sY;                             // 4352-float overlay (<4992)
    int t = threadIdx.x;                          // 512 threads, 8 waves
    int lane = t & 63, wave = t >> 6;
    int e0 = blockIdx.x * FGK_EPB;

    if (wave == 0) {                              // meta load + parallel slot detect
        int e = 0, sv = 0, dv = 0x7fffffff;
        if (lane < FGK_EPB) {
            e = perm[e0 + lane];
            sv = srcIdx[e];
            dv = dstIdx[e];
            sE[lane] = e; sSrc[lane] = sv; sDst[lane] = dv;
        }
        int prev = __shfl_up(dv, 1);
        bool isStart = (lane < FGK_EPB) && (lane == 0 || dv != prev);
        unsigned long long mask = __ballot(isStart);
        int ns = __popcll(mask);
        if (isStart) {
            int s = (int)__popcll(mask & ((1ull << lane) - 1ull));
            sStart[s] = lane;
            sDstSlot[s] = dv;
            if (lane) sEnd[s - 1] = lane;
        }
        if (lane == 0) { sNS = ns; sEnd[ns - 1] = FGK_EPB; }
    }
    __syncthreads();

    // ---- msg = relu(hinB[src] + ea) + 1e-7 -> bf16 hi/lo A-frags ----
    // one thread <-> (edge el, 8 consecutive cols); hin gathered as bf16 (16B/thread)
    {
        int el = t >> 4, b = t & 15;
        s16x8 hraw = *(const s16x8*)(hinB + (size_t)sSrc[el] * FGK_H + b * 8);
        const float4* ap = (const float4*)(eatt + (size_t)sE[el] * 8);
        float4 a0 = ap[0], a1 = ap[1];
        float av[8] = {a0.x, a0.y, a0.z, a0.w, a1.x, a1.y, a1.z, a1.w};
        const float4* bp = (const float4*)(eeb + b * 8);
        float4 b0 = bp[0], b1 = bp[1];
        float acc[8] = {b0.x, b0.y, b0.z, b0.w, b1.x, b1.y, b1.z, b1.w};
#pragma unroll
        for (int kk = 0; kk < 8; ++kk) {
            const float4* wp = (const float4*)(eew + kk * FGK_H + b * 8);
            float4 w0 = wp[0], w1 = wp[1];
            acc[0] += av[kk] * w0.x; acc[1] += av[kk] * w0.y;
            acc[2] += av[kk] * w0.z; acc[3] += av[kk] * w0.w;
            acc[4] += av[kk] * w1.x; acc[5] += av[kk] * w1.y;
            acc[6] += av[kk] * w1.z; acc[7] += av[kk] * w1.w;
        }
        s16x8 hb, lb;
#pragma unroll
        for (int jj = 0; jj < 8; ++jj) {
            float hv = fgk_u2f((unsigned short)hraw[jj]);
            float m = fmaxf(hv + acc[jj], 0.f) + 1e-7f;
            unsigned short h = fgk_f2b(m);
            hb[jj] = (short)h;
            lb[jj] = (short)fgk_f2b(m - fgk_u2f(h));
        }
        int c = b >> 2, g = b & 3;                // k = b*8+jj = 32c+8g+jj
        int idx = fgk_swL(c * 128 + 32 * g + el) * 8;
        *(s16x8*)&aH[idx] = hb;
        *(s16x8*)&aL[idx] = lb;
    }
    __syncthreads();

    // ---- y = msg @ a1w via MFMA (writes sY); wave w: A-tile et=w&1, nt=(w>>1)+4k ----
    {
        int et = wave & 1;
        s16x8 ah[4], al[4];
#pragma unroll
        for (int c = 0; c < 4; ++c) {
            int idx = fgk_swL(c * 128 + 32 * (lane >> 4) + 16 * et + (lane & 15)) * 8;
            ah[c] = *(const s16x8*)&aH[idx];
            al[c] = *(const s16x8*)&aL[idx];
        }
        int n = lane & 15, qd = lane >> 4;
        for (int nt = (wave >> 1); nt < 10; nt += 4) {
            f32x4 acc = {0.f, 0.f, 0.f, 0.f};
#pragma unroll
            for (int c = 0; c < 4; ++c) {
                size_t bidx = ((size_t)(nt * 4 + c) * 64 + lane) * 8;
                s16x8 bh = *(const s16x8*)(bHi + bidx);
                s16x8 bl = *(const s16x8*)(bLo + bidx);
                acc = __builtin_amdgcn_mfma_f32_16x16x32_bf16(al[c], bh, acc, 0, 0, 0);
                acc = __builtin_amdgcn_mfma_f32_16x16x32_bf16(ah[c], bl, acc, 0, 0, 0);
                acc = __builtin_amdgcn_mfma_f32_16x16x32_bf16(ah[c], bh, acc, 0, 0, 0);
            }
            int j = nt * 16 + n;
            if (j < FGK_F) {                       // GUARD: pad cols must not wrap
                float bias = a1b[j];
#pragma unroll
                for (int reg = 0; reg < 4; ++reg)
                    sY[16 * et + 4 * qd + reg][j] = acc[reg] + bias;
            }
        }
    }
    __syncthreads();   // sY = y; aH/aL dead -> uni becomes L-frag region

    // ---- L build pass 1: vectorized half-rows (FILL_IDX maps each 8-elem
    //      half-row to 8 contiguous sY floats, ascending p<120 / descending) ----
    {
#pragma unroll
        for (int it = 0; it < 2; ++it) {
            int s = t + it * 512;            // 1024 slots: el(32) x r(32)
            int el = s & 31;
            int r  = s >> 5;                 // 0..31
            int i  = r & 15, h = r >> 4;
            int pstart = 16 * i + 8 * h;
            float v[8];
            if (pstart < 120) {              // q = p+16 ascending
                const float4* rp = (const float4*)&sY[el][32 + pstart];
                float4 v0 = rp[0], v1 = rp[1];
                v[0] = v0.x; v[1] = v0.y; v[2] = v0.z; v[3] = v0.w;
                v[4] = v1.x; v[5] = v1.y; v[6] = v1.z; v[7] = v1.w;
            } else {                         // q = 255-p descending
                const float4* rp = (const float4*)&sY[el][264 - pstart];
                float4 v0 = rp[0], v1 = rp[1];
                v[0] = v1.w; v[1] = v1.z; v[2] = v1.y; v[3] = v1.x;
                v[4] = v0.w; v[5] = v0.z; v[6] = v0.y; v[7] = v0.x;
            }
            s16x8 hb, lb;
#pragma unroll
            for (int jj = 0; jj < 8; ++jj) {
                unsigned short hbv = fgk_f2b(v[jj]);
                hb[jj] = (short)hbv;
                lb[jj] = (short)fgk_f2b(v[jj] - fgk_u2f(hbv));
            }
            int idx = fgk_swL(el * 32 + i + 16 * h) * 8;
            *(s16x8*)&lH[idx] = hb;
            *(s16x8*)&lL[idx] = lb;
        }
    }
    __syncthreads();

    // ---- pass 2: diag softplus + per-slot score reduction/atomics ----
    {
        int el = t >> 4, d = t & 15;         // el 0..31
        int p = 17 * d;
        int q = (p < 120) ? (p + 16) : (255 - p);
        float v = sY[el][16 + q];
        v = fmaxf(v, 0.f) + log1pf(expf(-fabsf(v)));  // softplus
        unsigned short hb = fgk_f2b(v);
        unsigned short lb = fgk_f2b(v - fgk_u2f(hb));
        int idx = fgk_swL(el * 32 + d + 16 * (d >> 3)) * 8 + (d & 7);
        lH[idx] = hb; lL[idx] = lb;
        int s = el, j = d;
        if (s < sNS) {
            float sum = 0.f;
            for (int e2 = sStart[s]; e2 < sEnd[s]; ++e2) sum += sY[e2][j];
            atomicAdd(&snAcc[(size_t)sDstSlot[s] * FGK_P + j], sum);
        }
    }
    __syncthreads();

    // ---- Fe = L L^T via MFMA; park lower tri in LDS (overlay sY) ----
#pragma unroll
    for (int i4 = 0; i4 < 4; ++i4) {
        int el = wave * 4 + i4;              // 0..31
        s16x8 fh = {0, 0, 0, 0, 0, 0, 0, 0};
        s16x8 fl = {0, 0, 0, 0, 0, 0, 0, 0};
        if (lane < 32) {
            int idx = fgk_swL(el * 32 + lane) * 8;
            fh = *(const s16x8*)&lH[idx];
            fl = *(const s16x8*)&lL[idx];
        }
        f32x4 acc = {0.f, 0.f, 0.f, 0.f};
        acc = __builtin_amdgcn_mfma_f32_16x16x32_bf16(fh, fh, acc, 0, 0, 0);
        acc = __builtin_amdgcn_mfma_f32_16x16x32_bf16(fh, fl, acc, 0, 0, 0);
        acc = __builtin_amdgcn_mfma_f32_16x16x32_bf16(fl, fh, acc, 0, 0, 0);
        int j = lane & 15, qd = lane >> 4;
#pragma unroll
        for (int reg = 0; reg < 4; ++reg) {
            int ii = 4 * qd + reg;
            if (ii >= j) sTri[el * FGK_TRI + ii * (ii + 1) / 2 + j] = acc[reg];
        }
    }
    __syncthreads();

    // ---- per-slot tri reduction -> coalesced atomics ----
    {
        int nS = sNS;
        for (int o = t; o < nS * FGK_TRI; o += 512) {
            int s = o / FGK_TRI, p = o - s * FGK_TRI;
            float sum = 0.f;
            for (int el = sStart[s]; el < sEnd[s]; ++el) sum += sTri[el * FGK_TRI + p];
            atomicAdd(&fnAcc[(size_t)sDstSlot[s] * FGK_TRI + p], sum);
        }
    }
}

// one thread per node: fully-unrolled register Cholesky solve of (F_n+I) x = s_n
// 64-thread blocks: 313 workgroups spread over all 256 CUs
#define TA(i, j) a[(i) * ((i) + 1) / 2 + (j)]
__global__ void __launch_bounds__(64)
fgkSolve(const float* __restrict__ snAcc,
         const float* __restrict__ fnAcc,
         float* __restrict__ mleOut)
{
    int n = blockIdx.x * blockDim.x + threadIdx.x;
    if (n >= FGK_NN) return;
    float a[FGK_TRI];
    const float4* src = (const float4*)(fnAcc + (size_t)n * FGK_TRI);
#pragma unroll
    for (int p = 0; p < FGK_TRI / 4; ++p) {
        float4 v = src[p];
        a[p * 4] = v.x; a[p * 4 + 1] = v.y; a[p * 4 + 2] = v.z; a[p * 4 + 3] = v.w;
    }
#pragma unroll
    for (int i = 0; i < 16; ++i) TA(i, i) += 1.f;
#pragma unroll
    for (int k = 0; k < 16; ++k) {
        float d = sqrtf(TA(k, k));
        float inv = 1.f / d;
        TA(k, k) = d;
#pragma unroll
        for (int i = k + 1; i < 16; ++i) TA(i, k) *= inv;
#pragma unroll
        for (int j = k + 1; j < 16; ++j) {
            float ajk = TA(j, k);
#pragma unroll
            for (int i = j; i < 16; ++i) TA(i, j) -= TA(i, k) * ajk;
        }
    }
    const float* sp = snAcc + (size_t)n * FGK_P;
    float y[16], x[16];
#pragma unroll
    for (int i = 0; i < 16; ++i) {
        float acc = sp[i];
#pragma unroll
        for (int k = 0; k < 16; ++k) if (k < i) acc -= TA(i, k) * y[k];
        y[i] = acc / TA(i, i);
    }
#pragma unroll
    for (int i = 15; i >= 0; --i) {
        float acc = y[i];
#pragma unroll
        for (int k = 0; k < 16; ++k) if (k > i) acc -= TA(k, i) * x[k];
        x[i] = acc / TA(i, i);
    }
    float4* dst = (float4*)(mleOut + (size_t)n * FGK_P);
#pragma unroll
    for (int p = 0; p < 4; ++p) dst[p] = make_float4(x[p * 4], x[p * 4 + 1], x[p * 4 + 2], x[p * 4 + 3]);
}
#undef TA

// node (16 nodes/block): a2+res -> m1 MFMA -> LN -> m2 MFMA -> hout
// + fused next-layer relu(LN(hout)) -> hinNext f32 + bf16 (doNext)
__global__ void __launch_bounds__(256)
fgkNode(const float* __restrict__ hin,
        const float* __restrict__ mleIn,
        const float* __restrict__ a2w, const float* __restrict__ a2b,
        const unsigned short* __restrict__ m1H, const unsigned short* __restrict__ m1L,
        const float* __restrict__ m1b,
        const float* __restrict__ gamma, const float* __restrict__ beta,
        const unsigned short* __restrict__ m2H, const unsigned short* __restrict__ m2L,
        const float* __restrict__ m2b,
        float* __restrict__ hout, int addres,
        float* __restrict__ hinNext, unsigned short* __restrict__ hinNextB,
        const float* __restrict__ gN, const float* __restrict__ bN, int doNext)
{
    __shared__ char uniN[16384];
    __shared__ float sT[16][260];
    __shared__ float stats[16][2];
    unsigned short* ovH = (unsigned short*)uniN;
    unsigned short* ovL = (unsigned short*)uniN + 2048;
    unsigned short* t2H = (unsigned short*)uniN;
    unsigned short* t2L = (unsigned short*)uniN + 4096;
    int t = threadIdx.x, lane = t & 63, wave = t >> 6;
    int n0 = blockIdx.x * 16;

    // ---- a2 matvec + residual -> bf16 hi/lo frags (one pass, vectorized) ----
    {
        int node = t >> 4, cg = t & 15;            // 8 cols per thread
        const float4* m4 = (const float4*)(mleIn + (size_t)(n0 + node) * FGK_P);
        float4 q0 = m4[0], q1 = m4[1], q2 = m4[2], q3 = m4[3];
        float mv[16] = {q0.x, q0.y, q0.z, q0.w, q1.x, q1.y, q1.z, q1.w,
                        q2.x, q2.y, q2.z, q2.w, q3.x, q3.y, q3.z, q3.w};
        const float4* bp = (const float4*)(a2b + cg * 8);
        float4 b0 = bp[0], b1 = bp[1];
        const float4* hp = (const float4*)(hin + (size_t)(n0 + node) * FGK_H + cg * 8);
        float4 h0 = hp[0], h1 = hp[1];
        float acc[8] = {b0.x + h0.x, b0.y + h0.y, b0.z + h0.z, b0.w + h0.w,
                        b1.x + h1.x, b1.y + h1.y, b1.z + h1.z, b1.w + h1.w};
#pragma unroll
        for (int k = 0; k < 16; ++k) {
            const float4* wp = (const float4*)(a2w + k * FGK_H + cg * 8);
            float4 w0 = wp[0], w1 = wp[1];
            acc[0] += mv[k] * w0.x; acc[1] += mv[k] * w0.y;
            acc[2] += mv[k] * w0.z; acc[3] += mv[k] * w0.w;
            acc[4] += mv[k] * w1.x; acc[5] += mv[k] * w1.y;
            acc[6] += mv[k] * w1.z; acc[7] += mv[k] * w1.w;
        }
        s16x8 hb, lb;
#pragma unroll
        for (int jj = 0; jj < 8; ++jj) {
            unsigned short hbv = fgk_f2b(acc[jj]);
            hb[jj] = (short)hbv;
            lb[jj] = (short)fgk_f2b(acc[jj] - fgk_u2f(hbv));
        }
        int idx = fgk_sw(cg * 16 + node) * 8;      // u = c*64+16g+node = 16*cg+node
        *(s16x8*)&ovH[idx] = hb;
        *(s16x8*)&ovL[idx] = lb;
    }
    __syncthreads();

    {
        s16x8 ah[4], al[4];
#pragma unroll
        for (int c = 0; c < 4; ++c) {
            int idx = fgk_sw(c * 64 + lane) * 8;
            ah[c] = *(const s16x8*)&ovH[idx];
            al[c] = *(const s16x8*)&ovL[idx];
        }
        int n = lane & 15, qd = lane >> 4;
#pragma unroll
        for (int i4 = 0; i4 < 4; ++i4) {
            int nt = wave + i4 * 4;
            f32x4 acc = {0.f, 0.f, 0.f, 0.f};
#pragma unroll
            for (int c = 0; c < 4; ++c) {
                size_t bidx = ((size_t)(nt * 4 + c) * 64 + lane) * 8;
                s16x8 bh = *(const s16x8*)(m1H + bidx);
                s16x8 bl = *(const s16x8*)(m1L + bidx);
                acc = __builtin_amdgcn_mfma_f32_16x16x32_bf16(al[c], bh, acc, 0, 0, 0);
                acc = __builtin_amdgcn_mfma_f32_16x16x32_bf16(ah[c], bl, acc, 0, 0, 0);
                acc = __builtin_amdgcn_mfma_f32_16x16x32_bf16(ah[c], bh, acc, 0, 0, 0);
            }
            int j = nt * 16 + n;
            float bias = m1b[j];
#pragma unroll
            for (int reg = 0; reg < 4; ++reg)
                sT[4 * qd + reg][j] = acc[reg] + bias;
        }
    }
    __syncthreads();

    {
        int node = t >> 4, seg = t & 15;
        const float* rowp = &sT[node][seg * 16];
        float s1 = 0.f, s2 = 0.f;
#pragma unroll
        for (int k = 0; k < 16; ++k) { float v = rowp[k]; s1 += v; s2 += v * v; }
#pragma unroll
        for (int off = 8; off; off >>= 1) {
            s1 += __shfl_down(s1, off, 16);
            s2 += __shfl_down(s2, off, 16);
        }
        if (seg == 0) {
            float mu = s1 * (1.f / 256.f);
            float var = s2 * (1.f / 256.f) - mu * mu;
            stats[node][0] = mu;
            stats[node][1] = rsqrtf(var + 1e-5f);
        }
    }
    __syncthreads();

    // ---- LN + relu -> bf16 hi/lo frags (vectorized, swizzled b128 stores) ----
    {
        int node = t >> 4;
        float mu = stats[node][0], rstd = stats[node][1];
#pragma unroll
        for (int h = 0; h < 2; ++h) {
            int cg = (t & 15) + 16 * h;            // 0..31, 8 cols each
            const float4* rp = (const float4*)&sT[node][cg * 8];
            float4 v0 = rp[0], v1 = rp[1];
            const float4* gp = (const float4*)(gamma + cg * 8);
            float4 g0 = gp[0], g1 = gp[1];
            const float4* bb = (const float4*)(beta + cg * 8);
            float4 e0 = bb[0], e1 = bb[1];
            float vv[8] = {v0.x, v0.y, v0.z, v0.w, v1.x, v1.y, v1.z, v1.w};
            float gg[8] = {g0.x, g0.y, g0.z, g0.w, g1.x, g1.y, g1.z, g1.w};
            float ee[8] = {e0.x, e0.y, e0.z, e0.w, e1.x, e1.y, e1.z, e1.w};
            s16x8 hb, lb;
#pragma unroll
            for (int jj = 0; jj < 8; ++jj) {
                float tv = fmaxf((vv[jj] - mu) * rstd * gg[jj] + ee[jj], 0.f);
                unsigned short hbv = fgk_f2b(tv);
                hb[jj] = (short)hbv;
                lb[jj] = (short)fgk_f2b(tv - fgk_u2f(hbv));
            }
            int idx = fgk_sw(cg * 16 + node) * 8;
            *(s16x8*)&t2H[idx] = hb;
            *(s16x8*)&t2L[idx] = lb;
        }
    }
    __syncthreads();

    {
        s16x8 ah[8], al[8];
#pragma unroll
        for (int c = 0; c < 8; ++c) {
            int idx = fgk_sw(c * 64 + lane) * 8;
            ah[c] = *(const s16x8*)&t2H[idx];
            al[c] = *(const s16x8*)&t2L[idx];
        }
        int n = lane & 15, qd = lane >> 4;
#pragma unroll
        for (int i2 = 0; i2 < 2; ++i2) {
            int nt = wave * 2 + i2;
            f32x4 acc = {0.f, 0.f, 0.f, 0.f};
#pragma unroll
            for (int c = 0; c < 8; ++c) {
                size_t bidx = ((size_t)(nt * 8 + c) * 64 + lane) * 8;
                s16x8 bh = *(const s16x8*)(m2H + bidx);
                s16x8 bl = *(const s16x8*)(m2L + bidx);
                acc = __builtin_amdgcn_mfma_f32_16x16x32_bf16(al[c], bh, acc, 0, 0, 0);
                acc = __builtin_amdgcn_mfma_f32_16x16x32_bf16(ah[c], bl, acc, 0, 0, 0);
                acc = __builtin_amdgcn_mfma_f32_16x16x32_bf16(ah[c], bh, acc, 0, 0, 0);
            }
            int j = nt * 16 + n;
            float bias = m2b[j];
#pragma unroll
            for (int reg = 0; reg < 4; ++reg) {
                int node = 4 * qd + reg;
                size_t idx = (size_t)(n0 + node) * FGK_H + j;
                float val = acc[reg] + bias;
                float nv = addres ? (hout[idx] + val) : val;
                hout[idx] = nv;
                sT[node][j] = nv;          // park for fused next-layer LN
            }
        }
    }
    if (doNext) {                          // hinNext = relu(LN(hout, gN, bN))
        __syncthreads();
        int node = t >> 4, seg = t & 15;
        const float* rowp = &sT[node][seg * 8];
        float s1 = 0.f, s2 = 0.f;
#pragma unroll
        for (int k = 0; k < 8; ++k) { float v = rowp[k]; s1 += v; s2 += v * v; }
#pragma unroll
        for (int off = 8; off; off >>= 1) {
            s1 += __shfl_down(s1, off, 16);
            s2 += __shfl_down(s2, off, 16);
        }
        if (seg == 0) {
            float mu = s1 * (1.f / 128.f);
            float var = s2 * (1.f / 128.f) - mu * mu;
            stats[node][0] = mu;
            stats[node][1] = rsqrtf(var + 1e-5f);
        }
        __syncthreads();
        float mu = stats[node][0], rstd = stats[node][1];
#pragma unroll
        for (int kk = 0; kk < 8; ++kk) {
            int k = seg * 8 + kk;
            float v = sT[node][k];
            float nv = fmaxf((v - mu) * rstd * gN[k] + bN[k], 0.f);
            size_t oidx = (size_t)(n0 + node) * FGK_H + k;
            hinNext[oidx] = nv;
            hinNextB[oidx] = fgk_f2b(nv);
        }
    }
}

// out = relu(LN(h, g0, b0)) @ lin_w + lin_b   (f32 out)
__global__ void fgkFinal(const float* __restrict__ hsrc,
                         const float* __restrict__ gamma,
                         const float* __restrict__ beta,
                         const float* __restrict__ lw,
                         const float* __restrict__ lb,
                         float* __restrict__ outp)
{
    int n = blockIdx.x, t = threadIdx.x;   // block = 128
    __shared__ float tt[FGK_H];
    __shared__ float red[4];
    float v = hsrc[(size_t)n * FGK_H + t];
    float s1 = v, s2 = v * v;
#pragma unroll
    for (int off = 32; off; off >>= 1) { s1 += __shfl_down(s1, off); s2 += __shfl_down(s2, off); }
    int wid = t >> 6, lane = t & 63;
    if (lane == 0) { red[wid] = s1; red[2 + wid] = s2; }
    __syncthreads();
    float mu = (red[0] + red[1]) * (1.f / FGK_H);
    float var = (red[2] + red[3]) * (1.f / FGK_H) - mu * mu;
    float rstd = rsqrtf(var + 1e-5f);
    tt[t] = fmaxf((v - mu) * rstd * gamma[t] + beta[t], 0.f);
    __syncthreads();
    if (t < 112) {
        float acc = lb[t];
        for (int k = 0; k < FGK_H; k++) acc += tt[k] * lw[k * 112 + t];
        outp[(size_t)n * 112 + t] = acc;
    }
}

extern "C" void kernel_launch(void* const* d_in, const int* in_sizes, int n_in,
                              void* d_out, int out_size, void* d_ws, size_t ws_size,
                              hipStream_t stream)
{
    const float* xin  = (const float*)d_in[0];
    const float* eatt = (const float*)d_in[1];
    const int*   eidx = (const int*)d_in[2];
    const float* nEw  = (const float*)d_in[3];
    const float* nEb  = (const float*)d_in[4];
    const float* eEw  = (const float*)d_in[5];
    const float* eEb  = (const float*)d_in[6];
    const float* a1w  = (const float*)d_in[7];
    const float* a1b  = (const float*)d_in[8];
    const float* a2w  = (const float*)d_in[9];
    const float* a2b  = (const float*)d_in[10];
    const float* m1w  = (const float*)d_in[11];
    const float* m1b  = (const float*)d_in[12];
    const float* lng  = (const float*)d_in[13];
    const float* lnb  = (const float*)d_in[14];
    const float* m2w  = (const float*)d_in[15];
    const float* m2b  = (const float*)d_in[16];
    const float* ng   = (const float*)d_in[17];
    const float* nb   = (const float*)d_in[18];
    const float* lw   = (const float*)d_in[19];
    const float* lb   = (const float*)d_in[20];
    float* outp = (float*)d_out;
    const int* srcIdx = eidx;
    const int* dstIdx = eidx + FGK_NE;

    float* ws   = (float*)d_ws;
    float* hAcc = ws;                                    // NN*128
    float* hin  = hAcc + (size_t)FGK_NN * FGK_H;         // NN*128
    float* snA  = hin  + (size_t)FGK_NN * FGK_H;         // NN*16
    float* fnA  = snA  + (size_t)FGK_NN * FGK_P;         // NN*136
    float* mle  = fnA  + (size_t)FGK_NN * FGK_TRI;       // NN*16
    unsigned short* wsU = (unsigned short*)(mle + (size_t)FGK_NN * FGK_P);
    const int A1F = 40 * 512, M1F = 64 * 512, M2F = 64 * 512;
    unsigned short* a1Hi = wsU;
    unsigned short* a1Lo = a1Hi + 3 * A1F;
    unsigned short* m1Hi = a1Lo + 3 * A1F;
    unsigned short* m1Lo = m1Hi + 3 * M1F;
    unsigned short* m2Hi = m1Lo + 3 * M1F;
    unsigned short* m2Lo = m2Hi + 3 * M2F;
    int* cursor = (int*)(m2Lo + 3 * M2F);                // NN ints
    int* perm   = cursor + FGK_NN;                       // NE ints
    unsigned short* hinB = (unsigned short*)(perm + FGK_NE);   // NN*128 bf16

    // dst-sorted edge permutation (edge_index constant; rebuilt every launch)
    fgkZeroI<<<(FGK_NN + 255) / 256, 256, 0, stream>>>(cursor, FGK_NN);
    fgkHist<<<(FGK_NE + 255) / 256, 256, 0, stream>>>(dstIdx, cursor);
    fgkScan<<<1, 1024, 0, stream>>>(cursor, cursor);     // in-place exclusive scan
    fgkScatterE<<<(FGK_NE + 255) / 256, 256, 0, stream>>>(dstIdx, cursor, perm);

    for (int l = 0; l < 3; l++) {
        fgkPrepW<<<40, 64, 0, stream>>>(a1w + (size_t)l * FGK_H * FGK_F, 128, 152,
                                        a1Hi + l * A1F, a1Lo + l * A1F);
        fgkPrepW<<<64, 64, 0, stream>>>(m1w + (size_t)l * FGK_H * 256, 128, 256,
                                        m1Hi + l * M1F, m1Lo + l * M1F);
        fgkPrepW<<<64, 64, 0, stream>>>(m2w + (size_t)l * 256 * FGK_H, 256, 128,
                                        m2Hi + l * M2F, m2Lo + l * M2F);
    }
    fgkEnc<<<(FGK_NN * FGK_H + 255) / 256, 256, 0, stream>>>(xin, nEw, nEb, hin, hinB);
    for (int l = 0; l < 3; l++) {
        fgkZero<<<(FGK_NN * (FGK_P + FGK_TRI) + 255) / 256, 256, 0, stream>>>(snA);
        fgkEdge<<<FGK_NE / FGK_EPB, 512, 0, stream>>>(eatt, srcIdx, dstIdx, perm, eEw, eEb,
            a1Hi + l * A1F, a1Lo + l * A1F, a1b + (size_t)l * FGK_F, hinB, snA, fnA);
        fgkSolve<<<(FGK_NN + 63) / 64, 64, 0, stream>>>(snA, fnA, mle);
        fgkNode<<<FGK_NN / 16, 256, 0, stream>>>(hin, mle,
            a2w + (size_t)l * FGK_P * FGK_H, a2b + (size_t)l * FGK_H,
            m1Hi + l * M1F, m1Lo + l * M1F, m1b + (size_t)l * 256,
            lng + (size_t)l * 256, lnb + (size_t)l * 256,
            m2Hi + l * M2F, m2Lo + l * M2F, m2b + (size_t)l * FGK_H,
            hAcc, l > 0 ? 1 : 0,
            hin, hinB, ng + (l + 1) * FGK_H, nb + (l + 1) * FGK_H, l < 2 ? 1 : 0);
    }
    fgkFinal<<<FGK_NN, FGK_H, 0, stream>>>(hAcc, ng, nb, lw, lb, outp);
}

// Round 9
// 795.866 us; speedup vs baseline: 1.0498x; 1.0498x over previous
//
#include <hip/hip_runtime.h>
#include <cmath>
#include <cstddef>

#define FGK_NN   20000
#define FGK_NE   320000
#define FGK_H    128
#define FGK_P    16
#define FGK_TRI  136
#define FGK_F    152
#define FGK_EPB  32
#define FGK_YP   156          // sY row stride (>=152, 16B-aligned rows, 28 mod 32)

typedef short  s16x8 __attribute__((ext_vector_type(8)));
typedef float  f32x4 __attribute__((ext_vector_type(4)));

__device__ __forceinline__ unsigned short fgk_f2b(float f) {   // RNE f32->bf16 (native cvt)
    __bf16 b = (__bf16)f;
    return __builtin_bit_cast(unsigned short, b);
}
__device__ __forceinline__ float fgk_u2f(unsigned short u) {
    return __uint_as_float(((unsigned int)u) << 16);
}
// bank-conflict swizzles on 16B-unit index (bijective XOR of high bits into group bits)
__device__ __forceinline__ int fgk_sw(int u)  { return u ^ ((u >> 4) & 7); }  // node-kernel pattern
__device__ __forceinline__ int fgk_swL(int u) { return u ^ ((u >> 5) & 7); }  // edge-kernel pattern

__global__ void FishnetGCN_62096637165586_kernel() {}

__global__ void fgkZero(float* acc) {
    int i = blockIdx.x * blockDim.x + threadIdx.x;
    if (i < FGK_NN * (FGK_P + FGK_TRI)) acc[i] = 0.f;
}
__global__ void fgkZeroI(int* p, int n) {
    int i = blockIdx.x * blockDim.x + threadIdx.x;
    if (i < n) p[i] = 0;
}
// ---- dst-sort: histogram -> block scan -> scatter (edge_index constant) ----
__global__ void fgkHist(const int* __restrict__ dst, int* __restrict__ hist) {
    int e = blockIdx.x * blockDim.x + threadIdx.x;
    if (e < FGK_NE) atomicAdd(&hist[dst[e]], 1);
}
__global__ void fgkScan(const int* __restrict__ hist, int* __restrict__ cursor)
{
    __shared__ int sWave[16];
    __shared__ int sRun;
    int t = threadIdx.x;             // 1024
    int lane = t & 63, wv = t >> 6;
    if (t == 0) sRun = 0;
    __syncthreads();
    for (int base = 0; base < FGK_NN; base += 1024) {
        int idx = base + t;
        int v = (idx < FGK_NN) ? hist[idx] : 0;
        int sc = v;
#pragma unroll
        for (int off = 1; off < 64; off <<= 1) {
            int u = __shfl_up(sc, off);
            if (lane >= off) sc += u;
        }
        if (lane == 63) sWave[wv] = sc;
        __syncthreads();
        if (wv == 0 && lane < 16) {
            int w = sWave[lane];
#pragma unroll
            for (int off = 1; off < 16; off <<= 1) {
                int u = __shfl_up(w, off, 16);
                if (lane >= off) w += u;
            }
            sWave[lane] = w;
        }
        __syncthreads();
        int waveOff = (wv == 0) ? 0 : sWave[wv - 1];
        int run = sRun;
        if (idx < FGK_NN) cursor[idx] = run + waveOff + sc - v;   // exclusive
        __syncthreads();
        if (t == 1023) sRun = run + sWave[15];
        __syncthreads();
    }
}
// scatter + emit perm-ordered src/dst arrays (removes double-indirection later)
__global__ void fgkScatterE(const int* __restrict__ dst, const int* __restrict__ src,
                            int* __restrict__ cursor, int* __restrict__ perm,
                            int* __restrict__ srcP, int* __restrict__ dstP) {
    int e = blockIdx.x * blockDim.x + threadIdx.x;
    if (e < FGK_NE) {
        int d = dst[e];
        int pos = atomicAdd(&cursor[d], 1);
        perm[pos] = e;
        srcP[pos] = src[e];
        dstP[pos] = d;
    }
}

// One-time, layer-invariant: eaP[pos] = bf16(eatt[perm[pos]] @ eew + eeb), perm order.
// 256 threads: thread = (pos in 16-group, 8-col group)
__global__ void fgkEncE(const float* __restrict__ eatt,
                        const int* __restrict__ perm,
                        const float* __restrict__ eew,
                        const float* __restrict__ eeb,
                        unsigned short* __restrict__ eaP)
{
    int pos = blockIdx.x * 16 + (threadIdx.x >> 4);
    int b = threadIdx.x & 15;
    int e = perm[pos];
    const float4* ap = (const float4*)(eatt + (size_t)e * 8);
    float4 a0 = ap[0], a1 = ap[1];
    float av[8] = {a0.x, a0.y, a0.z, a0.w, a1.x, a1.y, a1.z, a1.w};
    const float4* bp = (const float4*)(eeb + b * 8);
    float4 b0 = bp[0], b1 = bp[1];
    float acc[8] = {b0.x, b0.y, b0.z, b0.w, b1.x, b1.y, b1.z, b1.w};
#pragma unroll
    for (int kk = 0; kk < 8; ++kk) {
        const float4* wp = (const float4*)(eew + kk * FGK_H + b * 8);
        float4 w0 = wp[0], w1 = wp[1];
        acc[0] += av[kk] * w0.x; acc[1] += av[kk] * w0.y;
        acc[2] += av[kk] * w0.z; acc[3] += av[kk] * w0.w;
        acc[4] += av[kk] * w1.x; acc[5] += av[kk] * w1.y;
        acc[6] += av[kk] * w1.z; acc[7] += av[kk] * w1.w;
    }
    s16x8 r;
#pragma unroll
    for (int jj = 0; jj < 8; ++jj) r[jj] = (short)fgk_f2b(acc[jj]);
    *(s16x8*)&eaP[(size_t)pos * FGK_H + b * 8] = r;
}

// Generic prepack of W[K,N] (row-major) into MFMA B-fragment order, bf16 hi/lo.
__global__ void fgkPrepW(const float* __restrict__ W, int K, int N,
                         unsigned short* __restrict__ hi,
                         unsigned short* __restrict__ lo)
{
    int chunks = K >> 5;
    int b = blockIdx.x;
    int nt = b / chunks, c = b - nt * chunks;
    int lane = threadIdx.x;
    int n = nt * 16 + (lane & 15);
    int g = lane >> 4;
    size_t base = ((size_t)b * 64 + lane) * 8;
#pragma unroll
    for (int j = 0; j < 8; ++j) {
        int k = c * 32 + g * 8 + j;
        float v = (n < N) ? W[(size_t)k * N + n] : 0.f;
        unsigned short hb = fgk_f2b(v);
        unsigned short lb = fgk_f2b(v - fgk_u2f(hb));
        hi[base + j] = hb;
        lo[base + j] = lb;
    }
}

// hin = x @ W[8,128] + b   (f32 + bf16 gather copy)
__global__ void fgkEnc(const float* __restrict__ xin,
                       const float* __restrict__ wenc,
                       const float* __restrict__ benc,
                       float* __restrict__ hin,
                       unsigned short* __restrict__ hinB)
{
    int idx = blockIdx.x * blockDim.x + threadIdx.x;
    if (idx >= FGK_NN * FGK_H) return;
    int n = idx >> 7, j = idx & 127;
    float acc = benc[j];
    const float* xp = xin + (size_t)n * 8;
#pragma unroll
    for (int k = 0; k < 8; k++) acc += xp[k] * wenc[k * FGK_H + j];
    hin[idx] = acc;
    hinB[idx] = fgk_f2b(acc);
}

// edge (sorted by dst), 32 edges/block, 512 threads:
// bf16 hin gather + streamed eaP -> msg -> A-frags ; y=MFMA ; L->frags ;
// Fe=MFMA ; per-slot LDS reduction ; atomics per distinct dst
__global__ void __launch_bounds__(512, 4)
fgkEdge(const int* __restrict__ srcP,
        const int* __restrict__ dstP,
        const unsigned short* __restrict__ eaP,
        const unsigned short* __restrict__ bHi,
        const unsigned short* __restrict__ bLo,
        const float* __restrict__ a1b,
        const unsigned short* __restrict__ hinB,
        float* __restrict__ snAcc,
        float* __restrict__ fnAcc)
{
    __shared__ float uni[8192];                   // 32 KB: A-frags (16K), then L-frags (32K)
    __shared__ float sY[FGK_EPB][FGK_YP];         // y, later overlaid by sTri
    __shared__ int sSrc[FGK_EPB], sDst[FGK_EPB];
    __shared__ int sStart[FGK_EPB], sEnd[FGK_EPB], sDstSlot[FGK_EPB];
    __shared__ int sNS;
    unsigned short* aH = (unsigned short*)uni;            // 4096 us
    unsigned short* aL = (unsigned short*)uni + 4096;     // 4096 us
    unsigned short* lH = (unsigned short*)uni;            // 8192 us (after reuse)
    unsigned short* lL = (unsigned short*)uni + 8192;     // 8192 us
    float* sTri = (float*)sY;                             // 4352-float overlay (<4992)
    int t = threadIdx.x;                          // 512 threads, 8 waves
    int lane = t & 63, wave = t >> 6;
    int e0 = blockIdx.x * FGK_EPB;

    if (wave == 0) {                              // meta load + parallel slot detect
        int sv = 0, dv = 0x7fffffff;
        if (lane < FGK_EPB) {
            sv = srcP[e0 + lane];
            dv = dstP[e0 + lane];
            sSrc[lane] = sv; sDst[lane] = dv;
        }
        int prev = __shfl_up(dv, 1);
        bool isStart = (lane < FGK_EPB) && (lane == 0 || dv != prev);
        unsigned long long mask = __ballot(isStart);
        int ns = __popcll(mask);
        if (isStart) {
            int s = (int)__popcll(mask & ((1ull << lane) - 1ull));
            sStart[s] = lane;
            sDstSlot[s] = dv;
            if (lane) sEnd[s - 1] = lane;
        }
        if (lane == 0) { sNS = ns; sEnd[ns - 1] = FGK_EPB; }
    }
    __syncthreads();

    // ---- msg = relu(hinB[src] + eaP) + 1e-7 -> bf16 hi/lo A-frags ----
    // one thread <-> (edge el, 8 cols); hin gathered bf16, eaP streamed bf16
    {
        int el = t >> 4, b = t & 15;
        s16x8 hraw = *(const s16x8*)(hinB + (size_t)sSrc[el] * FGK_H + b * 8);
        s16x8 eraw = *(const s16x8*)(eaP + (size_t)(e0 + el) * FGK_H + b * 8);
        s16x8 hb, lb;
#pragma unroll
        for (int jj = 0; jj < 8; ++jj) {
            float hv = fgk_u2f((unsigned short)hraw[jj]);
            float ev = fgk_u2f((unsigned short)eraw[jj]);
            float m = fmaxf(hv + ev, 0.f) + 1e-7f;
            unsigned short h = fgk_f2b(m);
            hb[jj] = (short)h;
            lb[jj] = (short)fgk_f2b(m - fgk_u2f(h));
        }
        int c = b >> 2, g = b & 3;                // k = b*8+jj = 32c+8g+jj
        int idx = fgk_swL(c * 128 + 32 * g + el) * 8;
        *(s16x8*)&aH[idx] = hb;
        *(s16x8*)&aL[idx] = lb;
    }
    __syncthreads();

    // ---- y = msg @ a1w via MFMA (writes sY); wave w: A-tile et=w&1, nt=(w>>1)+4k ----
    {
        int et = wave & 1;
        s16x8 ah[4], al[4];
#pragma unroll
        for (int c = 0; c < 4; ++c) {
            int idx = fgk_swL(c * 128 + 32 * (lane >> 4) + 16 * et + (lane & 15)) * 8;
            ah[c] = *(const s16x8*)&aH[idx];
            al[c] = *(const s16x8*)&aL[idx];
        }
        int n = lane & 15, qd = lane >> 4;
        for (int nt = (wave >> 1); nt < 10; nt += 4) {
            f32x4 acc = {0.f, 0.f, 0.f, 0.f};
#pragma unroll
            for (int c = 0; c < 4; ++c) {
                size_t bidx = ((size_t)(nt * 4 + c) * 64 + lane) * 8;
                s16x8 bh = *(const s16x8*)(bHi + bidx);
                s16x8 bl = *(const s16x8*)(bLo + bidx);
                acc = __builtin_amdgcn_mfma_f32_16x16x32_bf16(al[c], bh, acc, 0, 0, 0);
                acc = __builtin_amdgcn_mfma_f32_16x16x32_bf16(ah[c], bl, acc, 0, 0, 0);
                acc = __builtin_amdgcn_mfma_f32_16x16x32_bf16(ah[c], bh, acc, 0, 0, 0);
            }
            int j = nt * 16 + n;
            if (j < FGK_F) {                       // GUARD: pad cols must not wrap
                float bias = a1b[j];
#pragma unroll
                for (int reg = 0; reg < 4; ++reg)
                    sY[16 * et + 4 * qd + reg][j] = acc[reg] + bias;
            }
        }
    }
    __syncthreads();   // sY = y; aH/aL dead -> uni becomes L-frag region

    // ---- L build pass 1: vectorized half-rows (FILL_IDX maps each 8-elem
    //      half-row to 8 contiguous sY floats, ascending p<120 / descending) ----
    {
#pragma unroll
        for (int it = 0; it < 2; ++it) {
            int s = t + it * 512;            // 1024 slots: el(32) x r(32)
            int el = s & 31;
            int r  = s >> 5;                 // 0..31
            int i  = r & 15, h = r >> 4;
            int pstart = 16 * i + 8 * h;
            float v[8];
            if (pstart < 120) {              // q = p+16 ascending
                const float4* rp = (const float4*)&sY[el][32 + pstart];
                float4 v0 = rp[0], v1 = rp[1];
                v[0] = v0.x; v[1] = v0.y; v[2] = v0.z; v[3] = v0.w;
                v[4] = v1.x; v[5] = v1.y; v[6] = v1.z; v[7] = v1.w;
            } else {                         // q = 255-p descending
                const float4* rp = (const float4*)&sY[el][264 - pstart];
                float4 v0 = rp[0], v1 = rp[1];
                v[0] = v1.w; v[1] = v1.z; v[2] = v1.y; v[3] = v1.x;
                v[4] = v0.w; v[5] = v0.z; v[6] = v0.y; v[7] = v0.x;
            }
            s16x8 hb, lb;
#pragma unroll
            for (int jj = 0; jj < 8; ++jj) {
                unsigned short hbv = fgk_f2b(v[jj]);
                hb[jj] = (short)hbv;
                lb[jj] = (short)fgk_f2b(v[jj] - fgk_u2f(hbv));
            }
            int idx = fgk_swL(el * 32 + i + 16 * h) * 8;
            *(s16x8*)&lH[idx] = hb;
            *(s16x8*)&lL[idx] = lb;
        }
    }
    __syncthreads();

    // ---- pass 2: diag softplus + per-slot score reduction/atomics ----
    {
        int el = t >> 4, d = t & 15;         // el 0..31
        int p = 17 * d;
        int q = (p < 120) ? (p + 16) : (255 - p);
        float v = sY[el][16 + q];
        v = fmaxf(v, 0.f) + log1pf(expf(-fabsf(v)));  // softplus
        unsigned short hb = fgk_f2b(v);
        unsigned short lb = fgk_f2b(v - fgk_u2f(hb));
        int idx = fgk_swL(el * 32 + d + 16 * (d >> 3)) * 8 + (d & 7);
        lH[idx] = hb; lL[idx] = lb;
        int s = el, j = d;
        if (s < sNS) {
            float sum = 0.f;
            for (int e2 = sStart[s]; e2 < sEnd[s]; ++e2) sum += sY[e2][j];
            atomicAdd(&snAcc[(size_t)sDstSlot[s] * FGK_P + j], sum);
        }
    }
    __syncthreads();

    // ---- Fe = L L^T via MFMA; park lower tri in LDS (overlay sY) ----
#pragma unroll
    for (int i4 = 0; i4 < 4; ++i4) {
        int el = wave * 4 + i4;              // 0..31
        s16x8 fh = {0, 0, 0, 0, 0, 0, 0, 0};
        s16x8 fl = {0, 0, 0, 0, 0, 0, 0, 0};
        if (lane < 32) {
            int idx = fgk_swL(el * 32 + lane) * 8;
            fh = *(const s16x8*)&lH[idx];
            fl = *(const s16x8*)&lL[idx];
        }
        f32x4 acc = {0.f, 0.f, 0.f, 0.f};
        acc = __builtin_amdgcn_mfma_f32_16x16x32_bf16(fh, fh, acc, 0, 0, 0);
        acc = __builtin_amdgcn_mfma_f32_16x16x32_bf16(fh, fl, acc, 0, 0, 0);
        acc = __builtin_amdgcn_mfma_f32_16x16x32_bf16(fl, fh, acc, 0, 0, 0);
        int j = lane & 15, qd = lane >> 4;
#pragma unroll
        for (int reg = 0; reg < 4; ++reg) {
            int ii = 4 * qd + reg;
            if (ii >= j) sTri[el * FGK_TRI + ii * (ii + 1) / 2 + j] = acc[reg];
        }
    }
    __syncthreads();

    // ---- per-slot tri reduction -> coalesced atomics ----
    {
        int nS = sNS;
        for (int o = t; o < nS * FGK_TRI; o += 512) {
            int s = o / FGK_TRI, p = o - s * FGK_TRI;
            float sum = 0.f;
            for (int el = sStart[s]; el < sEnd[s]; ++el) sum += sTri[el * FGK_TRI + p];
            atomicAdd(&fnAcc[(size_t)sDstSlot[s] * FGK_TRI + p], sum);
        }
    }
}

// one thread per node: fully-unrolled register Cholesky solve of (F_n+I) x = s_n
// 64-thread blocks: 313 workgroups spread over all 256 CUs
#define TA(i, j) a[(i) * ((i) + 1) / 2 + (j)]
__global__ void __launch_bounds__(64)
fgkSolve(const float* __restrict__ snAcc,
         const float* __restrict__ fnAcc,
         float* __restrict__ mleOut)
{
    int n = blockIdx.x * blockDim.x + threadIdx.x;
    if (n >= FGK_NN) return;
    float a[FGK_TRI];
    const float4* src = (const float4*)(fnAcc + (size_t)n * FGK_TRI);
#pragma unroll
    for (int p = 0; p < FGK_TRI / 4; ++p) {
        float4 v = src[p];
        a[p * 4] = v.x; a[p * 4 + 1] = v.y; a[p * 4 + 2] = v.z; a[p * 4 + 3] = v.w;
    }
#pragma unroll
    for (int i = 0; i < 16; ++i) TA(i, i) += 1.f;
#pragma unroll
    for (int k = 0; k < 16; ++k) {
        float d = sqrtf(TA(k, k));
        float inv = 1.f / d;
        TA(k, k) = d;
#pragma unroll
        for (int i = k + 1; i < 16; ++i) TA(i, k) *= inv;
#pragma unroll
        for (int j = k + 1; j < 16; ++j) {
            float ajk = TA(j, k);
#pragma unroll
            for (int i = j; i < 16; ++i) TA(i, j) -= TA(i, k) * ajk;
        }
    }
    const float* sp = snAcc + (size_t)n * FGK_P;
    float y[16], x[16];
#pragma unroll
    for (int i = 0; i < 16; ++i) {
        float acc = sp[i];
#pragma unroll
        for (int k = 0; k < 16; ++k) if (k < i) acc -= TA(i, k) * y[k];
        y[i] = acc / TA(i, i);
    }
#pragma unroll
    for (int i = 15; i >= 0; --i) {
        float acc = y[i];
#pragma unroll
        for (int k = 0; k < 16; ++k) if (k > i) acc -= TA(k, i) * x[k];
        x[i] = acc / TA(i, i);
    }
    float4* dst = (float4*)(mleOut + (size_t)n * FGK_P);
#pragma unroll
    for (int p = 0; p < 4; ++p) dst[p] = make_float4(x[p * 4], x[p * 4 + 1], x[p * 4 + 2], x[p * 4 + 3]);
}
#undef TA

// node (16 nodes/block): a2+res -> m1 MFMA -> LN -> m2 MFMA -> hout
// + fused next-layer relu(LN(hout)) -> hinNext f32 + bf16 (doNext)
__global__ void __launch_bounds__(256)
fgkNode(const float* __restrict__ hin,
        const float* __restrict__ mleIn,
        const float* __restrict__ a2w, const float* __restrict__ a2b,
        const unsigned short* __restrict__ m1H, const unsigned short* __restrict__ m1L,
        const float* __restrict__ m1b,
        const float* __restrict__ gamma, const float* __restrict__ beta,
        const unsigned short* __restrict__ m2H, const unsigned short* __restrict__ m2L,
        const float* __restrict__ m2b,
        float* __restrict__ hout, int addres,
        float* __restrict__ hinNext, unsigned short* __restrict__ hinNextB,
        const float* __restrict__ gN, const float* __restrict__ bN, int doNext)
{
    __shared__ char uniN[16384];
    __shared__ float sT[16][260];
    __shared__ float stats[16][2];
    unsigned short* ovH = (unsigned short*)uniN;
    unsigned short* ovL = (unsigned short*)uniN + 2048;
    unsigned short* t2H = (unsigned short*)uniN;
    unsigned short* t2L = (unsigned short*)uniN + 4096;
    int t = threadIdx.x, lane = t & 63, wave = t >> 6;
    int n0 = blockIdx.x * 16;

    // ---- a2 matvec + residual -> bf16 hi/lo frags (one pass, vectorized) ----
    {
        int node = t >> 4, cg = t & 15;            // 8 cols per thread
        const float4* m4 = (const float4*)(mleIn + (size_t)(n0 + node) * FGK_P);
        float4 q0 = m4[0], q1 = m4[1], q2 = m4[2], q3 = m4[3];
        float mv[16] = {q0.x, q0.y, q0.z, q0.w, q1.x, q1.y, q1.z, q1.w,
                        q2.x, q2.y, q2.z, q2.w, q3.x, q3.y, q3.z, q3.w};
        const float4* bp = (const float4*)(a2b + cg * 8);
        float4 b0 = bp[0], b1 = bp[1];
        const float4* hp = (const float4*)(hin + (size_t)(n0 + node) * FGK_H + cg * 8);
        float4 h0 = hp[0], h1 = hp[1];
        float acc[8] = {b0.x + h0.x, b0.y + h0.y, b0.z + h0.z, b0.w + h0.w,
                        b1.x + h1.x, b1.y + h1.y, b1.z + h1.z, b1.w + h1.w};
#pragma unroll
        for (int k = 0; k < 16; ++k) {
            const float4* wp = (const float4*)(a2w + k * FGK_H + cg * 8);
            float4 w0 = wp[0], w1 = wp[1];
            acc[0] += mv[k] * w0.x; acc[1] += mv[k] * w0.y;
            acc[2] += mv[k] * w0.z; acc[3] += mv[k] * w0.w;
            acc[4] += mv[k] * w1.x; acc[5] += mv[k] * w1.y;
            acc[6] += mv[k] * w1.z; acc[7] += mv[k] * w1.w;
        }
        s16x8 hb, lb;
#pragma unroll
        for (int jj = 0; jj < 8; ++jj) {
            unsigned short hbv = fgk_f2b(acc[jj]);
            hb[jj] = (short)hbv;
            lb[jj] = (short)fgk_f2b(acc[jj] - fgk_u2f(hbv));
        }
        int idx = fgk_sw(cg * 16 + node) * 8;      // u = c*64+16g+node = 16*cg+node
        *(s16x8*)&ovH[idx] = hb;
        *(s16x8*)&ovL[idx] = lb;
    }
    __syncthreads();

    {
        s16x8 ah[4], al[4];
#pragma unroll
        for (int c = 0; c < 4; ++c) {
            int idx = fgk_sw(c * 64 + lane) * 8;
            ah[c] = *(const s16x8*)&ovH[idx];
            al[c] = *(const s16x8*)&ovL[idx];
        }
        int n = lane & 15, qd = lane >> 4;
#pragma unroll
        for (int i4 = 0; i4 < 4; ++i4) {
            int nt = wave + i4 * 4;
            f32x4 acc = {0.f, 0.f, 0.f, 0.f};
#pragma unroll
            for (int c = 0; c < 4; ++c) {
                size_t bidx = ((size_t)(nt * 4 + c) * 64 + lane) * 8;
                s16x8 bh = *(const s16x8*)(m1H + bidx);
                s16x8 bl = *(const s16x8*)(m1L + bidx);
                acc = __builtin_amdgcn_mfma_f32_16x16x32_bf16(al[c], bh, acc, 0, 0, 0);
                acc = __builtin_amdgcn_mfma_f32_16x16x32_bf16(ah[c], bl, acc, 0, 0, 0);
                acc = __builtin_amdgcn_mfma_f32_16x16x32_bf16(ah[c], bh, acc, 0, 0, 0);
            }
            int j = nt * 16 + n;
            float bias = m1b[j];
#pragma unroll
            for (int reg = 0; reg < 4; ++reg)
                sT[4 * qd + reg][j] = acc[reg] + bias;
        }
    }
    __syncthreads();

    {
        int node = t >> 4, seg = t & 15;
        const float* rowp = &sT[node][seg * 16];
        float s1 = 0.f, s2 = 0.f;
#pragma unroll
        for (int k = 0; k < 16; ++k) { float v = rowp[k]; s1 += v; s2 += v * v; }
#pragma unroll
        for (int off = 8; off; off >>= 1) {
            s1 += __shfl_down(s1, off, 16);
            s2 += __shfl_down(s2, off, 16);
        }
        if (seg == 0) {
            float mu = s1 * (1.f / 256.f);
            float var = s2 * (1.f / 256.f) - mu * mu;
            stats[node][0] = mu;
            stats[node][1] = rsqrtf(var + 1e-5f);
        }
    }
    __syncthreads();

    // ---- LN + relu -> bf16 hi/lo frags (vectorized, swizzled b128 stores) ----
    {
        int node = t >> 4;
        float mu = stats[node][0], rstd = stats[node][1];
#pragma unroll
        for (int h = 0; h < 2; ++h) {
            int cg = (t & 15) + 16 * h;            // 0..31, 8 cols each
            const float4* rp = (const float4*)&sT[node][cg * 8];
            float4 v0 = rp[0], v1 = rp[1];
            const float4* gp = (const float4*)(gamma + cg * 8);
            float4 g0 = gp[0], g1 = gp[1];
            const float4* bb = (const float4*)(beta + cg * 8);
            float4 e0 = bb[0], e1 = bb[1];
            float vv[8] = {v0.x, v0.y, v0.z, v0.w, v1.x, v1.y, v1.z, v1.w};
            float gg[8] = {g0.x, g0.y, g0.z, g0.w, g1.x, g1.y, g1.z, g1.w};
            float ee[8] = {e0.x, e0.y, e0.z, e0.w, e1.x, e1.y, e1.z, e1.w};
            s16x8 hb, lb;
#pragma unroll
            for (int jj = 0; jj < 8; ++jj) {
                float tv = fmaxf((vv[jj] - mu) * rstd * gg[jj] + ee[jj], 0.f);
                unsigned short hbv = fgk_f2b(tv);
                hb[jj] = (short)hbv;
                lb[jj] = (short)fgk_f2b(tv - fgk_u2f(hbv));
            }
            int idx = fgk_sw(cg * 16 + node) * 8;
            *(s16x8*)&t2H[idx] = hb;
            *(s16x8*)&t2L[idx] = lb;
        }
    }
    __syncthreads();

    {
        s16x8 ah[8], al[8];
#pragma unroll
        for (int c = 0; c < 8; ++c) {
            int idx = fgk_sw(c * 64 + lane) * 8;
            ah[c] = *(const s16x8*)&t2H[idx];
            al[c] = *(const s16x8*)&t2L[idx];
        }
        int n = lane & 15, qd = lane >> 4;
#pragma unroll
        for (int i2 = 0; i2 < 2; ++i2) {
            int nt = wave * 2 + i2;
            f32x4 acc = {0.f, 0.f, 0.f, 0.f};
#pragma unroll
            for (int c = 0; c < 8; ++c) {
                size_t bidx = ((size_t)(nt * 8 + c) * 64 + lane) * 8;
                s16x8 bh = *(const s16x8*)(m2H + bidx);
                s16x8 bl = *(const s16x8*)(m2L + bidx);
                acc = __builtin_amdgcn_mfma_f32_16x16x32_bf16(al[c], bh, acc, 0, 0, 0);
                acc = __builtin_amdgcn_mfma_f32_16x16x32_bf16(ah[c], bl, acc, 0, 0, 0);
                acc = __builtin_amdgcn_mfma_f32_16x16x32_bf16(ah[c], bh, acc, 0, 0, 0);
            }
            int j = nt * 16 + n;
            float bias = m2b[j];
#pragma unroll
            for (int reg = 0; reg < 4; ++reg) {
                int node = 4 * qd + reg;
                size_t idx = (size_t)(n0 + node) * FGK_H + j;
                float val = acc[reg] + bias;
                float nv = addres ? (hout[idx] + val) : val;
                hout[idx] = nv;
                sT[node][j] = nv;          // park for fused next-layer LN
            }
        }
    }
    if (doNext) {                          // hinNext = relu(LN(hout, gN, bN))
        __syncthreads();
        int node = t >> 4, seg = t & 15;
        const float* rowp = &sT[node][seg * 8];
        float s1 = 0.f, s2 = 0.f;
#pragma unroll
        for (int k = 0; k < 8; ++k) { float v = rowp[k]; s1 += v; s2 += v * v; }
#pragma unroll
        for (int off = 8; off; off >>= 1) {
            s1 += __shfl_down(s1, off, 16);
            s2 += __shfl_down(s2, off, 16);
        }
        if (seg == 0) {
            float mu = s1 * (1.f / 128.f);
            float var = s2 * (1.f / 128.f) - mu * mu;
            stats[node][0] = mu;
            stats[node][1] = rsqrtf(var + 1e-5f);
        }
        __syncthreads();
        float mu = stats[node][0], rstd = stats[node][1];
#pragma unroll
        for (int kk = 0; kk < 8; ++kk) {
            int k = seg * 8 + kk;
            float v = sT[node][k];
            float nv = fmaxf((v - mu) * rstd * gN[k] + bN[k], 0.f);
            size_t oidx = (size_t)(n0 + node) * FGK_H + k;
            hinNext[oidx] = nv;
            hinNextB[oidx] = fgk_f2b(nv);
        }
    }
}

// out = relu(LN(h, g0, b0)) @ lin_w + lin_b   (f32 out)
__global__ void fgkFinal(const float* __restrict__ hsrc,
                         const float* __restrict__ gamma,
                         const float* __restrict__ beta,
                         const float* __restrict__ lw,
                         const float* __restrict__ lb,
                         float* __restrict__ outp)
{
    int n = blockIdx.x, t = threadIdx.x;   // block = 128
    __shared__ float tt[FGK_H];
    __shared__ float red[4];
    float v = hsrc[(size_t)n * FGK_H + t];
    float s1 = v, s2 = v * v;
#pragma unroll
    for (int off = 32; off; off >>= 1) { s1 += __shfl_down(s1, off); s2 += __shfl_down(s2, off); }
    int wid = t >> 6, lane = t & 63;
    if (lane == 0) { red[wid] = s1; red[2 + wid] = s2; }
    __syncthreads();
    float mu = (red[0] + red[1]) * (1.f / FGK_H);
    float var = (red[2] + red[3]) * (1.f / FGK_H) - mu * mu;
    float rstd = rsqrtf(var + 1e-5f);
    tt[t] = fmaxf((v - mu) * rstd * gamma[t] + beta[t], 0.f);
    __syncthreads();
    if (t < 112) {
        float acc = lb[t];
        for (int k = 0; k < FGK_H; k++) acc += tt[k] * lw[k * 112 + t];
        outp[(size_t)n * 112 + t] = acc;
    }
}

extern "C" void kernel_launch(void* const* d_in, const int* in_sizes, int n_in,
                              void* d_out, int out_size, void* d_ws, size_t ws_size,
                              hipStream_t stream)
{
    const float* xin  = (const float*)d_in[0];
    const float* eatt = (const float*)d_in[1];
    const int*   eidx = (const int*)d_in[2];
    const float* nEw  = (const float*)d_in[3];
    const float* nEb  = (const float*)d_in[4];
    const float* eEw  = (const float*)d_in[5];
    const float* eEb  = (const float*)d_in[6];
    const float* a1w  = (const float*)d_in[7];
    const float* a1b  = (const float*)d_in[8];
    const float* a2w  = (const float*)d_in[9];
    const float* a2b  = (const float*)d_in[10];
    const float* m1w  = (const float*)d_in[11];
    const float* m1b  = (const float*)d_in[12];
    const float* lng  = (const float*)d_in[13];
    const float* lnb  = (const float*)d_in[14];
    const float* m2w  = (const float*)d_in[15];
    const float* m2b  = (const float*)d_in[16];
    const float* ng   = (const float*)d_in[17];
    const float* nb   = (const float*)d_in[18];
    const float* lw   = (const float*)d_in[19];
    const float* lb   = (const float*)d_in[20];
    float* outp = (float*)d_out;
    const int* srcIdx = eidx;
    const int* dstIdx = eidx + FGK_NE;

    float* ws   = (float*)d_ws;
    float* hAcc = ws;                                    // NN*128
    float* hin  = hAcc + (size_t)FGK_NN * FGK_H;         // NN*128
    float* snA  = hin  + (size_t)FGK_NN * FGK_H;         // NN*16
    float* fnA  = snA  + (size_t)FGK_NN * FGK_P;         // NN*136
    float* mle  = fnA  + (size_t)FGK_NN * FGK_TRI;       // NN*16
    unsigned short* wsU = (unsigned short*)(mle + (size_t)FGK_NN * FGK_P);
    const int A1F = 40 * 512, M1F = 64 * 512, M2F = 64 * 512;
    unsigned short* a1Hi = wsU;
    unsigned short* a1Lo = a1Hi + 3 * A1F;
    unsigned short* m1Hi = a1Lo + 3 * A1F;
    unsigned short* m1Lo = m1Hi + 3 * M1F;
    unsigned short* m2Hi = m1Lo + 3 * M1F;
    unsigned short* m2Lo = m2Hi + 3 * M2F;
    int* cursor = (int*)(m2Lo + 3 * M2F);                // NN ints
    int* perm   = cursor + FGK_NN;                       // NE ints
    int* srcP   = perm + FGK_NE;                         // NE ints (perm-ordered src)
    int* dstP   = srcP + FGK_NE;                         // NE ints (perm-ordered dst)
    unsigned short* hinB = (unsigned short*)(dstP + FGK_NE);   // NN*128 bf16
    unsigned short* eaP  = hinB + (size_t)FGK_NN * FGK_H;      // NE*128 bf16 (82 MB)

    // dst-sorted edge permutation (edge_index constant; rebuilt every launch)
    fgkZeroI<<<(FGK_NN + 255) / 256, 256, 0, stream>>>(cursor, FGK_NN);
    fgkHist<<<(FGK_NE + 255) / 256, 256, 0, stream>>>(dstIdx, cursor);
    fgkScan<<<1, 1024, 0, stream>>>(cursor, cursor);     // in-place exclusive scan
    fgkScatterE<<<(FGK_NE + 255) / 256, 256, 0, stream>>>(dstIdx, srcIdx, cursor,
                                                          perm, srcP, dstP);
    // one-time layer-invariant edge encoding, perm-ordered bf16
    fgkEncE<<<FGK_NE / 16, 256, 0, stream>>>(eatt, perm, eEw, eEb, eaP);

    for (int l = 0; l < 3; l++) {
        fgkPrepW<<<40, 64, 0, stream>>>(a1w + (size_t)l * FGK_H * FGK_F, 128, 152,
                                        a1Hi + l * A1F, a1Lo + l * A1F);
        fgkPrepW<<<64, 64, 0, stream>>>(m1w + (size_t)l * FGK_H * 256, 128, 256,
                                        m1Hi + l * M1F, m1Lo + l * M1F);
        fgkPrepW<<<64, 64, 0, stream>>>(m2w + (size_t)l * 256 * FGK_H, 256, 128,
                                        m2Hi + l * M2F, m2Lo + l * M2F);
    }
    fgkEnc<<<(FGK_NN * FGK_H + 255) / 256, 256, 0, stream>>>(xin, nEw, nEb, hin, hinB);
    for (int l = 0; l < 3; l++) {
        fgkZero<<<(FGK_NN * (FGK_P + FGK_TRI) + 255) / 256, 256, 0, stream>>>(snA);
        fgkEdge<<<FGK_NE / FGK_EPB, 512, 0, stream>>>(srcP, dstP, eaP,
            a1Hi + l * A1F, a1Lo + l * A1F, a1b + (size_t)l * FGK_F, hinB, snA, fnA);
        fgkSolve<<<(FGK_NN + 63) / 64, 64, 0, stream>>>(snA, fnA, mle);
        fgkNode<<<FGK_NN / 16, 256, 0, stream>>>(hin, mle,
            a2w + (size_t)l * FGK_P * FGK_H, a2b + (size_t)l * FGK_H,
            m1Hi + l * M1F, m1Lo + l * M1F, m1b + (size_t)l * 256,
            lng + (size_t)l * 256, lnb + (size_t)l * 256,
            m2Hi + l * M2F, m2Lo + l * M2F, m2b + (size_t)l * FGK_H,
            hAcc, l > 0 ? 1 : 0,
            hin, hinB, ng + (l + 1) * FGK_H, nb + (l + 1) * FGK_H, l < 2 ? 1 : 0);
    }
    fgkFinal<<<FGK_NN, FGK_H, 0, stream>>>(hAcc, ng, nb, lw, lb, outp);
}

// Round 12
// 781.347 us; speedup vs baseline: 1.0693x; 1.0186x over previous
//
#include <hip/hip_runtime.h>
#include <cmath>
#include <cstddef>

#define FGK_NN   20000
#define FGK_NE   320000
#define FGK_H    128
#define FGK_P    16
#define FGK_TRI  136
#define FGK_F    152
#define FGK_EPB  32
#define FGK_YP   156          // sY row stride (>=152, 16B-aligned rows, 28 mod 32)

typedef short  s16x8 __attribute__((ext_vector_type(8)));
typedef float  f32x4 __attribute__((ext_vector_type(4)));

__device__ __forceinline__ unsigned short fgk_f2b(float f) {   // RNE f32->bf16 (native cvt)
    __bf16 b = (__bf16)f;
    return __builtin_bit_cast(unsigned short, b);
}
__device__ __forceinline__ float fgk_u2f(unsigned short u) {
    return __uint_as_float(((unsigned int)u) << 16);
}
// bank-conflict swizzles on 16B-unit index (bijective XOR of high bits into group bits)
__device__ __forceinline__ int fgk_sw(int u)  { return u ^ ((u >> 4) & 7); }  // node-kernel pattern
__device__ __forceinline__ int fgk_swL(int u) { return u ^ ((u >> 5) & 7); }  // edge-kernel pattern

__global__ void FishnetGCN_62096637165586_kernel() {}

__global__ void fgkZero(float* acc) {
    int i = blockIdx.x * blockDim.x + threadIdx.x;
    if (i < FGK_NN * (FGK_P + FGK_TRI)) acc[i] = 0.f;
}
__global__ void fgkZeroI(int* p, int n) {
    int i = blockIdx.x * blockDim.x + threadIdx.x;
    if (i < n) p[i] = 0;
}
// ---- dst-sort: histogram -> block scan -> scatter (edge_index constant) ----
__global__ void fgkHist(const int* __restrict__ dst, int* __restrict__ hist) {
    int e = blockIdx.x * blockDim.x + threadIdx.x;
    if (e < FGK_NE) atomicAdd(&hist[dst[e]], 1);
}
__global__ void fgkScan(const int* __restrict__ hist, int* __restrict__ cursor)
{
    __shared__ int sWave[16];
    __shared__ int sRun;
    int t = threadIdx.x;             // 1024
    int lane = t & 63, wv = t >> 6;
    if (t == 0) sRun = 0;
    __syncthreads();
    for (int base = 0; base < FGK_NN; base += 1024) {
        int idx = base + t;
        int v = (idx < FGK_NN) ? hist[idx] : 0;
        int sc = v;
#pragma unroll
        for (int off = 1; off < 64; off <<= 1) {
            int u = __shfl_up(sc, off);
            if (lane >= off) sc += u;
        }
        if (lane == 63) sWave[wv] = sc;
        __syncthreads();
        if (wv == 0 && lane < 16) {
            int w = sWave[lane];
#pragma unroll
            for (int off = 1; off < 16; off <<= 1) {
                int u = __shfl_up(w, off, 16);
                if (lane >= off) w += u;
            }
            sWave[lane] = w;
        }
        __syncthreads();
        int waveOff = (wv == 0) ? 0 : sWave[wv - 1];
        int run = sRun;
        if (idx < FGK_NN) cursor[idx] = run + waveOff + sc - v;   // exclusive
        __syncthreads();
        if (t == 1023) sRun = run + sWave[15];
        __syncthreads();
    }
}
// scatter + emit perm-ordered src/dst arrays (removes double-indirection later)
__global__ void fgkScatterE(const int* __restrict__ dst, const int* __restrict__ src,
                            int* __restrict__ cursor, int* __restrict__ perm,
                            int* __restrict__ srcP, int* __restrict__ dstP) {
    int e = blockIdx.x * blockDim.x + threadIdx.x;
    if (e < FGK_NE) {
        int d = dst[e];
        int pos = atomicAdd(&cursor[d], 1);
        perm[pos] = e;
        srcP[pos] = src[e];
        dstP[pos] = d;
    }
}

// One-time, layer-invariant: eaP[pos] = bf16(eatt[perm[pos]] @ eew + eeb), perm order.
// 256 threads: thread = (pos in 16-group, 8-col group)
__global__ void fgkEncE(const float* __restrict__ eatt,
                        const int* __restrict__ perm,
                        const float* __restrict__ eew,
                        const float* __restrict__ eeb,
                        unsigned short* __restrict__ eaP)
{
    int pos = blockIdx.x * 16 + (threadIdx.x >> 4);
    int b = threadIdx.x & 15;
    int e = perm[pos];
    const float4* ap = (const float4*)(eatt + (size_t)e * 8);
    float4 a0 = ap[0], a1 = ap[1];
    float av[8] = {a0.x, a0.y, a0.z, a0.w, a1.x, a1.y, a1.z, a1.w};
    const float4* bp = (const float4*)(eeb + b * 8);
    float4 b0 = bp[0], b1 = bp[1];
    float acc[8] = {b0.x, b0.y, b0.z, b0.w, b1.x, b1.y, b1.z, b1.w};
#pragma unroll
    for (int kk = 0; kk < 8; ++kk) {
        const float4* wp = (const float4*)(eew + kk * FGK_H + b * 8);
        float4 w0 = wp[0], w1 = wp[1];
        acc[0] += av[kk] * w0.x; acc[1] += av[kk] * w0.y;
        acc[2] += av[kk] * w0.z; acc[3] += av[kk] * w0.w;
        acc[4] += av[kk] * w1.x; acc[5] += av[kk] * w1.y;
        acc[6] += av[kk] * w1.z; acc[7] += av[kk] * w1.w;
    }
    s16x8 r;
#pragma unroll
    for (int jj = 0; jj < 8; ++jj) r[jj] = (short)fgk_f2b(acc[jj]);
    *(s16x8*)&eaP[(size_t)pos * FGK_H + b * 8] = r;
}

// Generic prepack of W[K,N] (row-major) into MFMA B-fragment order, bf16 hi/lo.
__global__ void fgkPrepW(const float* __restrict__ W, int K, int N,
                         unsigned short* __restrict__ hi,
                         unsigned short* __restrict__ lo)
{
    int chunks = K >> 5;
    int b = blockIdx.x;
    int nt = b / chunks, c = b - nt * chunks;
    int lane = threadIdx.x;
    int n = nt * 16 + (lane & 15);
    int g = lane >> 4;
    size_t base = ((size_t)b * 64 + lane) * 8;
#pragma unroll
    for (int j = 0; j < 8; ++j) {
        int k = c * 32 + g * 8 + j;
        float v = (n < N) ? W[(size_t)k * N + n] : 0.f;
        unsigned short hb = fgk_f2b(v);
        unsigned short lb = fgk_f2b(v - fgk_u2f(hb));
        hi[base + j] = hb;
        lo[base + j] = lb;
    }
}

// hin = x @ W[8,128] + b   (f32 + bf16 gather copy)
__global__ void fgkEnc(const float* __restrict__ xin,
                       const float* __restrict__ wenc,
                       const float* __restrict__ benc,
                       float* __restrict__ hin,
                       unsigned short* __restrict__ hinB)
{
    int idx = blockIdx.x * blockDim.x + threadIdx.x;
    if (idx >= FGK_NN * FGK_H) return;
    int n = idx >> 7, j = idx & 127;
    float acc = benc[j];
    const float* xp = xin + (size_t)n * 8;
#pragma unroll
    for (int k = 0; k < 8; k++) acc += xp[k] * wenc[k * FGK_H + j];
    hin[idx] = acc;
    hinB[idx] = fgk_f2b(acc);
}

// edge (sorted by dst), 32 edges/block, 512 threads:
// bf16 hin gather + streamed eaP -> msg (A hi only) ; y=MFMA (2 mfma/c) ;
// L-build + inline diag softplus + score-reduce ; Fe=MFMA (dual) ; tri-reduce
__global__ void __launch_bounds__(512, 4)
fgkEdge(const int* __restrict__ srcP,
        const int* __restrict__ dstP,
        const unsigned short* __restrict__ eaP,
        const unsigned short* __restrict__ bHi,
        const unsigned short* __restrict__ bLo,
        const float* __restrict__ a1b,
        const unsigned short* __restrict__ hinB,
        float* __restrict__ snAcc,
        float* __restrict__ fnAcc)
{
    __shared__ float uni[8192];                   // 32 KB: aH (8K), then lH/lL (32K)
    __shared__ float sY[FGK_EPB][FGK_YP];         // y, later overlaid by sTri
    __shared__ int sSrc[FGK_EPB], sDst[FGK_EPB];
    __shared__ int sStart[FGK_EPB], sEnd[FGK_EPB], sDstSlot[FGK_EPB];
    __shared__ int sNS;
    unsigned short* aH = (unsigned short*)uni;            // 4096 us (8 KB)
    unsigned short* lH = (unsigned short*)uni;            // 8192 us (after reuse)
    unsigned short* lL = (unsigned short*)uni + 8192;     // 8192 us
    float* sTri = (float*)sY;                             // 4352-float overlay (<4992)
    int t = threadIdx.x;                          // 512 threads, 8 waves
    int lane = t & 63, wave = t >> 6;
    int e0 = blockIdx.x * FGK_EPB;

    if (wave == 0) {                              // meta load + parallel slot detect
        int sv = 0, dv = 0x7fffffff;
        if (lane < FGK_EPB) {
            sv = srcP[e0 + lane];
            dv = dstP[e0 + lane];
            sSrc[lane] = sv; sDst[lane] = dv;
        }
        int prev = __shfl_up(dv, 1);
        bool isStart = (lane < FGK_EPB) && (lane == 0 || dv != prev);
        unsigned long long mask = __ballot(isStart);
        int ns = __popcll(mask);
        if (isStart) {
            int s = (int)__popcll(mask & ((1ull << lane) - 1ull));
            sStart[s] = lane;
            sDstSlot[s] = dv;
            if (lane) sEnd[s - 1] = lane;
        }
        if (lane == 0) { sNS = ns; sEnd[ns - 1] = FGK_EPB; }
    }
    __syncthreads();                              // bar 1

    // ---- msg = relu(hinB[src] + eaP) + 1e-7 -> bf16 A-frags (hi only; both
    //      addends are already bf16 so the lo residual is sub-dominant) ----
    {
        int el = t >> 4, b = t & 15;
        s16x8 hraw = *(const s16x8*)(hinB + (size_t)sSrc[el] * FGK_H + b * 8);
        s16x8 eraw = *(const s16x8*)(eaP + (size_t)(e0 + el) * FGK_H + b * 8);
        s16x8 hb;
#pragma unroll
        for (int jj = 0; jj < 8; ++jj) {
            float hv = fgk_u2f((unsigned short)hraw[jj]);
            float ev = fgk_u2f((unsigned short)eraw[jj]);
            float m = fmaxf(hv + ev, 0.f) + 1e-7f;
            hb[jj] = (short)fgk_f2b(m);
        }
        int c = b >> 2, g = b & 3;                // k = b*8+jj = 32c+8g+jj
        int idx = fgk_swL(c * 128 + 32 * g + el) * 8;
        *(s16x8*)&aH[idx] = hb;
    }
    __syncthreads();                              // bar 2

    // ---- y = msg @ a1w via MFMA (A hi-only, B dual): 2 mfma per c ----
    {
        int et = wave & 1;
        s16x8 ah[4];
#pragma unroll
        for (int c = 0; c < 4; ++c) {
            int idx = fgk_swL(c * 128 + 32 * (lane >> 4) + 16 * et + (lane & 15)) * 8;
            ah[c] = *(const s16x8*)&aH[idx];
        }
        int n = lane & 15, qd = lane >> 4;
        for (int nt = (wave >> 1); nt < 10; nt += 4) {
            f32x4 acc = {0.f, 0.f, 0.f, 0.f};
#pragma unroll
            for (int c = 0; c < 4; ++c) {
                size_t bidx = ((size_t)(nt * 4 + c) * 64 + lane) * 8;
                s16x8 bh = *(const s16x8*)(bHi + bidx);
                s16x8 bl = *(const s16x8*)(bLo + bidx);
                acc = __builtin_amdgcn_mfma_f32_16x16x32_bf16(ah[c], bl, acc, 0, 0, 0);
                acc = __builtin_amdgcn_mfma_f32_16x16x32_bf16(ah[c], bh, acc, 0, 0, 0);
            }
            int j = nt * 16 + n;
            if (j < FGK_F) {                       // GUARD: pad cols must not wrap
                float bias = a1b[j];
#pragma unroll
                for (int reg = 0; reg < 4; ++reg)
                    sY[16 * et + 4 * qd + reg][j] = acc[reg] + bias;
            }
        }
    }
    __syncthreads();                              // bar 3 (sY done; aH dead)

    // ---- L build (vectorized half-rows, diag softplus inline)
    //      + independent per-slot score reduction/atomics (reads sY only) ----
    {
#pragma unroll
        for (int it = 0; it < 2; ++it) {
            int s = t + it * 512;            // 1024 slots: el(32) x r(32)
            int el = s & 31;
            int r  = s >> 5;                 // 0..31
            int i  = r & 15, h = r >> 4;
            int pstart = 16 * i + 8 * h;
            float v[8];
            if (pstart < 120) {              // q = p+16 ascending
                const float4* rp = (const float4*)&sY[el][32 + pstart];
                float4 v0 = rp[0], v1 = rp[1];
                v[0] = v0.x; v[1] = v0.y; v[2] = v0.z; v[3] = v0.w;
                v[4] = v1.x; v[5] = v1.y; v[6] = v1.z; v[7] = v1.w;
            } else {                         // q = 255-p descending
                const float4* rp = (const float4*)&sY[el][264 - pstart];
                float4 v0 = rp[0], v1 = rp[1];
                v[0] = v1.w; v[1] = v1.z; v[2] = v1.y; v[3] = v1.x;
                v[4] = v0.w; v[5] = v0.z; v[6] = v0.y; v[7] = v0.x;
            }
            if (h == (i >> 3)) {             // slot holds the diag elem at i&7
                int jd = i & 7;
                float d0 = v[jd];
                // softplus via HW exp2/log2 (sub-bf16-ulp accurate)
                v[jd] = fmaxf(d0, 0.f) +
                        0.69314718f * log2f(1.f + exp2f(-1.44269504f * fabsf(d0)));
            }
            s16x8 hb, lb;
#pragma unroll
            for (int jj = 0; jj < 8; ++jj) {
                unsigned short hbv = fgk_f2b(v[jj]);
                hb[jj] = (short)hbv;
                lb[jj] = (short)fgk_f2b(v[jj] - fgk_u2f(hbv));
            }
            int idx = fgk_swL(el * 32 + i + 16 * h) * 8;
            *(s16x8*)&lH[idx] = hb;
            *(s16x8*)&lL[idx] = lb;
        }
        int el = t >> 4, d = t & 15;         // per-slot score reduce (sY readers)
        if (el < sNS) {
            float sum = 0.f;
            for (int e2 = sStart[el]; e2 < sEnd[el]; ++e2) sum += sY[e2][d];
            atomicAdd(&snAcc[(size_t)sDstSlot[el] * FGK_P + d], sum);
        }
    }
    __syncthreads();                              // bar 4 (lH/lL done; sY free)

    // ---- Fe = L L^T via MFMA (dual precision); park lower tri in LDS ----
#pragma unroll
    for (int i4 = 0; i4 < 4; ++i4) {
        int el = wave * 4 + i4;              // 0..31
        s16x8 fh = {0, 0, 0, 0, 0, 0, 0, 0};
        s16x8 fl = {0, 0, 0, 0, 0, 0, 0, 0};
        if (lane < 32) {
            int idx = fgk_swL(el * 32 + lane) * 8;
            fh = *(const s16x8*)&lH[idx];
            fl = *(const s16x8*)&lL[idx];
        }
        f32x4 acc = {0.f, 0.f, 0.f, 0.f};
        acc = __builtin_amdgcn_mfma_f32_16x16x32_bf16(fh, fh, acc, 0, 0, 0);
        acc = __builtin_amdgcn_mfma_f32_16x16x32_bf16(fh, fl, acc, 0, 0, 0);
        acc = __builtin_amdgcn_mfma_f32_16x16x32_bf16(fl, fh, acc, 0, 0, 0);
        int j = lane & 15, qd = lane >> 4;
#pragma unroll
        for (int reg = 0; reg < 4; ++reg) {
            int ii = 4 * qd + reg;
            if (ii >= j) sTri[el * FGK_TRI + ii * (ii + 1) / 2 + j] = acc[reg];
        }
    }
    __syncthreads();                              // bar 5

    // ---- per-slot tri reduction -> coalesced atomics ----
    {
        int nS = sNS;
        for (int o = t; o < nS * FGK_TRI; o += 512) {
            int s = o / FGK_TRI, p = o - s * FGK_TRI;
            float sum = 0.f;
            for (int el = sStart[s]; el < sEnd[s]; ++el) sum += sTri[el * FGK_TRI + p];
            atomicAdd(&fnAcc[(size_t)sDstSlot[s] * FGK_TRI + p], sum);
        }
    }
}

// one thread per node: fully-unrolled register Cholesky solve of (F_n+I) x = s_n
// 64-thread blocks: 313 workgroups spread over all 256 CUs
#define TA(i, j) a[(i) * ((i) + 1) / 2 + (j)]
__global__ void __launch_bounds__(64)
fgkSolve(const float* __restrict__ snAcc,
         const float* __restrict__ fnAcc,
         float* __restrict__ mleOut)
{
    int n = blockIdx.x * blockDim.x + threadIdx.x;
    if (n >= FGK_NN) return;
    float a[FGK_TRI];
    const float4* src = (const float4*)(fnAcc + (size_t)n * FGK_TRI);
#pragma unroll
    for (int p = 0; p < FGK_TRI / 4; ++p) {
        float4 v = src[p];
        a[p * 4] = v.x; a[p * 4 + 1] = v.y; a[p * 4 + 2] = v.z; a[p * 4 + 3] = v.w;
    }
#pragma unroll
    for (int i = 0; i < 16; ++i) TA(i, i) += 1.f;
#pragma unroll
    for (int k = 0; k < 16; ++k) {
        float d = sqrtf(TA(k, k));
        float inv = 1.f / d;
        TA(k, k) = d;
#pragma unroll
        for (int i = k + 1; i < 16; ++i) TA(i, k) *= inv;
#pragma unroll
        for (int j = k + 1; j < 16; ++j) {
            float ajk = TA(j, k);
#pragma unroll
            for (int i = j; i < 16; ++i) TA(i, j) -= TA(i, k) * ajk;
        }
    }
    const float* sp = snAcc + (size_t)n * FGK_P;
    float y[16], x[16];
#pragma unroll
    for (int i = 0; i < 16; ++i) {
        float acc = sp[i];
#pragma unroll
        for (int k = 0; k < 16; ++k) if (k < i) acc -= TA(i, k) * y[k];
        y[i] = acc / TA(i, i);
    }
#pragma unroll
    for (int i = 15; i >= 0; --i) {
        float acc = y[i];
#pragma unroll
        for (int k = 0; k < 16; ++k) if (k > i) acc -= TA(k, i) * x[k];
        x[i] = acc / TA(i, i);
    }
    float4* dst = (float4*)(mleOut + (size_t)n * FGK_P);
#pragma unroll
    for (int p = 0; p < 4; ++p) dst[p] = make_float4(x[p * 4], x[p * 4 + 1], x[p * 4 + 2], x[p * 4 + 3]);
}
#undef TA

// node (16 nodes/block): a2+res -> m1 MFMA -> LN -> m2 MFMA -> hout
// + fused next-layer relu(LN(hout)) -> hinNext f32 + bf16 (doNext)
__global__ void __launch_bounds__(256)
fgkNode(const float* __restrict__ hin,
        const float* __restrict__ mleIn,
        const float* __restrict__ a2w, const float* __restrict__ a2b,
        const unsigned short* __restrict__ m1H, const unsigned short* __restrict__ m1L,
        const float* __restrict__ m1b,
        const float* __restrict__ gamma, const float* __restrict__ beta,
        const unsigned short* __restrict__ m2H, const unsigned short* __restrict__ m2L,
        const float* __restrict__ m2b,
        float* __restrict__ hout, int addres,
        float* __restrict__ hinNext, unsigned short* __restrict__ hinNextB,
        const float* __restrict__ gN, const float* __restrict__ bN, int doNext)
{
    __shared__ char uniN[16384];
    __shared__ float sT[16][260];
    __shared__ float stats[16][2];
    unsigned short* ovH = (unsigned short*)uniN;
    unsigned short* ovL = (unsigned short*)uniN + 2048;
    unsigned short* t2H = (unsigned short*)uniN;
    unsigned short* t2L = (unsigned short*)uniN + 4096;
    int t = threadIdx.x, lane = t & 63, wave = t >> 6;
    int n0 = blockIdx.x * 16;

    // ---- a2 matvec + residual -> bf16 hi/lo frags (one pass, vectorized) ----
    {
        int node = t >> 4, cg = t & 15;            // 8 cols per thread
        const float4* m4 = (const float4*)(mleIn + (size_t)(n0 + node) * FGK_P);
        float4 q0 = m4[0], q1 = m4[1], q2 = m4[2], q3 = m4[3];
        float mv[16] = {q0.x, q0.y, q0.z, q0.w, q1.x, q1.y, q1.z, q1.w,
                        q2.x, q2.y, q2.z, q2.w, q3.x, q3.y, q3.z, q3.w};
        const float4* bp = (const float4*)(a2b + cg * 8);
        float4 b0 = bp[0], b1 = bp[1];
        const float4* hp = (const float4*)(hin + (size_t)(n0 + node) * FGK_H + cg * 8);
        float4 h0 = hp[0], h1 = hp[1];
        float acc[8] = {b0.x + h0.x, b0.y + h0.y, b0.z + h0.z, b0.w + h0.w,
                        b1.x + h1.x, b1.y + h1.y, b1.z + h1.z, b1.w + h1.w};
#pragma unroll
        for (int k = 0; k < 16; ++k) {
            const float4* wp = (const float4*)(a2w + k * FGK_H + cg * 8);
            float4 w0 = wp[0], w1 = wp[1];
            acc[0] += mv[k] * w0.x; acc[1] += mv[k] * w0.y;
            acc[2] += mv[k] * w0.z; acc[3] += mv[k] * w0.w;
            acc[4] += mv[k] * w1.x; acc[5] += mv[k] * w1.y;
            acc[6] += mv[k] * w1.z; acc[7] += mv[k] * w1.w;
        }
        s16x8 hb, lb;
#pragma unroll
        for (int jj = 0; jj < 8; ++jj) {
            unsigned short hbv = fgk_f2b(acc[jj]);
            hb[jj] = (short)hbv;
            lb[jj] = (short)fgk_f2b(acc[jj] - fgk_u2f(hbv));
        }
        int idx = fgk_sw(cg * 16 + node) * 8;      // u = c*64+16g+node = 16*cg+node
        *(s16x8*)&ovH[idx] = hb;
        *(s16x8*)&ovL[idx] = lb;
    }
    __syncthreads();

    {
        s16x8 ah[4], al[4];
#pragma unroll
        for (int c = 0; c < 4; ++c) {
            int idx = fgk_sw(c * 64 + lane) * 8;
            ah[c] = *(const s16x8*)&ovH[idx];
            al[c] = *(const s16x8*)&ovL[idx];
        }
        int n = lane & 15, qd = lane >> 4;
#pragma unroll
        for (int i4 = 0; i4 < 4; ++i4) {
            int nt = wave + i4 * 4;
            f32x4 acc = {0.f, 0.f, 0.f, 0.f};
#pragma unroll
            for (int c = 0; c < 4; ++c) {
                size_t bidx = ((size_t)(nt * 4 + c) * 64 + lane) * 8;
                s16x8 bh = *(const s16x8*)(m1H + bidx);
                s16x8 bl = *(const s16x8*)(m1L + bidx);
                acc = __builtin_amdgcn_mfma_f32_16x16x32_bf16(al[c], bh, acc, 0, 0, 0);
                acc = __builtin_amdgcn_mfma_f32_16x16x32_bf16(ah[c], bl, acc, 0, 0, 0);
                acc = __builtin_amdgcn_mfma_f32_16x16x32_bf16(ah[c], bh, acc, 0, 0, 0);
            }
            int j = nt * 16 + n;
            float bias = m1b[j];
#pragma unroll
            for (int reg = 0; reg < 4; ++reg)
                sT[4 * qd + reg][j] = acc[reg] + bias;
        }
    }
    __syncthreads();

    {
        int node = t >> 4, seg = t & 15;
        const float* rowp = &sT[node][seg * 16];
        float s1 = 0.f, s2 = 0.f;
#pragma unroll
        for (int k = 0; k < 16; ++k) { float v = rowp[k]; s1 += v; s2 += v * v; }
#pragma unroll
        for (int off = 8; off; off >>= 1) {
            s1 += __shfl_down(s1, off, 16);
            s2 += __shfl_down(s2, off, 16);
        }
        if (seg == 0) {
            float mu = s1 * (1.f / 256.f);
            float var = s2 * (1.f / 256.f) - mu * mu;
            stats[node][0] = mu;
            stats[node][1] = rsqrtf(var + 1e-5f);
        }
    }
    __syncthreads();

    // ---- LN + relu -> bf16 hi/lo frags (vectorized, swizzled b128 stores) ----
    {
        int node = t >> 4;
        float mu = stats[node][0], rstd = stats[node][1];
#pragma unroll
        for (int h = 0; h < 2; ++h) {
            int cg = (t & 15) + 16 * h;            // 0..31, 8 cols each
            const float4* rp = (const float4*)&sT[node][cg * 8];
            float4 v0 = rp[0], v1 = rp[1];
            const float4* gp = (const float4*)(gamma + cg * 8);
            float4 g0 = gp[0], g1 = gp[1];
            const float4* bb = (const float4*)(beta + cg * 8);
            float4 e0 = bb[0], e1 = bb[1];
            float vv[8] = {v0.x, v0.y, v0.z, v0.w, v1.x, v1.y, v1.z, v1.w};
            float gg[8] = {g0.x, g0.y, g0.z, g0.w, g1.x, g1.y, g1.z, g1.w};
            float ee[8] = {e0.x, e0.y, e0.z, e0.w, e1.x, e1.y, e1.z, e1.w};
            s16x8 hb, lb;
#pragma unroll
            for (int jj = 0; jj < 8; ++jj) {
                float tv = fmaxf((vv[jj] - mu) * rstd * gg[jj] + ee[jj], 0.f);
                unsigned short hbv = fgk_f2b(tv);
                hb[jj] = (short)hbv;
                lb[jj] = (short)fgk_f2b(tv - fgk_u2f(hbv));
            }
            int idx = fgk_sw(cg * 16 + node) * 8;
            *(s16x8*)&t2H[idx] = hb;
            *(s16x8*)&t2L[idx] = lb;
        }
    }
    __syncthreads();

    {
        s16x8 ah[8], al[8];
#pragma unroll
        for (int c = 0; c < 8; ++c) {
            int idx = fgk_sw(c * 64 + lane) * 8;
            ah[c] = *(const s16x8*)&t2H[idx];
            al[c] = *(const s16x8*)&t2L[idx];
        }
        int n = lane & 15, qd = lane >> 4;
#pragma unroll
        for (int i2 = 0; i2 < 2; ++i2) {
            int nt = wave * 2 + i2;
            f32x4 acc = {0.f, 0.f, 0.f, 0.f};
#pragma unroll
            for (int c = 0; c < 8; ++c) {
                size_t bidx = ((size_t)(nt * 8 + c) * 64 + lane) * 8;
                s16x8 bh = *(const s16x8*)(m2H + bidx);
                s16x8 bl = *(const s16x8*)(m2L + bidx);
                acc = __builtin_amdgcn_mfma_f32_16x16x32_bf16(al[c], bh, acc, 0, 0, 0);
                acc = __builtin_amdgcn_mfma_f32_16x16x32_bf16(ah[c], bl, acc, 0, 0, 0);
                acc = __builtin_amdgcn_mfma_f32_16x16x32_bf16(ah[c], bh, acc, 0, 0, 0);
            }
            int j = nt * 16 + n;
            float bias = m2b[j];
#pragma unroll
            for (int reg = 0; reg < 4; ++reg) {
                int node = 4 * qd + reg;
                size_t idx = (size_t)(n0 + node) * FGK_H + j;
                float val = acc[reg] + bias;
                float nv = addres ? (hout[idx] + val) : val;
                hout[idx] = nv;
                sT[node][j] = nv;          // park for fused next-layer LN
            }
        }
    }
    if (doNext) {                          // hinNext = relu(LN(hout, gN, bN))
        __syncthreads();
        int node = t >> 4, seg = t & 15;
        const float* rowp = &sT[node][seg * 8];
        float s1 = 0.f, s2 = 0.f;
#pragma unroll
        for (int k = 0; k < 8; ++k) { float v = rowp[k]; s1 += v; s2 += v * v; }
#pragma unroll
        for (int off = 8; off; off >>= 1) {
            s1 += __shfl_down(s1, off, 16);
            s2 += __shfl_down(s2, off, 16);
        }
        if (seg == 0) {
            float mu = s1 * (1.f / 128.f);
            float var = s2 * (1.f / 128.f) - mu * mu;
            stats[node][0] = mu;
            stats[node][1] = rsqrtf(var + 1e-5f);
        }
        __syncthreads();
        float mu = stats[node][0], rstd = stats[node][1];
#pragma unroll
        for (int kk = 0; kk < 8; ++kk) {
            int k = seg * 8 + kk;
            float v = sT[node][k];
            float nv = fmaxf((v - mu) * rstd * gN[k] + bN[k], 0.f);
            size_t oidx = (size_t)(n0 + node) * FGK_H + k;
            hinNext[oidx] = nv;
            hinNextB[oidx] = fgk_f2b(nv);
        }
    }
}

// out = relu(LN(h, g0, b0)) @ lin_w + lin_b   (f32 out)
__global__ void fgkFinal(const float* __restrict__ hsrc,
                         const float* __restrict__ gamma,
                         const float* __restrict__ beta,
                         const float* __restrict__ lw,
                         const float* __restrict__ lb,
                         float* __restrict__ outp)
{
    int n = blockIdx.x, t = threadIdx.x;   // block = 128
    __shared__ float tt[FGK_H];
    __shared__ float red[4];
    float v = hsrc[(size_t)n * FGK_H + t];
    float s1 = v, s2 = v * v;
#pragma unroll
    for (int off = 32; off; off >>= 1) { s1 += __shfl_down(s1, off); s2 += __shfl_down(s2, off); }
    int wid = t >> 6, lane = t & 63;
    if (lane == 0) { red[wid] = s1; red[2 + wid] = s2; }
    __syncthreads();
    float mu = (red[0] + red[1]) * (1.f / FGK_H);
    float var = (red[2] + red[3]) * (1.f / FGK_H) - mu * mu;
    float rstd = rsqrtf(var + 1e-5f);
    tt[t] = fmaxf((v - mu) * rstd * gamma[t] + beta[t], 0.f);
    __syncthreads();
    if (t < 112) {
        float acc = lb[t];
        for (int k = 0; k < FGK_H; k++) acc += tt[k] * lw[k * 112 + t];
        outp[(size_t)n * 112 + t] = acc;
    }
}

extern "C" void kernel_launch(void* const* d_in, const int* in_sizes, int n_in,
                              void* d_out, int out_size, void* d_ws, size_t ws_size,
                              hipStream_t stream)
{
    const float* xin  = (const float*)d_in[0];
    const float* eatt = (const float*)d_in[1];
    const int*   eidx = (const int*)d_in[2];
    const float* nEw  = (const float*)d_in[3];
    const float* nEb  = (const float*)d_in[4];
    const float* eEw  = (const float*)d_in[5];
    const float* eEb  = (const float*)d_in[6];
    const float* a1w  = (const float*)d_in[7];
    const float* a1b  = (const float*)d_in[8];
    const float* a2w  = (const float*)d_in[9];
    const float* a2b  = (const float*)d_in[10];
    const float* m1w  = (const float*)d_in[11];
    const float* m1b  = (const float*)d_in[12];
    const float* lng  = (const float*)d_in[13];
    const float* lnb  = (const float*)d_in[14];
    const float* m2w  = (const float*)d_in[15];
    const float* m2b  = (const float*)d_in[16];
    const float* ng   = (const float*)d_in[17];
    const float* nb   = (const float*)d_in[18];
    const float* lw   = (const float*)d_in[19];
    const float* lb   = (const float*)d_in[20];
    float* outp = (float*)d_out;
    const int* srcIdx = eidx;
    const int* dstIdx = eidx + FGK_NE;

    float* ws   = (float*)d_ws;
    float* hAcc = ws;                                    // NN*128
    float* hin  = hAcc + (size_t)FGK_NN * FGK_H;         // NN*128
    float* snA  = hin  + (size_t)FGK_NN * FGK_H;         // NN*16
    float* fnA  = snA  + (size_t)FGK_NN * FGK_P;         // NN*136
    float* mle  = fnA  + (size_t)FGK_NN * FGK_TRI;       // NN*16
    unsigned short* wsU = (unsigned short*)(mle + (size_t)FGK_NN * FGK_P);
    const int A1F = 40 * 512, M1F = 64 * 512, M2F = 64 * 512;
    unsigned short* a1Hi = wsU;
    unsigned short* a1Lo = a1Hi + 3 * A1F;
    unsigned short* m1Hi = a1Lo + 3 * A1F;
    unsigned short* m1Lo = m1Hi + 3 * M1F;
    unsigned short* m2Hi = m1Lo + 3 * M1F;
    unsigned short* m2Lo = m2Hi + 3 * M2F;
    int* cursor = (int*)(m2Lo + 3 * M2F);                // NN ints
    int* perm   = cursor + FGK_NN;                       // NE ints
    int* srcP   = perm + FGK_NE;                         // NE ints (perm-ordered src)
    int* dstP   = srcP + FGK_NE;                         // NE ints (perm-ordered dst)
    unsigned short* hinB = (unsigned short*)(dstP + FGK_NE);   // NN*128 bf16
    unsigned short* eaP  = hinB + (size_t)FGK_NN * FGK_H;      // NE*128 bf16 (82 MB)

    // dst-sorted edge permutation (edge_index constant; rebuilt every launch)
    fgkZeroI<<<(FGK_NN + 255) / 256, 256, 0, stream>>>(cursor, FGK_NN);
    fgkHist<<<(FGK_NE + 255) / 256, 256, 0, stream>>>(dstIdx, cursor);
    fgkScan<<<1, 1024, 0, stream>>>(cursor, cursor);     // in-place exclusive scan
    fgkScatterE<<<(FGK_NE + 255) / 256, 256, 0, stream>>>(dstIdx, srcIdx, cursor,
                                                          perm, srcP, dstP);
    // one-time layer-invariant edge encoding, perm-ordered bf16
    fgkEncE<<<FGK_NE / 16, 256, 0, stream>>>(eatt, perm, eEw, eEb, eaP);

    for (int l = 0; l < 3; l++) {
        fgkPrepW<<<40, 64, 0, stream>>>(a1w + (size_t)l * FGK_H * FGK_F, 128, 152,
                                        a1Hi + l * A1F, a1Lo + l * A1F);
        fgkPrepW<<<64, 64, 0, stream>>>(m1w + (size_t)l * FGK_H * 256, 128, 256,
                                        m1Hi + l * M1F, m1Lo + l * M1F);
        fgkPrepW<<<64, 64, 0, stream>>>(m2w + (size_t)l * 256 * FGK_H, 256, 128,
                                        m2Hi + l * M2F, m2Lo + l * M2F);
    }
    fgkEnc<<<(FGK_NN * FGK_H + 255) / 256, 256, 0, stream>>>(xin, nEw, nEb, hin, hinB);
    for (int l = 0; l < 3; l++) {
        fgkZero<<<(FGK_NN * (FGK_P + FGK_TRI) + 255) / 256, 256, 0, stream>>>(snA);
        fgkEdge<<<FGK_NE / FGK_EPB, 512, 0, stream>>>(srcP, dstP, eaP,
            a1Hi + l * A1F, a1Lo + l * A1F, a1b + (size_t)l * FGK_F, hinB, snA, fnA);
        fgkSolve<<<(FGK_NN + 63) / 64, 64, 0, stream>>>(snA, fnA, mle);
        fgkNode<<<FGK_NN / 16, 256, 0, stream>>>(hin, mle,
            a2w + (size_t)l * FGK_P * FGK_H, a2b + (size_t)l * FGK_H,
            m1Hi + l * M1F, m1Lo + l * M1F, m1b + (size_t)l * 256,
            lng + (size_t)l * 256, lnb + (size_t)l * 256,
            m2Hi + l * M2F, m2Lo + l * M2F, m2b + (size_t)l * FGK_H,
            hAcc, l > 0 ? 1 : 0,
            hin, hinB, ng + (l + 1) * FGK_H, nb + (l + 1) * FGK_H, l < 2 ? 1 : 0);
    }
    fgkFinal<<<FGK_NN, FGK_H, 0, stream>>>(hAcc, ng, nb, lw, lb, outp);
}

// Round 13
// 744.501 us; speedup vs baseline: 1.1223x; 1.0495x over previous
//
#include <hip/hip_runtime.h>
#include <cmath>
#include <cstddef>

#define FGK_NN   20000
#define FGK_NE   320000
#define FGK_H    128
#define FGK_P    16
#define FGK_TRI  136
#define FGK_F    152
#define FGK_EPB  32
#define FGK_YP   156          // sY row stride (>=152, 16B-aligned rows, 28 mod 32)

typedef short  s16x8 __attribute__((ext_vector_type(8)));
typedef float  f32x4 __attribute__((ext_vector_type(4)));

__device__ __forceinline__ unsigned short fgk_f2b(float f) {   // RNE f32->bf16 (native cvt)
    __bf16 b = (__bf16)f;
    return __builtin_bit_cast(unsigned short, b);
}
__device__ __forceinline__ float fgk_u2f(unsigned short u) {
    return __uint_as_float(((unsigned int)u) << 16);
}
// bank-conflict swizzles on 16B-unit index (bijective XOR of high bits into group bits)
__device__ __forceinline__ int fgk_sw(int u)  { return u ^ ((u >> 4) & 7); }  // node-kernel pattern
__device__ __forceinline__ int fgk_swL(int u) { return u ^ ((u >> 5) & 7); }  // edge-kernel pattern

__global__ void FishnetGCN_62096637165586_kernel() {}

__global__ void fgkZero(float* acc) {
    int i = blockIdx.x * blockDim.x + threadIdx.x;
    if (i < FGK_NN * (FGK_P + FGK_TRI)) acc[i] = 0.f;
}
__global__ void fgkZeroI(int* p, int n) {
    int i = blockIdx.x * blockDim.x + threadIdx.x;
    if (i < n) p[i] = 0;
}
// ---- dst-sort: histogram -> block scan -> scatter (edge_index constant) ----
__global__ void fgkHist(const int* __restrict__ dst, int* __restrict__ hist) {
    int e = blockIdx.x * blockDim.x + threadIdx.x;
    if (e < FGK_NE) atomicAdd(&hist[dst[e]], 1);
}
__global__ void fgkScan(const int* __restrict__ hist, int* __restrict__ cursor)
{
    __shared__ int sWave[16];
    __shared__ int sRun;
    int t = threadIdx.x;             // 1024
    int lane = t & 63, wv = t >> 6;
    if (t == 0) sRun = 0;
    __syncthreads();
    for (int base = 0; base < FGK_NN; base += 1024) {
        int idx = base + t;
        int v = (idx < FGK_NN) ? hist[idx] : 0;
        int sc = v;
#pragma unroll
        for (int off = 1; off < 64; off <<= 1) {
            int u = __shfl_up(sc, off);
            if (lane >= off) sc += u;
        }
        if (lane == 63) sWave[wv] = sc;
        __syncthreads();
        if (wv == 0 && lane < 16) {
            int w = sWave[lane];
#pragma unroll
            for (int off = 1; off < 16; off <<= 1) {
                int u = __shfl_up(w, off, 16);
                if (lane >= off) w += u;
            }
            sWave[lane] = w;
        }
        __syncthreads();
        int waveOff = (wv == 0) ? 0 : sWave[wv - 1];
        int run = sRun;
        if (idx < FGK_NN) cursor[idx] = run + waveOff + sc - v;   // exclusive
        __syncthreads();
        if (t == 1023) sRun = run + sWave[15];
        __syncthreads();
    }
}
// scatter + emit perm-ordered src/dst arrays (removes double-indirection later)
__global__ void fgkScatterE(const int* __restrict__ dst, const int* __restrict__ src,
                            int* __restrict__ cursor, int* __restrict__ perm,
                            int* __restrict__ srcP, int* __restrict__ dstP) {
    int e = blockIdx.x * blockDim.x + threadIdx.x;
    if (e < FGK_NE) {
        int d = dst[e];
        int pos = atomicAdd(&cursor[d], 1);
        perm[pos] = e;
        srcP[pos] = src[e];
        dstP[pos] = d;
    }
}

// One-time, layer-invariant: eaP[pos] = bf16(eatt[perm[pos]] @ eew + eeb), perm order.
// 256 threads: thread = (pos in 16-group, 8-col group)
__global__ void fgkEncE(const float* __restrict__ eatt,
                        const int* __restrict__ perm,
                        const float* __restrict__ eew,
                        const float* __restrict__ eeb,
                        unsigned short* __restrict__ eaP)
{
    int pos = blockIdx.x * 16 + (threadIdx.x >> 4);
    int b = threadIdx.x & 15;
    int e = perm[pos];
    const float4* ap = (const float4*)(eatt + (size_t)e * 8);
    float4 a0 = ap[0], a1 = ap[1];
    float av[8] = {a0.x, a0.y, a0.z, a0.w, a1.x, a1.y, a1.z, a1.w};
    const float4* bp = (const float4*)(eeb + b * 8);
    float4 b0 = bp[0], b1 = bp[1];
    float acc[8] = {b0.x, b0.y, b0.z, b0.w, b1.x, b1.y, b1.z, b1.w};
#pragma unroll
    for (int kk = 0; kk < 8; ++kk) {
        const float4* wp = (const float4*)(eew + kk * FGK_H + b * 8);
        float4 w0 = wp[0], w1 = wp[1];
        acc[0] += av[kk] * w0.x; acc[1] += av[kk] * w0.y;
        acc[2] += av[kk] * w0.z; acc[3] += av[kk] * w0.w;
        acc[4] += av[kk] * w1.x; acc[5] += av[kk] * w1.y;
        acc[6] += av[kk] * w1.z; acc[7] += av[kk] * w1.w;
    }
    s16x8 r;
#pragma unroll
    for (int jj = 0; jj < 8; ++jj) r[jj] = (short)fgk_f2b(acc[jj]);
    *(s16x8*)&eaP[(size_t)pos * FGK_H + b * 8] = r;
}

// Generic prepack of W[K,N] (row-major) into MFMA B-fragment order, bf16 hi/lo.
__global__ void fgkPrepW(const float* __restrict__ W, int K, int N,
                         unsigned short* __restrict__ hi,
                         unsigned short* __restrict__ lo)
{
    int chunks = K >> 5;
    int b = blockIdx.x;
    int nt = b / chunks, c = b - nt * chunks;
    int lane = threadIdx.x;
    int n = nt * 16 + (lane & 15);
    int g = lane >> 4;
    size_t base = ((size_t)b * 64 + lane) * 8;
#pragma unroll
    for (int j = 0; j < 8; ++j) {
        int k = c * 32 + g * 8 + j;
        float v = (n < N) ? W[(size_t)k * N + n] : 0.f;
        unsigned short hb = fgk_f2b(v);
        unsigned short lb = fgk_f2b(v - fgk_u2f(hb));
        hi[base + j] = hb;
        lo[base + j] = lb;
    }
}

// hin = x @ W[8,128] + b   (f32 + bf16 gather copy)
__global__ void fgkEnc(const float* __restrict__ xin,
                       const float* __restrict__ wenc,
                       const float* __restrict__ benc,
                       float* __restrict__ hin,
                       unsigned short* __restrict__ hinB)
{
    int idx = blockIdx.x * blockDim.x + threadIdx.x;
    if (idx >= FGK_NN * FGK_H) return;
    int n = idx >> 7, j = idx & 127;
    float acc = benc[j];
    const float* xp = xin + (size_t)n * 8;
#pragma unroll
    for (int k = 0; k < 8; k++) acc += xp[k] * wenc[k * FGK_H + j];
    hin[idx] = acc;
    hinB[idx] = fgk_f2b(acc);
}

// edge (sorted by dst), 32 edges/block, 512 threads, ~37 KB LDS (4 blocks/CU):
// msg (A hi only) ; y=MFMA ; then per-16-edge halves: L-build -> Fe=MFMA,
// sTri for each half overlays that half's dead sY rows.  7 barriers.
__global__ void __launch_bounds__(512, 4)
fgkEdge(const int* __restrict__ srcP,
        const int* __restrict__ dstP,
        const unsigned short* __restrict__ eaP,
        const unsigned short* __restrict__ bHi,
        const unsigned short* __restrict__ bLo,
        const float* __restrict__ a1b,
        const unsigned short* __restrict__ hinB,
        float* __restrict__ snAcc,
        float* __restrict__ fnAcc)
{
    __shared__ float uni[4096];                   // 16 KB: aH (8K); lH/lL (8K+8K)
    __shared__ float sY[FGK_EPB][FGK_YP];         // 19.9 KB: y; halves -> sTri
    __shared__ int sSrc[FGK_EPB], sDst[FGK_EPB];
    __shared__ int sStart[FGK_EPB], sEnd[FGK_EPB], sDstSlot[FGK_EPB];
    __shared__ int sNS;
    unsigned short* aH = (unsigned short*)uni;            // 4096 us (8 KB)
    unsigned short* lH = (unsigned short*)uni;            // 4096 us (per-half)
    unsigned short* lL = (unsigned short*)uni + 4096;     // 4096 us (per-half)
    float* sTriA = (float*)sY;                            // 16*136 over rows 0-15
    float* sTriB = (float*)&sY[16][0];                    // 16*136 over rows 16-31
    int t = threadIdx.x;                          // 512 threads, 8 waves
    int lane = t & 63, wave = t >> 6;
    int e0 = blockIdx.x * FGK_EPB;

    if (wave == 0) {                              // meta load + parallel slot detect
        int sv = 0, dv = 0x7fffffff;
        if (lane < FGK_EPB) {
            sv = srcP[e0 + lane];
            dv = dstP[e0 + lane];
            sSrc[lane] = sv; sDst[lane] = dv;
        }
        int prev = __shfl_up(dv, 1);
        bool isStart = (lane < FGK_EPB) && (lane == 0 || dv != prev);
        unsigned long long mask = __ballot(isStart);
        int ns = __popcll(mask);
        if (isStart) {
            int s = (int)__popcll(mask & ((1ull << lane) - 1ull));
            sStart[s] = lane;
            sDstSlot[s] = dv;
            if (lane) sEnd[s - 1] = lane;
        }
        if (lane == 0) { sNS = ns; sEnd[ns - 1] = FGK_EPB; }
    }
    __syncthreads();                              // bar 1

    // ---- msg = relu(hinB[src] + eaP) + 1e-7 -> bf16 A-frags (hi only) ----
    {
        int el = t >> 4, b = t & 15;
        s16x8 hraw = *(const s16x8*)(hinB + (size_t)sSrc[el] * FGK_H + b * 8);
        s16x8 eraw = *(const s16x8*)(eaP + (size_t)(e0 + el) * FGK_H + b * 8);
        s16x8 hb;
#pragma unroll
        for (int jj = 0; jj < 8; ++jj) {
            float hv = fgk_u2f((unsigned short)hraw[jj]);
            float ev = fgk_u2f((unsigned short)eraw[jj]);
            float m = fmaxf(hv + ev, 0.f) + 1e-7f;
            hb[jj] = (short)fgk_f2b(m);
        }
        int c = b >> 2, g = b & 3;                // k = b*8+jj = 32c+8g+jj
        int idx = fgk_swL(c * 128 + 32 * g + el) * 8;
        *(s16x8*)&aH[idx] = hb;
    }
    __syncthreads();                              // bar 2

    // ---- y = msg @ a1w via MFMA (A hi-only, B dual): 2 mfma per c ----
    {
        int et = wave & 1;
        s16x8 ah[4];
#pragma unroll
        for (int c = 0; c < 4; ++c) {
            int idx = fgk_swL(c * 128 + 32 * (lane >> 4) + 16 * et + (lane & 15)) * 8;
            ah[c] = *(const s16x8*)&aH[idx];
        }
        int n = lane & 15, qd = lane >> 4;
        for (int nt = (wave >> 1); nt < 10; nt += 4) {
            f32x4 acc = {0.f, 0.f, 0.f, 0.f};
#pragma unroll
            for (int c = 0; c < 4; ++c) {
                size_t bidx = ((size_t)(nt * 4 + c) * 64 + lane) * 8;
                s16x8 bh = *(const s16x8*)(bHi + bidx);
                s16x8 bl = *(const s16x8*)(bLo + bidx);
                acc = __builtin_amdgcn_mfma_f32_16x16x32_bf16(ah[c], bl, acc, 0, 0, 0);
                acc = __builtin_amdgcn_mfma_f32_16x16x32_bf16(ah[c], bh, acc, 0, 0, 0);
            }
            int j = nt * 16 + n;
            if (j < FGK_F) {                       // GUARD: pad cols must not wrap
                float bias = a1b[j];
#pragma unroll
                for (int reg = 0; reg < 4; ++reg)
                    sY[16 * et + 4 * qd + reg][j] = acc[reg] + bias;
            }
        }
    }
    __syncthreads();                              // bar 3 (sY done; aH dead)

    // ---- P4: per-slot score reduce (reads all sY) + L-build half A (el 0-15) ----
    {
        {
            int s = t;                        // 512 slots: el16(16) x r(32)
            int el16 = s & 15;
            int r  = s >> 4;                  // 0..31
            int i  = r & 15, h = r >> 4;
            int pstart = 16 * i + 8 * h;
            float v[8];
            if (pstart < 120) {
                const float4* rp = (const float4*)&sY[el16][32 + pstart];
                float4 v0 = rp[0], v1 = rp[1];
                v[0] = v0.x; v[1] = v0.y; v[2] = v0.z; v[3] = v0.w;
                v[4] = v1.x; v[5] = v1.y; v[6] = v1.z; v[7] = v1.w;
            } else {
                const float4* rp = (const float4*)&sY[el16][264 - pstart];
                float4 v0 = rp[0], v1 = rp[1];
                v[0] = v1.w; v[1] = v1.z; v[2] = v1.y; v[3] = v1.x;
                v[4] = v0.w; v[5] = v0.z; v[6] = v0.y; v[7] = v0.x;
            }
            if (h == (i >> 3)) {              // diag elem at i&7
                int jd = i & 7;
                float d0 = v[jd];
                v[jd] = fmaxf(d0, 0.f) +
                        0.69314718f * log2f(1.f + exp2f(-1.44269504f * fabsf(d0)));
            }
            s16x8 hb, lb;
#pragma unroll
            for (int jj = 0; jj < 8; ++jj) {
                unsigned short hbv = fgk_f2b(v[jj]);
                hb[jj] = (short)hbv;
                lb[jj] = (short)fgk_f2b(v[jj] - fgk_u2f(hbv));
            }
            int idx = fgk_swL(el16 * 32 + i + 16 * h) * 8;
            *(s16x8*)&lH[idx] = hb;
            *(s16x8*)&lL[idx] = lb;
        }
        int el = t >> 4, d = t & 15;          // score reduce (sY all rows)
        if (el < sNS) {
            float sum = 0.f;
            for (int e2 = sStart[el]; e2 < sEnd[el]; ++e2) sum += sY[e2][d];
            atomicAdd(&snAcc[(size_t)sDstSlot[el] * FGK_P + d], sum);
        }
    }
    __syncthreads();                              // bar 4

    // ---- P5: Fe half A -> sTriA (overlays sY rows 0-15, now dead) ----
#pragma unroll
    for (int i2 = 0; i2 < 2; ++i2) {
        int el16 = wave * 2 + i2;             // 0..15
        s16x8 fh = {0, 0, 0, 0, 0, 0, 0, 0};
        s16x8 fl = {0, 0, 0, 0, 0, 0, 0, 0};
        if (lane < 32) {
            int idx = fgk_swL(el16 * 32 + lane) * 8;
            fh = *(const s16x8*)&lH[idx];
            fl = *(const s16x8*)&lL[idx];
        }
        f32x4 acc = {0.f, 0.f, 0.f, 0.f};
        acc = __builtin_amdgcn_mfma_f32_16x16x32_bf16(fh, fh, acc, 0, 0, 0);
        acc = __builtin_amdgcn_mfma_f32_16x16x32_bf16(fh, fl, acc, 0, 0, 0);
        acc = __builtin_amdgcn_mfma_f32_16x16x32_bf16(fl, fh, acc, 0, 0, 0);
        int j = lane & 15, qd = lane >> 4;
#pragma unroll
        for (int reg = 0; reg < 4; ++reg) {
            int ii = 4 * qd + reg;
            if (ii >= j) sTriA[el16 * FGK_TRI + ii * (ii + 1) / 2 + j] = acc[reg];
        }
    }
    __syncthreads();                              // bar 5 (lH/lL A consumed)

    // ---- P6: L-build half B (el 16-31; sY rows 16-31 still intact) ----
    {
        int s = t;
        int el16 = s & 15;
        int r  = s >> 4;
        int i  = r & 15, h = r >> 4;
        int pstart = 16 * i + 8 * h;
        float v[8];
        if (pstart < 120) {
            const float4* rp = (const float4*)&sY[16 + el16][32 + pstart];
            float4 v0 = rp[0], v1 = rp[1];
            v[0] = v0.x; v[1] = v0.y; v[2] = v0.z; v[3] = v0.w;
            v[4] = v1.x; v[5] = v1.y; v[6] = v1.z; v[7] = v1.w;
        } else {
            const float4* rp = (const float4*)&sY[16 + el16][264 - pstart];
            float4 v0 = rp[0], v1 = rp[1];
            v[0] = v1.w; v[1] = v1.z; v[2] = v1.y; v[3] = v1.x;
            v[4] = v0.w; v[5] = v0.z; v[6] = v0.y; v[7] = v0.x;
        }
        if (h == (i >> 3)) {
            int jd = i & 7;
            float d0 = v[jd];
            v[jd] = fmaxf(d0, 0.f) +
                    0.69314718f * log2f(1.f + exp2f(-1.44269504f * fabsf(d0)));
        }
        s16x8 hb, lb;
#pragma unroll
        for (int jj = 0; jj < 8; ++jj) {
            unsigned short hbv = fgk_f2b(v[jj]);
            hb[jj] = (short)hbv;
            lb[jj] = (short)fgk_f2b(v[jj] - fgk_u2f(hbv));
        }
        int idx = fgk_swL(el16 * 32 + i + 16 * h) * 8;
        *(s16x8*)&lH[idx] = hb;
        *(s16x8*)&lL[idx] = lb;
    }
    __syncthreads();                              // bar 6

    // ---- P7: Fe half B -> sTriB (overlays sY rows 16-31, now dead) ----
#pragma unroll
    for (int i2 = 0; i2 < 2; ++i2) {
        int el16 = wave * 2 + i2;
        s16x8 fh = {0, 0, 0, 0, 0, 0, 0, 0};
        s16x8 fl = {0, 0, 0, 0, 0, 0, 0, 0};
        if (lane < 32) {
            int idx = fgk_swL(el16 * 32 + lane) * 8;
            fh = *(const s16x8*)&lH[idx];
            fl = *(const s16x8*)&lL[idx];
        }
        f32x4 acc = {0.f, 0.f, 0.f, 0.f};
        acc = __builtin_amdgcn_mfma_f32_16x16x32_bf16(fh, fh, acc, 0, 0, 0);
        acc = __builtin_amdgcn_mfma_f32_16x16x32_bf16(fh, fl, acc, 0, 0, 0);
        acc = __builtin_amdgcn_mfma_f32_16x16x32_bf16(fl, fh, acc, 0, 0, 0);
        int j = lane & 15, qd = lane >> 4;
#pragma unroll
        for (int reg = 0; reg < 4; ++reg) {
            int ii = 4 * qd + reg;
            if (ii >= j) sTriB[el16 * FGK_TRI + ii * (ii + 1) / 2 + j] = acc[reg];
        }
    }
    __syncthreads();                              // bar 7

    // ---- per-slot tri reduction -> coalesced atomics ----
    {
        int nS = sNS;
        for (int o = t; o < nS * FGK_TRI; o += 512) {
            int s = o / FGK_TRI, p = o - s * FGK_TRI;
            float sum = 0.f;
            for (int el = sStart[s]; el < sEnd[s]; ++el) {
                const float* tb = (el < 16) ? sTriA : sTriB;
                sum += tb[(el & 15) * FGK_TRI + p];
            }
            atomicAdd(&fnAcc[(size_t)sDstSlot[s] * FGK_TRI + p], sum);
        }
    }
}

// one thread per node: fully-unrolled register Cholesky solve of (F_n+I) x = s_n
// 64-thread blocks: 313 workgroups spread over all 256 CUs
#define TA(i, j) a[(i) * ((i) + 1) / 2 + (j)]
__global__ void __launch_bounds__(64)
fgkSolve(const float* __restrict__ snAcc,
         const float* __restrict__ fnAcc,
         float* __restrict__ mleOut)
{
    int n = blockIdx.x * blockDim.x + threadIdx.x;
    if (n >= FGK_NN) return;
    float a[FGK_TRI];
    const float4* src = (const float4*)(fnAcc + (size_t)n * FGK_TRI);
#pragma unroll
    for (int p = 0; p < FGK_TRI / 4; ++p) {
        float4 v = src[p];
        a[p * 4] = v.x; a[p * 4 + 1] = v.y; a[p * 4 + 2] = v.z; a[p * 4 + 3] = v.w;
    }
#pragma unroll
    for (int i = 0; i < 16; ++i) TA(i, i) += 1.f;
#pragma unroll
    for (int k = 0; k < 16; ++k) {
        float d = sqrtf(TA(k, k));
        float inv = 1.f / d;
        TA(k, k) = d;
#pragma unroll
        for (int i = k + 1; i < 16; ++i) TA(i, k) *= inv;
#pragma unroll
        for (int j = k + 1; j < 16; ++j) {
            float ajk = TA(j, k);
#pragma unroll
            for (int i = j; i < 16; ++i) TA(i, j) -= TA(i, k) * ajk;
        }
    }
    const float* sp = snAcc + (size_t)n * FGK_P;
    float y[16], x[16];
#pragma unroll
    for (int i = 0; i < 16; ++i) {
        float acc = sp[i];
#pragma unroll
        for (int k = 0; k < 16; ++k) if (k < i) acc -= TA(i, k) * y[k];
        y[i] = acc / TA(i, i);
    }
#pragma unroll
    for (int i = 15; i >= 0; --i) {
        float acc = y[i];
#pragma unroll
        for (int k = 0; k < 16; ++k) if (k > i) acc -= TA(k, i) * x[k];
        x[i] = acc / TA(i, i);
    }
    float4* dst = (float4*)(mleOut + (size_t)n * FGK_P);
#pragma unroll
    for (int p = 0; p < 4; ++p) dst[p] = make_float4(x[p * 4], x[p * 4 + 1], x[p * 4 + 2], x[p * 4 + 3]);
}
#undef TA

// node (16 nodes/block): a2+res -> m1 MFMA -> LN -> m2 MFMA -> hout
// + fused next-layer relu(LN(hout)) -> hinNext f32 + bf16 (doNext)
__global__ void __launch_bounds__(256)
fgkNode(const float* __restrict__ hin,
        const float* __restrict__ mleIn,
        const float* __restrict__ a2w, const float* __restrict__ a2b,
        const unsigned short* __restrict__ m1H, const unsigned short* __restrict__ m1L,
        const float* __restrict__ m1b,
        const float* __restrict__ gamma, const float* __restrict__ beta,
        const unsigned short* __restrict__ m2H, const unsigned short* __restrict__ m2L,
        const float* __restrict__ m2b,
        float* __restrict__ hout, int addres,
        float* __restrict__ hinNext, unsigned short* __restrict__ hinNextB,
        const float* __restrict__ gN, const float* __restrict__ bN, int doNext)
{
    __shared__ char uniN[16384];
    __shared__ float sT[16][260];
    __shared__ float stats[16][2];
    unsigned short* ovH = (unsigned short*)uniN;
    unsigned short* ovL = (unsigned short*)uniN + 2048;
    unsigned short* t2H = (unsigned short*)uniN;
    unsigned short* t2L = (unsigned short*)uniN + 4096;
    int t = threadIdx.x, lane = t & 63, wave = t >> 6;
    int n0 = blockIdx.x * 16;

    // ---- a2 matvec + residual -> bf16 hi/lo frags (one pass, vectorized) ----
    {
        int node = t >> 4, cg = t & 15;            // 8 cols per thread
        const float4* m4 = (const float4*)(mleIn + (size_t)(n0 + node) * FGK_P);
        float4 q0 = m4[0], q1 = m4[1], q2 = m4[2], q3 = m4[3];
        float mv[16] = {q0.x, q0.y, q0.z, q0.w, q1.x, q1.y, q1.z, q1.w,
                        q2.x, q2.y, q2.z, q2.w, q3.x, q3.y, q3.z, q3.w};
        const float4* bp = (const float4*)(a2b + cg * 8);
        float4 b0 = bp[0], b1 = bp[1];
        const float4* hp = (const float4*)(hin + (size_t)(n0 + node) * FGK_H + cg * 8);
        float4 h0 = hp[0], h1 = hp[1];
        float acc[8] = {b0.x + h0.x, b0.y + h0.y, b0.z + h0.z, b0.w + h0.w,
                        b1.x + h1.x, b1.y + h1.y, b1.z + h1.z, b1.w + h1.w};
#pragma unroll
        for (int k = 0; k < 16; ++k) {
            const float4* wp = (const float4*)(a2w + k * FGK_H + cg * 8);
            float4 w0 = wp[0], w1 = wp[1];
            acc[0] += mv[k] * w0.x; acc[1] += mv[k] * w0.y;
            acc[2] += mv[k] * w0.z; acc[3] += mv[k] * w0.w;
            acc[4] += mv[k] * w1.x; acc[5] += mv[k] * w1.y;
            acc[6] += mv[k] * w1.z; acc[7] += mv[k] * w1.w;
        }
        s16x8 hb, lb;
#pragma unroll
        for (int jj = 0; jj < 8; ++jj) {
            unsigned short hbv = fgk_f2b(acc[jj]);
            hb[jj] = (short)hbv;
            lb[jj] = (short)fgk_f2b(acc[jj] - fgk_u2f(hbv));
        }
        int idx = fgk_sw(cg * 16 + node) * 8;      // u = c*64+16g+node = 16*cg+node
        *(s16x8*)&ovH[idx] = hb;
        *(s16x8*)&ovL[idx] = lb;
    }
    __syncthreads();

    {
        s16x8 ah[4], al[4];
#pragma unroll
        for (int c = 0; c < 4; ++c) {
            int idx = fgk_sw(c * 64 + lane) * 8;
            ah[c] = *(const s16x8*)&ovH[idx];
            al[c] = *(const s16x8*)&ovL[idx];
        }
        int n = lane & 15, qd = lane >> 4;
#pragma unroll
        for (int i4 = 0; i4 < 4; ++i4) {
            int nt = wave + i4 * 4;
            f32x4 acc = {0.f, 0.f, 0.f, 0.f};
#pragma unroll
            for (int c = 0; c < 4; ++c) {
                size_t bidx = ((size_t)(nt * 4 + c) * 64 + lane) * 8;
                s16x8 bh = *(const s16x8*)(m1H + bidx);
                s16x8 bl = *(const s16x8*)(m1L + bidx);
                acc = __builtin_amdgcn_mfma_f32_16x16x32_bf16(al[c], bh, acc, 0, 0, 0);
                acc = __builtin_amdgcn_mfma_f32_16x16x32_bf16(ah[c], bl, acc, 0, 0, 0);
                acc = __builtin_amdgcn_mfma_f32_16x16x32_bf16(ah[c], bh, acc, 0, 0, 0);
            }
            int j = nt * 16 + n;
            float bias = m1b[j];
#pragma unroll
            for (int reg = 0; reg < 4; ++reg)
                sT[4 * qd + reg][j] = acc[reg] + bias;
        }
    }
    __syncthreads();

    {
        int node = t >> 4, seg = t & 15;
        const float* rowp = &sT[node][seg * 16];
        float s1 = 0.f, s2 = 0.f;
#pragma unroll
        for (int k = 0; k < 16; ++k) { float v = rowp[k]; s1 += v; s2 += v * v; }
#pragma unroll
        for (int off = 8; off; off >>= 1) {
            s1 += __shfl_down(s1, off, 16);
            s2 += __shfl_down(s2, off, 16);
        }
        if (seg == 0) {
            float mu = s1 * (1.f / 256.f);
            float var = s2 * (1.f / 256.f) - mu * mu;
            stats[node][0] = mu;
            stats[node][1] = rsqrtf(var + 1e-5f);
        }
    }
    __syncthreads();

    // ---- LN + relu -> bf16 hi/lo frags (vectorized, swizzled b128 stores) ----
    {
        int node = t >> 4;
        float mu = stats[node][0], rstd = stats[node][1];
#pragma unroll
        for (int h = 0; h < 2; ++h) {
            int cg = (t & 15) + 16 * h;            // 0..31, 8 cols each
            const float4* rp = (const float4*)&sT[node][cg * 8];
            float4 v0 = rp[0], v1 = rp[1];
            const float4* gp = (const float4*)(gamma + cg * 8);
            float4 g0 = gp[0], g1 = gp[1];
            const float4* bb = (const float4*)(beta + cg * 8);
            float4 e0 = bb[0], e1 = bb[1];
            float vv[8] = {v0.x, v0.y, v0.z, v0.w, v1.x, v1.y, v1.z, v1.w};
            float gg[8] = {g0.x, g0.y, g0.z, g0.w, g1.x, g1.y, g1.z, g1.w};
            float ee[8] = {e0.x, e0.y, e0.z, e0.w, e1.x, e1.y, e1.z, e1.w};
            s16x8 hb, lb;
#pragma unroll
            for (int jj = 0; jj < 8; ++jj) {
                float tv = fmaxf((vv[jj] - mu) * rstd * gg[jj] + ee[jj], 0.f);
                unsigned short hbv = fgk_f2b(tv);
                hb[jj] = (short)hbv;
                lb[jj] = (short)fgk_f2b(tv - fgk_u2f(hbv));
            }
            int idx = fgk_sw(cg * 16 + node) * 8;
            *(s16x8*)&t2H[idx] = hb;
            *(s16x8*)&t2L[idx] = lb;
        }
    }
    __syncthreads();

    {
        s16x8 ah[8], al[8];
#pragma unroll
        for (int c = 0; c < 8; ++c) {
            int idx = fgk_sw(c * 64 + lane) * 8;
            ah[c] = *(const s16x8*)&t2H[idx];
            al[c] = *(const s16x8*)&t2L[idx];
        }
        int n = lane & 15, qd = lane >> 4;
#pragma unroll
        for (int i2 = 0; i2 < 2; ++i2) {
            int nt = wave * 2 + i2;
            f32x4 acc = {0.f, 0.f, 0.f, 0.f};
#pragma unroll
            for (int c = 0; c < 8; ++c) {
                size_t bidx = ((size_t)(nt * 8 + c) * 64 + lane) * 8;
                s16x8 bh = *(const s16x8*)(m2H + bidx);
                s16x8 bl = *(const s16x8*)(m2L + bidx);
                acc = __builtin_amdgcn_mfma_f32_16x16x32_bf16(al[c], bh, acc, 0, 0, 0);
                acc = __builtin_amdgcn_mfma_f32_16x16x32_bf16(ah[c], bl, acc, 0, 0, 0);
                acc = __builtin_amdgcn_mfma_f32_16x16x32_bf16(ah[c], bh, acc, 0, 0, 0);
            }
            int j = nt * 16 + n;
            float bias = m2b[j];
#pragma unroll
            for (int reg = 0; reg < 4; ++reg) {
                int node = 4 * qd + reg;
                size_t idx = (size_t)(n0 + node) * FGK_H + j;
                float val = acc[reg] + bias;
                float nv = addres ? (hout[idx] + val) : val;
                hout[idx] = nv;
                sT[node][j] = nv;          // park for fused next-layer LN
            }
        }
    }
    if (doNext) {                          // hinNext = relu(LN(hout, gN, bN))
        __syncthreads();
        int node = t >> 4, seg = t & 15;
        const float* rowp = &sT[node][seg * 8];
        float s1 = 0.f, s2 = 0.f;
#pragma unroll
        for (int k = 0; k < 8; ++k) { float v = rowp[k]; s1 += v; s2 += v * v; }
#pragma unroll
        for (int off = 8; off; off >>= 1) {
            s1 += __shfl_down(s1, off, 16);
            s2 += __shfl_down(s2, off, 16);
        }
        if (seg == 0) {
            float mu = s1 * (1.f / 128.f);
            float var = s2 * (1.f / 128.f) - mu * mu;
            stats[node][0] = mu;
            stats[node][1] = rsqrtf(var + 1e-5f);
        }
        __syncthreads();
        float mu = stats[node][0], rstd = stats[node][1];
#pragma unroll
        for (int kk = 0; kk < 8; ++kk) {
            int k = seg * 8 + kk;
            float v = sT[node][k];
            float nv = fmaxf((v - mu) * rstd * gN[k] + bN[k], 0.f);
            size_t oidx = (size_t)(n0 + node) * FGK_H + k;
            hinNext[oidx] = nv;
            hinNextB[oidx] = fgk_f2b(nv);
        }
    }
}

// out = relu(LN(h, g0, b0)) @ lin_w + lin_b   (f32 out)
__global__ void fgkFinal(const float* __restrict__ hsrc,
                         const float* __restrict__ gamma,
                         const float* __restrict__ beta,
                         const float* __restrict__ lw,
                         const float* __restrict__ lb,
                         float* __restrict__ outp)
{
    int n = blockIdx.x, t = threadIdx.x;   // block = 128
    __shared__ float tt[FGK_H];
    __shared__ float red[4];
    float v = hsrc[(size_t)n * FGK_H + t];
    float s1 = v, s2 = v * v;
#pragma unroll
    for (int off = 32; off; off >>= 1) { s1 += __shfl_down(s1, off); s2 += __shfl_down(s2, off); }
    int wid = t >> 6, lane = t & 63;
    if (lane == 0) { red[wid] = s1; red[2 + wid] = s2; }
    __syncthreads();
    float mu = (red[0] + red[1]) * (1.f / FGK_H);
    float var = (red[2] + red[3]) * (1.f / FGK_H) - mu * mu;
    float rstd = rsqrtf(var + 1e-5f);
    tt[t] = fmaxf((v - mu) * rstd * gamma[t] + beta[t], 0.f);
    __syncthreads();
    if (t < 112) {
        float acc = lb[t];
        for (int k = 0; k < FGK_H; k++) acc += tt[k] * lw[k * 112 + t];
        outp[(size_t)n * 112 + t] = acc;
    }
}

extern "C" void kernel_launch(void* const* d_in, const int* in_sizes, int n_in,
                              void* d_out, int out_size, void* d_ws, size_t ws_size,
                              hipStream_t stream)
{
    const float* xin  = (const float*)d_in[0];
    const float* eatt = (const float*)d_in[1];
    const int*   eidx = (const int*)d_in[2];
    const float* nEw  = (const float*)d_in[3];
    const float* nEb  = (const float*)d_in[4];
    const float* eEw  = (const float*)d_in[5];
    const float* eEb  = (const float*)d_in[6];
    const float* a1w  = (const float*)d_in[7];
    const float* a1b  = (const float*)d_in[8];
    const float* a2w  = (const float*)d_in[9];
    const float* a2b  = (const float*)d_in[10];
    const float* m1w  = (const float*)d_in[11];
    const float* m1b  = (const float*)d_in[12];
    const float* lng  = (const float*)d_in[13];
    const float* lnb  = (const float*)d_in[14];
    const float* m2w  = (const float*)d_in[15];
    const float* m2b  = (const float*)d_in[16];
    const float* ng   = (const float*)d_in[17];
    const float* nb   = (const float*)d_in[18];
    const float* lw   = (const float*)d_in[19];
    const float* lb   = (const float*)d_in[20];
    float* outp = (float*)d_out;
    const int* srcIdx = eidx;
    const int* dstIdx = eidx + FGK_NE;

    float* ws   = (float*)d_ws;
    float* hAcc = ws;                                    // NN*128
    float* hin  = hAcc + (size_t)FGK_NN * FGK_H;         // NN*128
    float* snA  = hin  + (size_t)FGK_NN * FGK_H;         // NN*16
    float* fnA  = snA  + (size_t)FGK_NN * FGK_P;         // NN*136
    float* mle  = fnA  + (size_t)FGK_NN * FGK_TRI;       // NN*16
    unsigned short* wsU = (unsigned short*)(mle + (size_t)FGK_NN * FGK_P);
    const int A1F = 40 * 512, M1F = 64 * 512, M2F = 64 * 512;
    unsigned short* a1Hi = wsU;
    unsigned short* a1Lo = a1Hi + 3 * A1F;
    unsigned short* m1Hi = a1Lo + 3 * A1F;
    unsigned short* m1Lo = m1Hi + 3 * M1F;
    unsigned short* m2Hi = m1Lo + 3 * M1F;
    unsigned short* m2Lo = m2Hi + 3 * M2F;
    int* cursor = (int*)(m2Lo + 3 * M2F);                // NN ints
    int* perm   = cursor + FGK_NN;                       // NE ints
    int* srcP   = perm + FGK_NE;                         // NE ints (perm-ordered src)
    int* dstP   = srcP + FGK_NE;                         // NE ints (perm-ordered dst)
    unsigned short* hinB = (unsigned short*)(dstP + FGK_NE);   // NN*128 bf16
    unsigned short* eaP  = hinB + (size_t)FGK_NN * FGK_H;      // NE*128 bf16 (82 MB)

    // dst-sorted edge permutation (edge_index constant; rebuilt every launch)
    fgkZeroI<<<(FGK_NN + 255) / 256, 256, 0, stream>>>(cursor, FGK_NN);
    fgkHist<<<(FGK_NE + 255) / 256, 256, 0, stream>>>(dstIdx, cursor);
    fgkScan<<<1, 1024, 0, stream>>>(cursor, cursor);     // in-place exclusive scan
    fgkScatterE<<<(FGK_NE + 255) / 256, 256, 0, stream>>>(dstIdx, srcIdx, cursor,
                                                          perm, srcP, dstP);
    // one-time layer-invariant edge encoding, perm-ordered bf16
    fgkEncE<<<FGK_NE / 16, 256, 0, stream>>>(eatt, perm, eEw, eEb, eaP);

    for (int l = 0; l < 3; l++) {
        fgkPrepW<<<40, 64, 0, stream>>>(a1w + (size_t)l * FGK_H * FGK_F, 128, 152,
                                        a1Hi + l * A1F, a1Lo + l * A1F);
        fgkPrepW<<<64, 64, 0, stream>>>(m1w + (size_t)l * FGK_H * 256, 128, 256,
                                        m1Hi + l * M1F, m1Lo + l * M1F);
        fgkPrepW<<<64, 64, 0, stream>>>(m2w + (size_t)l * 256 * FGK_H, 256, 128,
                                        m2Hi + l * M2F, m2Lo + l * M2F);
    }
    fgkEnc<<<(FGK_NN * FGK_H + 255) / 256, 256, 0, stream>>>(xin, nEw, nEb, hin, hinB);
    for (int l = 0; l < 3; l++) {
        fgkZero<<<(FGK_NN * (FGK_P + FGK_TRI) + 255) / 256, 256, 0, stream>>>(snA);
        fgkEdge<<<FGK_NE / FGK_EPB, 512, 0, stream>>>(srcP, dstP, eaP,
            a1Hi + l * A1F, a1Lo + l * A1F, a1b + (size_t)l * FGK_F, hinB, snA, fnA);
        fgkSolve<<<(FGK_NN + 63) / 64, 64, 0, stream>>>(snA, fnA, mle);
        fgkNode<<<FGK_NN / 16, 256, 0, stream>>>(hin, mle,
            a2w + (size_t)l * FGK_P * FGK_H, a2b + (size_t)l * FGK_H,
            m1Hi + l * M1F, m1Lo + l * M1F, m1b + (size_t)l * 256,
            lng + (size_t)l * 256, lnb + (size_t)l * 256,
            m2Hi + l * M2F, m2Lo + l * M2F, m2b + (size_t)l * FGK_H,
            hAcc, l > 0 ? 1 : 0,
            hin, hinB, ng + (l + 1) * FGK_H, nb + (l + 1) * FGK_H, l < 2 ? 1 : 0);
    }
    fgkFinal<<<FGK_NN, FGK_H, 0, stream>>>(hAcc, ng, nb, lw, lb, outp);
}

// Round 14
// 727.653 us; speedup vs baseline: 1.1482x; 1.0232x over previous
//
#include <hip/hip_runtime.h>
#include <cmath>
#include <cstddef>

#define FGK_NN   20000
#define FGK_NE   320000
#define FGK_H    128
#define FGK_P    16
#define FGK_TRI  136
#define FGK_F    152
#define FGK_EPB  32
#define FGK_YP   156          // sY row stride (>=152, 16B-aligned rows, 28 mod 32)

typedef short  s16x8 __attribute__((ext_vector_type(8)));
typedef float  f32x4 __attribute__((ext_vector_type(4)));

__device__ __forceinline__ unsigned short fgk_f2b(float f) {   // RNE f32->bf16 (native cvt)
    __bf16 b = (__bf16)f;
    return __builtin_bit_cast(unsigned short, b);
}
__device__ __forceinline__ float fgk_u2f(unsigned short u) {
    return __uint_as_float(((unsigned int)u) << 16);
}
// bank-conflict swizzles on 16B-unit index (bijective XOR of high bits into group bits)
__device__ __forceinline__ int fgk_sw(int u)  { return u ^ ((u >> 4) & 7); }  // node-kernel pattern
__device__ __forceinline__ int fgk_swL(int u) { return u ^ ((u >> 5) & 7); }  // edge-kernel pattern

__global__ void FishnetGCN_62096637165586_kernel() {}

__global__ void fgkZero(float* acc) {
    int i = blockIdx.x * blockDim.x + threadIdx.x;
    if (i < FGK_NN * (FGK_P + FGK_TRI)) acc[i] = 0.f;
}
__global__ void fgkZeroI(int* p, int n) {
    int i = blockIdx.x * blockDim.x + threadIdx.x;
    if (i < n) p[i] = 0;
}
// ---- dst-sort: histogram -> block scan -> scatter (edge_index constant) ----
__global__ void fgkHist(const int* __restrict__ dst, int* __restrict__ hist) {
    int e = blockIdx.x * blockDim.x + threadIdx.x;
    if (e < FGK_NE) atomicAdd(&hist[dst[e]], 1);
}
__global__ void fgkScan(const int* __restrict__ hist, int* __restrict__ cursor)
{
    __shared__ int sWave[16];
    __shared__ int sRun;
    int t = threadIdx.x;             // 1024
    int lane = t & 63, wv = t >> 6;
    if (t == 0) sRun = 0;
    __syncthreads();
    for (int base = 0; base < FGK_NN; base += 1024) {
        int idx = base + t;
        int v = (idx < FGK_NN) ? hist[idx] : 0;
        int sc = v;
#pragma unroll
        for (int off = 1; off < 64; off <<= 1) {
            int u = __shfl_up(sc, off);
            if (lane >= off) sc += u;
        }
        if (lane == 63) sWave[wv] = sc;
        __syncthreads();
        if (wv == 0 && lane < 16) {
            int w = sWave[lane];
#pragma unroll
            for (int off = 1; off < 16; off <<= 1) {
                int u = __shfl_up(w, off, 16);
                if (lane >= off) w += u;
            }
            sWave[lane] = w;
        }
        __syncthreads();
        int waveOff = (wv == 0) ? 0 : sWave[wv - 1];
        int run = sRun;
        if (idx < FGK_NN) cursor[idx] = run + waveOff + sc - v;   // exclusive
        __syncthreads();
        if (t == 1023) sRun = run + sWave[15];
        __syncthreads();
    }
}
// scatter + emit perm-ordered src/dst arrays (removes double-indirection later)
__global__ void fgkScatterE(const int* __restrict__ dst, const int* __restrict__ src,
                            int* __restrict__ cursor, int* __restrict__ perm,
                            int* __restrict__ srcP, int* __restrict__ dstP) {
    int e = blockIdx.x * blockDim.x + threadIdx.x;
    if (e < FGK_NE) {
        int d = dst[e];
        int pos = atomicAdd(&cursor[d], 1);
        perm[pos] = e;
        srcP[pos] = src[e];
        dstP[pos] = d;
    }
}

// One-time, layer-invariant: eaP[pos] = bf16(eatt[perm[pos]] @ eew + eeb), perm order.
// 256 threads: thread = (pos in 16-group, 8-col group)
__global__ void fgkEncE(const float* __restrict__ eatt,
                        const int* __restrict__ perm,
                        const float* __restrict__ eew,
                        const float* __restrict__ eeb,
                        unsigned short* __restrict__ eaP)
{
    int pos = blockIdx.x * 16 + (threadIdx.x >> 4);
    int b = threadIdx.x & 15;
    int e = perm[pos];
    const float4* ap = (const float4*)(eatt + (size_t)e * 8);
    float4 a0 = ap[0], a1 = ap[1];
    float av[8] = {a0.x, a0.y, a0.z, a0.w, a1.x, a1.y, a1.z, a1.w};
    const float4* bp = (const float4*)(eeb + b * 8);
    float4 b0 = bp[0], b1 = bp[1];
    float acc[8] = {b0.x, b0.y, b0.z, b0.w, b1.x, b1.y, b1.z, b1.w};
#pragma unroll
    for (int kk = 0; kk < 8; ++kk) {
        const float4* wp = (const float4*)(eew + kk * FGK_H + b * 8);
        float4 w0 = wp[0], w1 = wp[1];
        acc[0] += av[kk] * w0.x; acc[1] += av[kk] * w0.y;
        acc[2] += av[kk] * w0.z; acc[3] += av[kk] * w0.w;
        acc[4] += av[kk] * w1.x; acc[5] += av[kk] * w1.y;
        acc[6] += av[kk] * w1.z; acc[7] += av[kk] * w1.w;
    }
    s16x8 r;
#pragma unroll
    for (int jj = 0; jj < 8; ++jj) r[jj] = (short)fgk_f2b(acc[jj]);
    *(s16x8*)&eaP[(size_t)pos * FGK_H + b * 8] = r;
}

// Generic prepack of W[K,N] (row-major) into MFMA B-fragment order, bf16 hi/lo.
__global__ void fgkPrepW(const float* __restrict__ W, int K, int N,
                         unsigned short* __restrict__ hi,
                         unsigned short* __restrict__ lo)
{
    int chunks = K >> 5;
    int b = blockIdx.x;
    int nt = b / chunks, c = b - nt * chunks;
    int lane = threadIdx.x;
    int n = nt * 16 + (lane & 15);
    int g = lane >> 4;
    size_t base = ((size_t)b * 64 + lane) * 8;
#pragma unroll
    for (int j = 0; j < 8; ++j) {
        int k = c * 32 + g * 8 + j;
        float v = (n < N) ? W[(size_t)k * N + n] : 0.f;
        unsigned short hb = fgk_f2b(v);
        unsigned short lb = fgk_f2b(v - fgk_u2f(hb));
        hi[base + j] = hb;
        lo[base + j] = lb;
    }
}

// hin = x @ W[8,128] + b   (f32 + bf16 gather copy)
__global__ void fgkEnc(const float* __restrict__ xin,
                       const float* __restrict__ wenc,
                       const float* __restrict__ benc,
                       float* __restrict__ hin,
                       unsigned short* __restrict__ hinB)
{
    int idx = blockIdx.x * blockDim.x + threadIdx.x;
    if (idx >= FGK_NN * FGK_H) return;
    int n = idx >> 7, j = idx & 127;
    float acc = benc[j];
    const float* xp = xin + (size_t)n * 8;
#pragma unroll
    for (int k = 0; k < 8; k++) acc += xp[k] * wenc[k * FGK_H + j];
    hin[idx] = acc;
    hinB[idx] = fgk_f2b(acc);
}

// edge (sorted by dst), 32 edges/block, 512 threads, ~37 KB LDS (4 blocks/CU):
// msg (A hi only) ; y=MFMA (wave owns nt, both et per B-tile) ; then per-16-edge
// halves: L-build -> Fe=MFMA, sTri overlays that half's dead sY rows.  7 barriers.
__global__ void __launch_bounds__(512, 4)
fgkEdge(const int* __restrict__ srcP,
        const int* __restrict__ dstP,
        const unsigned short* __restrict__ eaP,
        const unsigned short* __restrict__ bHi,
        const unsigned short* __restrict__ bLo,
        const float* __restrict__ a1b,
        const unsigned short* __restrict__ hinB,
        float* __restrict__ snAcc,
        float* __restrict__ fnAcc)
{
    __shared__ float uni[4096];                   // 16 KB: aH (8K); lH/lL (8K+8K)
    __shared__ float sY[FGK_EPB][FGK_YP];         // 19.9 KB: y; halves -> sTri
    __shared__ int sSrc[FGK_EPB], sDst[FGK_EPB];
    __shared__ int sStart[FGK_EPB], sEnd[FGK_EPB], sDstSlot[FGK_EPB];
    __shared__ int sNS;
    unsigned short* aH = (unsigned short*)uni;            // 4096 us (8 KB)
    unsigned short* lH = (unsigned short*)uni;            // 4096 us (per-half)
    unsigned short* lL = (unsigned short*)uni + 4096;     // 4096 us (per-half)
    float* sTriA = (float*)sY;                            // 16*136 over rows 0-15
    float* sTriB = (float*)&sY[16][0];                    // 16*136 over rows 16-31
    int t = threadIdx.x;                          // 512 threads, 8 waves
    int lane = t & 63, wave = t >> 6;
    int e0 = blockIdx.x * FGK_EPB;

    if (wave == 0) {                              // meta load + parallel slot detect
        int sv = 0, dv = 0x7fffffff;
        if (lane < FGK_EPB) {
            sv = srcP[e0 + lane];
            dv = dstP[e0 + lane];
            sSrc[lane] = sv; sDst[lane] = dv;
        }
        int prev = __shfl_up(dv, 1);
        bool isStart = (lane < FGK_EPB) && (lane == 0 || dv != prev);
        unsigned long long mask = __ballot(isStart);
        int ns = __popcll(mask);
        if (isStart) {
            int s = (int)__popcll(mask & ((1ull << lane) - 1ull));
            sStart[s] = lane;
            sDstSlot[s] = dv;
            if (lane) sEnd[s - 1] = lane;
        }
        if (lane == 0) { sNS = ns; sEnd[ns - 1] = FGK_EPB; }
    }
    __syncthreads();                              // bar 1

    // ---- msg = relu(hinB[src] + eaP) + 1e-7 -> bf16 A-frags (hi only) ----
    {
        int el = t >> 4, b = t & 15;
        s16x8 hraw = *(const s16x8*)(hinB + (size_t)sSrc[el] * FGK_H + b * 8);
        s16x8 eraw = *(const s16x8*)(eaP + (size_t)(e0 + el) * FGK_H + b * 8);
        s16x8 hb;
#pragma unroll
        for (int jj = 0; jj < 8; ++jj) {
            float hv = fgk_u2f((unsigned short)hraw[jj]);
            float ev = fgk_u2f((unsigned short)eraw[jj]);
            float m = fmaxf(hv + ev, 0.f) + 1e-7f;
            hb[jj] = (short)fgk_f2b(m);
        }
        int c = b >> 2, g = b & 3;                // k = b*8+jj = 32c+8g+jj
        int idx = fgk_swL(c * 128 + 32 * g + el) * 8;
        *(s16x8*)&aH[idx] = hb;
    }
    __syncthreads();                              // bar 2

    // ---- y = msg @ a1w via MFMA: wave owns nt (waves 0,1 also nt 8,9);
    //      BOTH et against one B-tile stream (halves per-block L2 B traffic) ----
    {
        s16x8 ah[2][4];
#pragma unroll
        for (int et = 0; et < 2; ++et)
#pragma unroll
            for (int c = 0; c < 4; ++c) {
                int idx = fgk_swL(c * 128 + 32 * (lane >> 4) + 16 * et + (lane & 15)) * 8;
                ah[et][c] = *(const s16x8*)&aH[idx];
            }
        int n = lane & 15, qd = lane >> 4;
        int npass = (wave < 2) ? 2 : 1;
        for (int pass = 0; pass < npass; ++pass) {
            int nt = (pass == 0) ? wave : 8 + wave;
            f32x4 acc0 = {0.f, 0.f, 0.f, 0.f};
            f32x4 acc1 = {0.f, 0.f, 0.f, 0.f};
#pragma unroll
            for (int c = 0; c < 4; ++c) {
                size_t bidx = ((size_t)(nt * 4 + c) * 64 + lane) * 8;
                s16x8 bh = *(const s16x8*)(bHi + bidx);
                s16x8 bl = *(const s16x8*)(bLo + bidx);
                acc0 = __builtin_amdgcn_mfma_f32_16x16x32_bf16(ah[0][c], bl, acc0, 0, 0, 0);
                acc0 = __builtin_amdgcn_mfma_f32_16x16x32_bf16(ah[0][c], bh, acc0, 0, 0, 0);
                acc1 = __builtin_amdgcn_mfma_f32_16x16x32_bf16(ah[1][c], bl, acc1, 0, 0, 0);
                acc1 = __builtin_amdgcn_mfma_f32_16x16x32_bf16(ah[1][c], bh, acc1, 0, 0, 0);
            }
            int j = nt * 16 + n;
            if (j < FGK_F) {                       // GUARD: pad cols must not wrap
                float bias = a1b[j];
#pragma unroll
                for (int reg = 0; reg < 4; ++reg) {
                    sY[4 * qd + reg][j] = acc0[reg] + bias;
                    sY[16 + 4 * qd + reg][j] = acc1[reg] + bias;
                }
            }
        }
    }
    __syncthreads();                              // bar 3 (sY done; aH dead)

    // ---- P4: per-slot score reduce (reads all sY) + L-build half A (el 0-15) ----
    {
        {
            int s = t;                        // 512 slots: el16(16) x r(32)
            int el16 = s & 15;
            int r  = s >> 4;                  // 0..31
            int i  = r & 15, h = r >> 4;
            int pstart = 16 * i + 8 * h;
            float v[8];
            if (pstart < 120) {
                const float4* rp = (const float4*)&sY[el16][32 + pstart];
                float4 v0 = rp[0], v1 = rp[1];
                v[0] = v0.x; v[1] = v0.y; v[2] = v0.z; v[3] = v0.w;
                v[4] = v1.x; v[5] = v1.y; v[6] = v1.z; v[7] = v1.w;
            } else {
                const float4* rp = (const float4*)&sY[el16][264 - pstart];
                float4 v0 = rp[0], v1 = rp[1];
                v[0] = v1.w; v[1] = v1.z; v[2] = v1.y; v[3] = v1.x;
                v[4] = v0.w; v[5] = v0.z; v[6] = v0.y; v[7] = v0.x;
            }
            if (h == (i >> 3)) {              // diag elem at i&7
                int jd = i & 7;
                float d0 = v[jd];
                v[jd] = fmaxf(d0, 0.f) +
                        0.69314718f * log2f(1.f + exp2f(-1.44269504f * fabsf(d0)));
            }
            s16x8 hb, lb;
#pragma unroll
            for (int jj = 0; jj < 8; ++jj) {
                unsigned short hbv = fgk_f2b(v[jj]);
                hb[jj] = (short)hbv;
                lb[jj] = (short)fgk_f2b(v[jj] - fgk_u2f(hbv));
            }
            int idx = fgk_swL(el16 * 32 + i + 16 * h) * 8;
            *(s16x8*)&lH[idx] = hb;
            *(s16x8*)&lL[idx] = lb;
        }
        int el = t >> 4, d = t & 15;          // score reduce (sY all rows)
        if (el < sNS) {
            float sum = 0.f;
            for (int e2 = sStart[el]; e2 < sEnd[el]; ++e2) sum += sY[e2][d];
            atomicAdd(&snAcc[(size_t)sDstSlot[el] * FGK_P + d], sum);
        }
    }
    __syncthreads();                              // bar 4

    // ---- P5: Fe half A -> sTriA (overlays sY rows 0-15, now dead) ----
#pragma unroll
    for (int i2 = 0; i2 < 2; ++i2) {
        int el16 = wave * 2 + i2;             // 0..15
        s16x8 fh = {0, 0, 0, 0, 0, 0, 0, 0};
        s16x8 fl = {0, 0, 0, 0, 0, 0, 0, 0};
        if (lane < 32) {
            int idx = fgk_swL(el16 * 32 + lane) * 8;
            fh = *(const s16x8*)&lH[idx];
            fl = *(const s16x8*)&lL[idx];
        }
        f32x4 acc = {0.f, 0.f, 0.f, 0.f};
        acc = __builtin_amdgcn_mfma_f32_16x16x32_bf16(fh, fh, acc, 0, 0, 0);
        acc = __builtin_amdgcn_mfma_f32_16x16x32_bf16(fh, fl, acc, 0, 0, 0);
        acc = __builtin_amdgcn_mfma_f32_16x16x32_bf16(fl, fh, acc, 0, 0, 0);
        int j = lane & 15, qd = lane >> 4;
#pragma unroll
        for (int reg = 0; reg < 4; ++reg) {
            int ii = 4 * qd + reg;
            if (ii >= j) sTriA[el16 * FGK_TRI + ii * (ii + 1) / 2 + j] = acc[reg];
        }
    }
    __syncthreads();                              // bar 5 (lH/lL A consumed)

    // ---- P6: L-build half B (el 16-31; sY rows 16-31 still intact) ----
    {
        int s = t;
        int el16 = s & 15;
        int r  = s >> 4;
        int i  = r & 15, h = r >> 4;
        int pstart = 16 * i + 8 * h;
        float v[8];
        if (pstart < 120) {
            const float4* rp = (const float4*)&sY[16 + el16][32 + pstart];
            float4 v0 = rp[0], v1 = rp[1];
            v[0] = v0.x; v[1] = v0.y; v[2] = v0.z; v[3] = v0.w;
            v[4] = v1.x; v[5] = v1.y; v[6] = v1.z; v[7] = v1.w;
        } else {
            const float4* rp = (const float4*)&sY[16 + el16][264 - pstart];
            float4 v0 = rp[0], v1 = rp[1];
            v[0] = v1.w; v[1] = v1.z; v[2] = v1.y; v[3] = v1.x;
            v[4] = v0.w; v[5] = v0.z; v[6] = v0.y; v[7] = v0.x;
        }
        if (h == (i >> 3)) {
            int jd = i & 7;
            float d0 = v[jd];
            v[jd] = fmaxf(d0, 0.f) +
                    0.69314718f * log2f(1.f + exp2f(-1.44269504f * fabsf(d0)));
        }
        s16x8 hb, lb;
#pragma unroll
        for (int jj = 0; jj < 8; ++jj) {
            unsigned short hbv = fgk_f2b(v[jj]);
            hb[jj] = (short)hbv;
            lb[jj] = (short)fgk_f2b(v[jj] - fgk_u2f(hbv));
        }
        int idx = fgk_swL(el16 * 32 + i + 16 * h) * 8;
        *(s16x8*)&lH[idx] = hb;
        *(s16x8*)&lL[idx] = lb;
    }
    __syncthreads();                              // bar 6

    // ---- P7: Fe half B -> sTriB (overlays sY rows 16-31, now dead) ----
#pragma unroll
    for (int i2 = 0; i2 < 2; ++i2) {
        int el16 = wave * 2 + i2;
        s16x8 fh = {0, 0, 0, 0, 0, 0, 0, 0};
        s16x8 fl = {0, 0, 0, 0, 0, 0, 0, 0};
        if (lane < 32) {
            int idx = fgk_swL(el16 * 32 + lane) * 8;
            fh = *(const s16x8*)&lH[idx];
            fl = *(const s16x8*)&lL[idx];
        }
        f32x4 acc = {0.f, 0.f, 0.f, 0.f};
        acc = __builtin_amdgcn_mfma_f32_16x16x32_bf16(fh, fh, acc, 0, 0, 0);
        acc = __builtin_amdgcn_mfma_f32_16x16x32_bf16(fh, fl, acc, 0, 0, 0);
        acc = __builtin_amdgcn_mfma_f32_16x16x32_bf16(fl, fh, acc, 0, 0, 0);
        int j = lane & 15, qd = lane >> 4;
#pragma unroll
        for (int reg = 0; reg < 4; ++reg) {
            int ii = 4 * qd + reg;
            if (ii >= j) sTriB[el16 * FGK_TRI + ii * (ii + 1) / 2 + j] = acc[reg];
        }
    }
    __syncthreads();                              // bar 7

    // ---- per-slot tri reduction -> coalesced atomics ----
    {
        int nS = sNS;
        for (int o = t; o < nS * FGK_TRI; o += 512) {
            int s = o / FGK_TRI, p = o - s * FGK_TRI;
            float sum = 0.f;
            for (int el = sStart[s]; el < sEnd[s]; ++el) {
                const float* tb = (el < 16) ? sTriA : sTriB;
                sum += tb[(el & 15) * FGK_TRI + p];
            }
            atomicAdd(&fnAcc[(size_t)sDstSlot[s] * FGK_TRI + p], sum);
        }
    }
}

// one thread per node: fully-unrolled register Cholesky solve of (F_n+I) x = s_n
// 64-thread blocks: 313 workgroups spread over all 256 CUs
#define TA(i, j) a[(i) * ((i) + 1) / 2 + (j)]
__global__ void __launch_bounds__(64)
fgkSolve(const float* __restrict__ snAcc,
         const float* __restrict__ fnAcc,
         float* __restrict__ mleOut)
{
    int n = blockIdx.x * blockDim.x + threadIdx.x;
    if (n >= FGK_NN) return;
    float a[FGK_TRI];
    const float4* src = (const float4*)(fnAcc + (size_t)n * FGK_TRI);
#pragma unroll
    for (int p = 0; p < FGK_TRI / 4; ++p) {
        float4 v = src[p];
        a[p * 4] = v.x; a[p * 4 + 1] = v.y; a[p * 4 + 2] = v.z; a[p * 4 + 3] = v.w;
    }
#pragma unroll
    for (int i = 0; i < 16; ++i) TA(i, i) += 1.f;
#pragma unroll
    for (int k = 0; k < 16; ++k) {
        float d = sqrtf(TA(k, k));
        float inv = 1.f / d;
        TA(k, k) = d;
#pragma unroll
        for (int i = k + 1; i < 16; ++i) TA(i, k) *= inv;
#pragma unroll
        for (int j = k + 1; j < 16; ++j) {
            float ajk = TA(j, k);
#pragma unroll
            for (int i = j; i < 16; ++i) TA(i, j) -= TA(i, k) * ajk;
        }
    }
    const float* sp = snAcc + (size_t)n * FGK_P;
    float y[16], x[16];
#pragma unroll
    for (int i = 0; i < 16; ++i) {
        float acc = sp[i];
#pragma unroll
        for (int k = 0; k < 16; ++k) if (k < i) acc -= TA(i, k) * y[k];
        y[i] = acc / TA(i, i);
    }
#pragma unroll
    for (int i = 15; i >= 0; --i) {
        float acc = y[i];
#pragma unroll
        for (int k = 0; k < 16; ++k) if (k > i) acc -= TA(k, i) * x[k];
        x[i] = acc / TA(i, i);
    }
    float4* dst = (float4*)(mleOut + (size_t)n * FGK_P);
#pragma unroll
    for (int p = 0; p < 4; ++p) dst[p] = make_float4(x[p * 4], x[p * 4 + 1], x[p * 4 + 2], x[p * 4 + 3]);
}
#undef TA

// node (16 nodes/block): a2+res -> m1 MFMA -> LN -> m2 MFMA -> hout
// + fused next-layer relu(LN(hout)) -> hinNext f32 + bf16 (doNext)
__global__ void __launch_bounds__(256)
fgkNode(const float* __restrict__ hin,
        const float* __restrict__ mleIn,
        const float* __restrict__ a2w, const float* __restrict__ a2b,
        const unsigned short* __restrict__ m1H, const unsigned short* __restrict__ m1L,
        const float* __restrict__ m1b,
        const float* __restrict__ gamma, const float* __restrict__ beta,
        const unsigned short* __restrict__ m2H, const unsigned short* __restrict__ m2L,
        const float* __restrict__ m2b,
        float* __restrict__ hout, int addres,
        float* __restrict__ hinNext, unsigned short* __restrict__ hinNextB,
        const float* __restrict__ gN, const float* __restrict__ bN, int doNext)
{
    __shared__ char uniN[16384];
    __shared__ float sT[16][260];
    __shared__ float stats[16][2];
    unsigned short* ovH = (unsigned short*)uniN;
    unsigned short* ovL = (unsigned short*)uniN + 2048;
    unsigned short* t2H = (unsigned short*)uniN;
    unsigned short* t2L = (unsigned short*)uniN + 4096;
    int t = threadIdx.x, lane = t & 63, wave = t >> 6;
    int n0 = blockIdx.x * 16;

    // ---- a2 matvec + residual -> bf16 hi/lo frags (one pass, vectorized) ----
    {
        int node = t >> 4, cg = t & 15;            // 8 cols per thread
        const float4* m4 = (const float4*)(mleIn + (size_t)(n0 + node) * FGK_P);
        float4 q0 = m4[0], q1 = m4[1], q2 = m4[2], q3 = m4[3];
        float mv[16] = {q0.x, q0.y, q0.z, q0.w, q1.x, q1.y, q1.z, q1.w,
                        q2.x, q2.y, q2.z, q2.w, q3.x, q3.y, q3.z, q3.w};
        const float4* bp = (const float4*)(a2b + cg * 8);
        float4 b0 = bp[0], b1 = bp[1];
        const float4* hp = (const float4*)(hin + (size_t)(n0 + node) * FGK_H + cg * 8);
        float4 h0 = hp[0], h1 = hp[1];
        float acc[8] = {b0.x + h0.x, b0.y + h0.y, b0.z + h0.z, b0.w + h0.w,
                        b1.x + h1.x, b1.y + h1.y, b1.z + h1.z, b1.w + h1.w};
#pragma unroll
        for (int k = 0; k < 16; ++k) {
            const float4* wp = (const float4*)(a2w + k * FGK_H + cg * 8);
            float4 w0 = wp[0], w1 = wp[1];
            acc[0] += mv[k] * w0.x; acc[1] += mv[k] * w0.y;
            acc[2] += mv[k] * w0.z; acc[3] += mv[k] * w0.w;
            acc[4] += mv[k] * w1.x; acc[5] += mv[k] * w1.y;
            acc[6] += mv[k] * w1.z; acc[7] += mv[k] * w1.w;
        }
        s16x8 hb, lb;
#pragma unroll
        for (int jj = 0; jj < 8; ++jj) {
            unsigned short hbv = fgk_f2b(acc[jj]);
            hb[jj] = (short)hbv;
            lb[jj] = (short)fgk_f2b(acc[jj] - fgk_u2f(hbv));
        }
        int idx = fgk_sw(cg * 16 + node) * 8;      // u = c*64+16g+node = 16*cg+node
        *(s16x8*)&ovH[idx] = hb;
        *(s16x8*)&ovL[idx] = lb;
    }
    __syncthreads();

    {
        s16x8 ah[4], al[4];
#pragma unroll
        for (int c = 0; c < 4; ++c) {
            int idx = fgk_sw(c * 64 + lane) * 8;
            ah[c] = *(const s16x8*)&ovH[idx];
            al[c] = *(const s16x8*)&ovL[idx];
        }
        int n = lane & 15, qd = lane >> 4;
#pragma unroll
        for (int i4 = 0; i4 < 4; ++i4) {
            int nt = wave + i4 * 4;
            f32x4 acc = {0.f, 0.f, 0.f, 0.f};
#pragma unroll
            for (int c = 0; c < 4; ++c) {
                size_t bidx = ((size_t)(nt * 4 + c) * 64 + lane) * 8;
                s16x8 bh = *(const s16x8*)(m1H + bidx);
                s16x8 bl = *(const s16x8*)(m1L + bidx);
                acc = __builtin_amdgcn_mfma_f32_16x16x32_bf16(al[c], bh, acc, 0, 0, 0);
                acc = __builtin_amdgcn_mfma_f32_16x16x32_bf16(ah[c], bl, acc, 0, 0, 0);
                acc = __builtin_amdgcn_mfma_f32_16x16x32_bf16(ah[c], bh, acc, 0, 0, 0);
            }
            int j = nt * 16 + n;
            float bias = m1b[j];
#pragma unroll
            for (int reg = 0; reg < 4; ++reg)
                sT[4 * qd + reg][j] = acc[reg] + bias;
        }
    }
    __syncthreads();

    {
        int node = t >> 4, seg = t & 15;
        const float* rowp = &sT[node][seg * 16];
        float s1 = 0.f, s2 = 0.f;
#pragma unroll
        for (int k = 0; k < 16; ++k) { float v = rowp[k]; s1 += v; s2 += v * v; }
#pragma unroll
        for (int off = 8; off; off >>= 1) {
            s1 += __shfl_down(s1, off, 16);
            s2 += __shfl_down(s2, off, 16);
        }
        if (seg == 0) {
            float mu = s1 * (1.f / 256.f);
            float var = s2 * (1.f / 256.f) - mu * mu;
            stats[node][0] = mu;
            stats[node][1] = rsqrtf(var + 1e-5f);
        }
    }
    __syncthreads();

    // ---- LN + relu -> bf16 hi/lo frags (vectorized, swizzled b128 stores) ----
    {
        int node = t >> 4;
        float mu = stats[node][0], rstd = stats[node][1];
#pragma unroll
        for (int h = 0; h < 2; ++h) {
            int cg = (t & 15) + 16 * h;            // 0..31, 8 cols each
            const float4* rp = (const float4*)&sT[node][cg * 8];
            float4 v0 = rp[0], v1 = rp[1];
            const float4* gp = (const float4*)(gamma + cg * 8);
            float4 g0 = gp[0], g1 = gp[1];
            const float4* bb = (const float4*)(beta + cg * 8);
            float4 e0 = bb[0], e1 = bb[1];
            float vv[8] = {v0.x, v0.y, v0.z, v0.w, v1.x, v1.y, v1.z, v1.w};
            float gg[8] = {g0.x, g0.y, g0.z, g0.w, g1.x, g1.y, g1.z, g1.w};
            float ee[8] = {e0.x, e0.y, e0.z, e0.w, e1.x, e1.y, e1.z, e1.w};
            s16x8 hb, lb;
#pragma unroll
            for (int jj = 0; jj < 8; ++jj) {
                float tv = fmaxf((vv[jj] - mu) * rstd * gg[jj] + ee[jj], 0.f);
                unsigned short hbv = fgk_f2b(tv);
                hb[jj] = (short)hbv;
                lb[jj] = (short)fgk_f2b(tv - fgk_u2f(hbv));
            }
            int idx = fgk_sw(cg * 16 + node) * 8;
            *(s16x8*)&t2H[idx] = hb;
            *(s16x8*)&t2L[idx] = lb;
        }
    }
    __syncthreads();

    {
        s16x8 ah[8], al[8];
#pragma unroll
        for (int c = 0; c < 8; ++c) {
            int idx = fgk_sw(c * 64 + lane) * 8;
            ah[c] = *(const s16x8*)&t2H[idx];
            al[c] = *(const s16x8*)&t2L[idx];
        }
        int n = lane & 15, qd = lane >> 4;
#pragma unroll
        for (int i2 = 0; i2 < 2; ++i2) {
            int nt = wave * 2 + i2;
            f32x4 acc = {0.f, 0.f, 0.f, 0.f};
#pragma unroll
            for (int c = 0; c < 8; ++c) {
                size_t bidx = ((size_t)(nt * 8 + c) * 64 + lane) * 8;
                s16x8 bh = *(const s16x8*)(m2H + bidx);
                s16x8 bl = *(const s16x8*)(m2L + bidx);
                acc = __builtin_amdgcn_mfma_f32_16x16x32_bf16(al[c], bh, acc, 0, 0, 0);
                acc = __builtin_amdgcn_mfma_f32_16x16x32_bf16(ah[c], bl, acc, 0, 0, 0);
                acc = __builtin_amdgcn_mfma_f32_16x16x32_bf16(ah[c], bh, acc, 0, 0, 0);
            }
            int j = nt * 16 + n;
            float bias = m2b[j];
#pragma unroll
            for (int reg = 0; reg < 4; ++reg) {
                int node = 4 * qd + reg;
                size_t idx = (size_t)(n0 + node) * FGK_H + j;
                float val = acc[reg] + bias;
                float nv = addres ? (hout[idx] + val) : val;
                hout[idx] = nv;
                sT[node][j] = nv;          // park for fused next-layer LN
            }
        }
    }
    if (doNext) {                          // hinNext = relu(LN(hout, gN, bN))
        __syncthreads();
        int node = t >> 4, seg = t & 15;
        const float* rowp = &sT[node][seg * 8];
        float s1 = 0.f, s2 = 0.f;
#pragma unroll
        for (int k = 0; k < 8; ++k) { float v = rowp[k]; s1 += v; s2 += v * v; }
#pragma unroll
        for (int off = 8; off; off >>= 1) {
            s1 += __shfl_down(s1, off, 16);
            s2 += __shfl_down(s2, off, 16);
        }
        if (seg == 0) {
            float mu = s1 * (1.f / 128.f);
            float var = s2 * (1.f / 128.f) - mu * mu;
            stats[node][0] = mu;
            stats[node][1] = rsqrtf(var + 1e-5f);
        }
        __syncthreads();
        float mu = stats[node][0], rstd = stats[node][1];
#pragma unroll
        for (int kk = 0; kk < 8; ++kk) {
            int k = seg * 8 + kk;
            float v = sT[node][k];
            float nv = fmaxf((v - mu) * rstd * gN[k] + bN[k], 0.f);
            size_t oidx = (size_t)(n0 + node) * FGK_H + k;
            hinNext[oidx] = nv;
            hinNextB[oidx] = fgk_f2b(nv);
        }
    }
}

// out = relu(LN(h, g0, b0)) @ lin_w + lin_b   (f32 out)
__global__ void fgkFinal(const float* __restrict__ hsrc,
                         const float* __restrict__ gamma,
                         const float* __restrict__ beta,
                         const float* __restrict__ lw,
                         const float* __restrict__ lb,
                         float* __restrict__ outp)
{
    int n = blockIdx.x, t = threadIdx.x;   // block = 128
    __shared__ float tt[FGK_H];
    __shared__ float red[4];
    float v = hsrc[(size_t)n * FGK_H + t];
    float s1 = v, s2 = v * v;
#pragma unroll
    for (int off = 32; off; off >>= 1) { s1 += __shfl_down(s1, off); s2 += __shfl_down(s2, off); }
    int wid = t >> 6, lane = t & 63;
    if (lane == 0) { red[wid] = s1; red[2 + wid] = s2; }
    __syncthreads();
    float mu = (red[0] + red[1]) * (1.f / FGK_H);
    float var = (red[2] + red[3]) * (1.f / FGK_H) - mu * mu;
    float rstd = rsqrtf(var + 1e-5f);
    tt[t] = fmaxf((v - mu) * rstd * gamma[t] + beta[t], 0.f);
    __syncthreads();
    if (t < 112) {
        float acc = lb[t];
        for (int k = 0; k < FGK_H; k++) acc += tt[k] * lw[k * 112 + t];
        outp[(size_t)n * 112 + t] = acc;
    }
}

extern "C" void kernel_launch(void* const* d_in, const int* in_sizes, int n_in,
                              void* d_out, int out_size, void* d_ws, size_t ws_size,
                              hipStream_t stream)
{
    const float* xin  = (const float*)d_in[0];
    const float* eatt = (const float*)d_in[1];
    const int*   eidx = (const int*)d_in[2];
    const float* nEw  = (const float*)d_in[3];
    const float* nEb  = (const float*)d_in[4];
    const float* eEw  = (const float*)d_in[5];
    const float* eEb  = (const float*)d_in[6];
    const float* a1w  = (const float*)d_in[7];
    const float* a1b  = (const float*)d_in[8];
    const float* a2w  = (const float*)d_in[9];
    const float* a2b  = (const float*)d_in[10];
    const float* m1w  = (const float*)d_in[11];
    const float* m1b  = (const float*)d_in[12];
    const float* lng  = (const float*)d_in[13];
    const float* lnb  = (const float*)d_in[14];
    const float* m2w  = (const float*)d_in[15];
    const float* m2b  = (const float*)d_in[16];
    const float* ng   = (const float*)d_in[17];
    const float* nb   = (const float*)d_in[18];
    const float* lw   = (const float*)d_in[19];
    const float* lb   = (const float*)d_in[20];
    float* outp = (float*)d_out;
    const int* srcIdx = eidx;
    const int* dstIdx = eidx + FGK_NE;

    float* ws   = (float*)d_ws;
    float* hAcc = ws;                                    // NN*128
    float* hin  = hAcc + (size_t)FGK_NN * FGK_H;         // NN*128
    float* snA  = hin  + (size_t)FGK_NN * FGK_H;         // NN*16
    float* fnA  = snA  + (size_t)FGK_NN * FGK_P;         // NN*136
    float* mle  = fnA  + (size_t)FGK_NN * FGK_TRI;       // NN*16
    unsigned short* wsU = (unsigned short*)(mle + (size_t)FGK_NN * FGK_P);
    const int A1F = 40 * 512, M1F = 64 * 512, M2F = 64 * 512;
    unsigned short* a1Hi = wsU;
    unsigned short* a1Lo = a1Hi + 3 * A1F;
    unsigned short* m1Hi = a1Lo + 3 * A1F;
    unsigned short* m1Lo = m1Hi + 3 * M1F;
    unsigned short* m2Hi = m1Lo + 3 * M1F;
    unsigned short* m2Lo = m2Hi + 3 * M2F;
    int* cursor = (int*)(m2Lo + 3 * M2F);                // NN ints
    int* perm   = cursor + FGK_NN;                       // NE ints
    int* srcP   = perm + FGK_NE;                         // NE ints (perm-ordered src)
    int* dstP   = srcP + FGK_NE;                         // NE ints (perm-ordered dst)
    unsigned short* hinB = (unsigned short*)(dstP + FGK_NE);   // NN*128 bf16
    unsigned short* eaP  = hinB + (size_t)FGK_NN * FGK_H;      // NE*128 bf16 (82 MB)

    // dst-sorted edge permutation (edge_index constant; rebuilt every launch)
    fgkZeroI<<<(FGK_NN + 255) / 256, 256, 0, stream>>>(cursor, FGK_NN);
    fgkHist<<<(FGK_NE + 255) / 256, 256, 0, stream>>>(dstIdx, cursor);
    fgkScan<<<1, 1024, 0, stream>>>(cursor, cursor);     // in-place exclusive scan
    fgkScatterE<<<(FGK_NE + 255) / 256, 256, 0, stream>>>(dstIdx, srcIdx, cursor,
                                                          perm, srcP, dstP);
    // one-time layer-invariant edge encoding, perm-ordered bf16
    fgkEncE<<<FGK_NE / 16, 256, 0, stream>>>(eatt, perm, eEw, eEb, eaP);

    for (int l = 0; l < 3; l++) {
        fgkPrepW<<<40, 64, 0, stream>>>(a1w + (size_t)l * FGK_H * FGK_F, 128, 152,
                                        a1Hi + l * A1F, a1Lo + l * A1F);
        fgkPrepW<<<64, 64, 0, stream>>>(m1w + (size_t)l * FGK_H * 256, 128, 256,
                                        m1Hi + l * M1F, m1Lo + l * M1F);
        fgkPrepW<<<64, 64, 0, stream>>>(m2w + (size_t)l * 256 * FGK_H, 256, 128,
                                        m2Hi + l * M2F, m2Lo + l * M2F);
    }
    fgkEnc<<<(FGK_NN * FGK_H + 255) / 256, 256, 0, stream>>>(xin, nEw, nEb, hin, hinB);
    for (int l = 0; l < 3; l++) {
        fgkZero<<<(FGK_NN * (FGK_P + FGK_TRI) + 255) / 256, 256, 0, stream>>>(snA);
        fgkEdge<<<FGK_NE / FGK_EPB, 512, 0, stream>>>(srcP, dstP, eaP,
            a1Hi + l * A1F, a1Lo + l * A1F, a1b + (size_t)l * FGK_F, hinB, snA, fnA);
        fgkSolve<<<(FGK_NN + 63) / 64, 64, 0, stream>>>(snA, fnA, mle);
        fgkNode<<<FGK_NN / 16, 256, 0, stream>>>(hin, mle,
            a2w + (size_t)l * FGK_P * FGK_H, a2b + (size_t)l * FGK_H,
            m1Hi + l * M1F, m1Lo + l * M1F, m1b + (size_t)l * 256,
            lng + (size_t)l * 256, lnb + (size_t)l * 256,
            m2Hi + l * M2F, m2Lo + l * M2F, m2b + (size_t)l * FGK_H,
            hAcc, l > 0 ? 1 : 0,
            hin, hinB, ng + (l + 1) * FGK_H, nb + (l + 1) * FGK_H, l < 2 ? 1 : 0);
    }
    fgkFinal<<<FGK_NN, FGK_H, 0, stream>>>(hAcc, ng, nb, lw, lb, outp);
}

// Round 15
// 697.309 us; speedup vs baseline: 1.1982x; 1.0435x over previous
//
#include <hip/hip_runtime.h>
#include <cmath>
#include <cstddef>

#define FGK_NN   20000
#define FGK_NE   320000
#define FGK_H    128
#define FGK_P    16
#define FGK_TRI  136
#define FGK_F    152
#define FGK_EPB  32
#define FGK_YP   156          // sY row stride (>=152, 16B-aligned rows, 28 mod 32)

typedef short  s16x8 __attribute__((ext_vector_type(8)));
typedef float  f32x4 __attribute__((ext_vector_type(4)));

__device__ __forceinline__ unsigned short fgk_f2b(float f) {   // RNE f32->bf16 (native cvt)
    __bf16 b = (__bf16)f;
    return __builtin_bit_cast(unsigned short, b);
}
__device__ __forceinline__ float fgk_u2f(unsigned short u) {
    return __uint_as_float(((unsigned int)u) << 16);
}
// bank-conflict swizzles on 16B-unit index (bijective XOR of high bits into group bits)
__device__ __forceinline__ int fgk_sw(int u)  { return u ^ ((u >> 4) & 7); }  // node-kernel pattern
__device__ __forceinline__ int fgk_swL(int u) { return u ^ ((u >> 5) & 7); }  // edge-kernel pattern

__global__ void FishnetGCN_62096637165586_kernel() {}

__global__ void fgkZero(float* acc) {
    int i = blockIdx.x * blockDim.x + threadIdx.x;
    if (i < FGK_NN * (FGK_P + FGK_TRI)) acc[i] = 0.f;
}
__global__ void fgkZeroI(int* p, int n) {
    int i = blockIdx.x * blockDim.x + threadIdx.x;
    if (i < n) p[i] = 0;
}
// ---- dst-sort: histogram -> block scan -> scatter (edge_index constant) ----
__global__ void fgkHist(const int* __restrict__ dst, int* __restrict__ hist) {
    int e = blockIdx.x * blockDim.x + threadIdx.x;
    if (e < FGK_NE) atomicAdd(&hist[dst[e]], 1);
}
__global__ void fgkScan(const int* __restrict__ hist, int* __restrict__ cursor)
{
    __shared__ int sWave[16];
    __shared__ int sRun;
    int t = threadIdx.x;             // 1024
    int lane = t & 63, wv = t >> 6;
    if (t == 0) sRun = 0;
    __syncthreads();
    for (int base = 0; base < FGK_NN; base += 1024) {
        int idx = base + t;
        int v = (idx < FGK_NN) ? hist[idx] : 0;
        int sc = v;
#pragma unroll
        for (int off = 1; off < 64; off <<= 1) {
            int u = __shfl_up(sc, off);
            if (lane >= off) sc += u;
        }
        if (lane == 63) sWave[wv] = sc;
        __syncthreads();
        if (wv == 0 && lane < 16) {
            int w = sWave[lane];
#pragma unroll
            for (int off = 1; off < 16; off <<= 1) {
                int u = __shfl_up(w, off, 16);
                if (lane >= off) w += u;
            }
            sWave[lane] = w;
        }
        __syncthreads();
        int waveOff = (wv == 0) ? 0 : sWave[wv - 1];
        int run = sRun;
        if (idx < FGK_NN) cursor[idx] = run + waveOff + sc - v;   // exclusive
        __syncthreads();
        if (t == 1023) sRun = run + sWave[15];
        __syncthreads();
    }
}
// scatter + emit perm-ordered src/dst arrays (removes double-indirection later)
__global__ void fgkScatterE(const int* __restrict__ dst, const int* __restrict__ src,
                            int* __restrict__ cursor, int* __restrict__ perm,
                            int* __restrict__ srcP, int* __restrict__ dstP) {
    int e = blockIdx.x * blockDim.x + threadIdx.x;
    if (e < FGK_NE) {
        int d = dst[e];
        int pos = atomicAdd(&cursor[d], 1);
        perm[pos] = e;
        srcP[pos] = src[e];
        dstP[pos] = d;
    }
}

// One-time, layer-invariant: eaP[pos] = bf16(eatt[perm[pos]] @ eew + eeb), perm order.
// 256 threads: thread = (pos in 16-group, 8-col group)
__global__ void fgkEncE(const float* __restrict__ eatt,
                        const int* __restrict__ perm,
                        const float* __restrict__ eew,
                        const float* __restrict__ eeb,
                        unsigned short* __restrict__ eaP)
{
    int pos = blockIdx.x * 16 + (threadIdx.x >> 4);
    int b = threadIdx.x & 15;
    int e = perm[pos];
    const float4* ap = (const float4*)(eatt + (size_t)e * 8);
    float4 a0 = ap[0], a1 = ap[1];
    float av[8] = {a0.x, a0.y, a0.z, a0.w, a1.x, a1.y, a1.z, a1.w};
    const float4* bp = (const float4*)(eeb + b * 8);
    float4 b0 = bp[0], b1 = bp[1];
    float acc[8] = {b0.x, b0.y, b0.z, b0.w, b1.x, b1.y, b1.z, b1.w};
#pragma unroll
    for (int kk = 0; kk < 8; ++kk) {
        const float4* wp = (const float4*)(eew + kk * FGK_H + b * 8);
        float4 w0 = wp[0], w1 = wp[1];
        acc[0] += av[kk] * w0.x; acc[1] += av[kk] * w0.y;
        acc[2] += av[kk] * w0.z; acc[3] += av[kk] * w0.w;
        acc[4] += av[kk] * w1.x; acc[5] += av[kk] * w1.y;
        acc[6] += av[kk] * w1.z; acc[7] += av[kk] * w1.w;
    }
    s16x8 r;
#pragma unroll
    for (int jj = 0; jj < 8; ++jj) r[jj] = (short)fgk_f2b(acc[jj]);
    *(s16x8*)&eaP[(size_t)pos * FGK_H + b * 8] = r;
}

// Generic prepack of W[K,N] (row-major) into MFMA B-fragment order, bf16 hi/lo.
__global__ void fgkPrepW(const float* __restrict__ W, int K, int N,
                         unsigned short* __restrict__ hi,
                         unsigned short* __restrict__ lo)
{
    int chunks = K >> 5;
    int b = blockIdx.x;
    int nt = b / chunks, c = b - nt * chunks;
    int lane = threadIdx.x;
    int n = nt * 16 + (lane & 15);
    int g = lane >> 4;
    size_t base = ((size_t)b * 64 + lane) * 8;
#pragma unroll
    for (int j = 0; j < 8; ++j) {
        int k = c * 32 + g * 8 + j;
        float v = (n < N) ? W[(size_t)k * N + n] : 0.f;
        unsigned short hb = fgk_f2b(v);
        unsigned short lb = fgk_f2b(v - fgk_u2f(hb));
        hi[base + j] = hb;
        lo[base + j] = lb;
    }
}

// hin = x @ W[8,128] + b   (f32 + bf16 gather copy)
__global__ void fgkEnc(const float* __restrict__ xin,
                       const float* __restrict__ wenc,
                       const float* __restrict__ benc,
                       float* __restrict__ hin,
                       unsigned short* __restrict__ hinB)
{
    int idx = blockIdx.x * blockDim.x + threadIdx.x;
    if (idx >= FGK_NN * FGK_H) return;
    int n = idx >> 7, j = idx & 127;
    float acc = benc[j];
    const float* xp = xin + (size_t)n * 8;
#pragma unroll
    for (int k = 0; k < 8; k++) acc += xp[k] * wenc[k * FGK_H + j];
    hin[idx] = acc;
    hinB[idx] = fgk_f2b(acc);
}

// edge (sorted by dst), 32 edges/block, 512 threads, ~37 KB LDS (4 blocks/CU):
// msg (A hi only) ; y=MFMA (wave owns nt, both et per B-tile) ; then per-16-edge
// halves: L-build -> Fe=MFMA, sTri overlays that half's dead sY rows.  7 barriers.
__global__ void __launch_bounds__(512, 4)
fgkEdge(const int* __restrict__ srcP,
        const int* __restrict__ dstP,
        const unsigned short* __restrict__ eaP,
        const unsigned short* __restrict__ bHi,
        const unsigned short* __restrict__ bLo,
        const float* __restrict__ a1b,
        const unsigned short* __restrict__ hinB,
        float* __restrict__ snAcc,
        float* __restrict__ fnAcc)
{
    __shared__ float uni[4096];                   // 16 KB: aH (8K); lH/lL (8K+8K)
    __shared__ float sY[FGK_EPB][FGK_YP];         // 19.9 KB: y; halves -> sTri
    __shared__ int sSrc[FGK_EPB], sDst[FGK_EPB];
    __shared__ int sStart[FGK_EPB], sEnd[FGK_EPB], sDstSlot[FGK_EPB];
    __shared__ int sNS;
    unsigned short* aH = (unsigned short*)uni;            // 4096 us (8 KB)
    unsigned short* lH = (unsigned short*)uni;            // 4096 us (per-half)
    unsigned short* lL = (unsigned short*)uni + 4096;     // 4096 us (per-half)
    float* sTriA = (float*)sY;                            // 16*136 over rows 0-15
    float* sTriB = (float*)&sY[16][0];                    // 16*136 over rows 16-31
    int t = threadIdx.x;                          // 512 threads, 8 waves
    int lane = t & 63, wave = t >> 6;
    int e0 = blockIdx.x * FGK_EPB;

    if (wave == 0) {                              // meta load + parallel slot detect
        int sv = 0, dv = 0x7fffffff;
        if (lane < FGK_EPB) {
            sv = srcP[e0 + lane];
            dv = dstP[e0 + lane];
            sSrc[lane] = sv; sDst[lane] = dv;
        }
        int prev = __shfl_up(dv, 1);
        bool isStart = (lane < FGK_EPB) && (lane == 0 || dv != prev);
        unsigned long long mask = __ballot(isStart);
        int ns = __popcll(mask);
        if (isStart) {
            int s = (int)__popcll(mask & ((1ull << lane) - 1ull));
            sStart[s] = lane;
            sDstSlot[s] = dv;
            if (lane) sEnd[s - 1] = lane;
        }
        if (lane == 0) { sNS = ns; sEnd[ns - 1] = FGK_EPB; }
    }
    __syncthreads();                              // bar 1

    // ---- msg = relu(hinB[src] + eaP) + 1e-7 -> bf16 A-frags (hi only) ----
    {
        int el = t >> 4, b = t & 15;
        s16x8 hraw = *(const s16x8*)(hinB + (size_t)sSrc[el] * FGK_H + b * 8);
        s16x8 eraw = *(const s16x8*)(eaP + (size_t)(e0 + el) * FGK_H + b * 8);
        s16x8 hb;
#pragma unroll
        for (int jj = 0; jj < 8; ++jj) {
            float hv = fgk_u2f((unsigned short)hraw[jj]);
            float ev = fgk_u2f((unsigned short)eraw[jj]);
            float m = fmaxf(hv + ev, 0.f) + 1e-7f;
            hb[jj] = (short)fgk_f2b(m);
        }
        int c = b >> 2, g = b & 3;                // k = b*8+jj = 32c+8g+jj
        int idx = fgk_swL(c * 128 + 32 * g + el) * 8;
        *(s16x8*)&aH[idx] = hb;
    }
    __syncthreads();                              // bar 2

    // ---- y = msg @ a1w via MFMA: wave owns nt (waves 0,1 also nt 8,9);
    //      BOTH et against one B-tile stream (halves per-block L2 B traffic) ----
    {
        s16x8 ah[2][4];
#pragma unroll
        for (int et = 0; et < 2; ++et)
#pragma unroll
            for (int c = 0; c < 4; ++c) {
                int idx = fgk_swL(c * 128 + 32 * (lane >> 4) + 16 * et + (lane & 15)) * 8;
                ah[et][c] = *(const s16x8*)&aH[idx];
            }
        int n = lane & 15, qd = lane >> 4;
        int npass = (wave < 2) ? 2 : 1;
        for (int pass = 0; pass < npass; ++pass) {
            int nt = (pass == 0) ? wave : 8 + wave;
            f32x4 acc0 = {0.f, 0.f, 0.f, 0.f};
            f32x4 acc1 = {0.f, 0.f, 0.f, 0.f};
#pragma unroll
            for (int c = 0; c < 4; ++c) {
                size_t bidx = ((size_t)(nt * 4 + c) * 64 + lane) * 8;
                s16x8 bh = *(const s16x8*)(bHi + bidx);
                s16x8 bl = *(const s16x8*)(bLo + bidx);
                acc0 = __builtin_amdgcn_mfma_f32_16x16x32_bf16(ah[0][c], bl, acc0, 0, 0, 0);
                acc0 = __builtin_amdgcn_mfma_f32_16x16x32_bf16(ah[0][c], bh, acc0, 0, 0, 0);
                acc1 = __builtin_amdgcn_mfma_f32_16x16x32_bf16(ah[1][c], bl, acc1, 0, 0, 0);
                acc1 = __builtin_amdgcn_mfma_f32_16x16x32_bf16(ah[1][c], bh, acc1, 0, 0, 0);
            }
            int j = nt * 16 + n;
            if (j < FGK_F) {                       // GUARD: pad cols must not wrap
                float bias = a1b[j];
#pragma unroll
                for (int reg = 0; reg < 4; ++reg) {
                    sY[4 * qd + reg][j] = acc0[reg] + bias;
                    sY[16 + 4 * qd + reg][j] = acc1[reg] + bias;
                }
            }
        }
    }
    __syncthreads();                              // bar 3 (sY done; aH dead)

    // ---- P4: per-slot score reduce (reads all sY) + L-build half A (el 0-15) ----
    {
        {
            int s = t;                        // 512 slots: el16(16) x r(32)
            int el16 = s & 15;
            int r  = s >> 4;                  // 0..31
            int i  = r & 15, h = r >> 4;
            int pstart = 16 * i + 8 * h;
            float v[8];
            if (pstart < 120) {
                const float4* rp = (const float4*)&sY[el16][32 + pstart];
                float4 v0 = rp[0], v1 = rp[1];
                v[0] = v0.x; v[1] = v0.y; v[2] = v0.z; v[3] = v0.w;
                v[4] = v1.x; v[5] = v1.y; v[6] = v1.z; v[7] = v1.w;
            } else {
                const float4* rp = (const float4*)&sY[el16][264 - pstart];
                float4 v0 = rp[0], v1 = rp[1];
                v[0] = v1.w; v[1] = v1.z; v[2] = v1.y; v[3] = v1.x;
                v[4] = v0.w; v[5] = v0.z; v[6] = v0.y; v[7] = v0.x;
            }
            if (h == (i >> 3)) {              // diag elem at i&7
                int jd = i & 7;
                float d0 = v[jd];
                v[jd] = fmaxf(d0, 0.f) +
                        0.69314718f * log2f(1.f + exp2f(-1.44269504f * fabsf(d0)));
            }
            s16x8 hb, lb;
#pragma unroll
            for (int jj = 0; jj < 8; ++jj) {
                unsigned short hbv = fgk_f2b(v[jj]);
                hb[jj] = (short)hbv;
                lb[jj] = (short)fgk_f2b(v[jj] - fgk_u2f(hbv));
            }
            int idx = fgk_swL(el16 * 32 + i + 16 * h) * 8;
            *(s16x8*)&lH[idx] = hb;
            *(s16x8*)&lL[idx] = lb;
        }
        int el = t >> 4, d = t & 15;          // score reduce (sY all rows)
        if (el < sNS) {
            float sum = 0.f;
            for (int e2 = sStart[el]; e2 < sEnd[el]; ++e2) sum += sY[e2][d];
            atomicAdd(&snAcc[(size_t)sDstSlot[el] * FGK_P + d], sum);
        }
    }
    __syncthreads();                              // bar 4

    // ---- P5: Fe half A -> sTriA (overlays sY rows 0-15, now dead) ----
#pragma unroll
    for (int i2 = 0; i2 < 2; ++i2) {
        int el16 = wave * 2 + i2;             // 0..15
        s16x8 fh = {0, 0, 0, 0, 0, 0, 0, 0};
        s16x8 fl = {0, 0, 0, 0, 0, 0, 0, 0};
        if (lane < 32) {
            int idx = fgk_swL(el16 * 32 + lane) * 8;
            fh = *(const s16x8*)&lH[idx];
            fl = *(const s16x8*)&lL[idx];
        }
        f32x4 acc = {0.f, 0.f, 0.f, 0.f};
        acc = __builtin_amdgcn_mfma_f32_16x16x32_bf16(fh, fh, acc, 0, 0, 0);
        acc = __builtin_amdgcn_mfma_f32_16x16x32_bf16(fh, fl, acc, 0, 0, 0);
        acc = __builtin_amdgcn_mfma_f32_16x16x32_bf16(fl, fh, acc, 0, 0, 0);
        int j = lane & 15, qd = lane >> 4;
#pragma unroll
        for (int reg = 0; reg < 4; ++reg) {
            int ii = 4 * qd + reg;
            if (ii >= j) sTriA[el16 * FGK_TRI + ii * (ii + 1) / 2 + j] = acc[reg];
        }
    }
    __syncthreads();                              // bar 5 (lH/lL A consumed)

    // ---- P6: L-build half B (el 16-31; sY rows 16-31 still intact) ----
    {
        int s = t;
        int el16 = s & 15;
        int r  = s >> 4;
        int i  = r & 15, h = r >> 4;
        int pstart = 16 * i + 8 * h;
        float v[8];
        if (pstart < 120) {
            const float4* rp = (const float4*)&sY[16 + el16][32 + pstart];
            float4 v0 = rp[0], v1 = rp[1];
            v[0] = v0.x; v[1] = v0.y; v[2] = v0.z; v[3] = v0.w;
            v[4] = v1.x; v[5] = v1.y; v[6] = v1.z; v[7] = v1.w;
        } else {
            const float4* rp = (const float4*)&sY[16 + el16][264 - pstart];
            float4 v0 = rp[0], v1 = rp[1];
            v[0] = v1.w; v[1] = v1.z; v[2] = v1.y; v[3] = v1.x;
            v[4] = v0.w; v[5] = v0.z; v[6] = v0.y; v[7] = v0.x;
        }
        if (h == (i >> 3)) {
            int jd = i & 7;
            float d0 = v[jd];
            v[jd] = fmaxf(d0, 0.f) +
                    0.69314718f * log2f(1.f + exp2f(-1.44269504f * fabsf(d0)));
        }
        s16x8 hb, lb;
#pragma unroll
        for (int jj = 0; jj < 8; ++jj) {
            unsigned short hbv = fgk_f2b(v[jj]);
            hb[jj] = (short)hbv;
            lb[jj] = (short)fgk_f2b(v[jj] - fgk_u2f(hbv));
        }
        int idx = fgk_swL(el16 * 32 + i + 16 * h) * 8;
        *(s16x8*)&lH[idx] = hb;
        *(s16x8*)&lL[idx] = lb;
    }
    __syncthreads();                              // bar 6

    // ---- P7: Fe half B -> sTriB (overlays sY rows 16-31, now dead) ----
#pragma unroll
    for (int i2 = 0; i2 < 2; ++i2) {
        int el16 = wave * 2 + i2;
        s16x8 fh = {0, 0, 0, 0, 0, 0, 0, 0};
        s16x8 fl = {0, 0, 0, 0, 0, 0, 0, 0};
        if (lane < 32) {
            int idx = fgk_swL(el16 * 32 + lane) * 8;
            fh = *(const s16x8*)&lH[idx];
            fl = *(const s16x8*)&lL[idx];
        }
        f32x4 acc = {0.f, 0.f, 0.f, 0.f};
        acc = __builtin_amdgcn_mfma_f32_16x16x32_bf16(fh, fh, acc, 0, 0, 0);
        acc = __builtin_amdgcn_mfma_f32_16x16x32_bf16(fh, fl, acc, 0, 0, 0);
        acc = __builtin_amdgcn_mfma_f32_16x16x32_bf16(fl, fh, acc, 0, 0, 0);
        int j = lane & 15, qd = lane >> 4;
#pragma unroll
        for (int reg = 0; reg < 4; ++reg) {
            int ii = 4 * qd + reg;
            if (ii >= j) sTriB[el16 * FGK_TRI + ii * (ii + 1) / 2 + j] = acc[reg];
        }
    }
    __syncthreads();                              // bar 7

    // ---- per-slot tri reduction -> coalesced atomics ----
    {
        int nS = sNS;
        for (int o = t; o < nS * FGK_TRI; o += 512) {
            int s = o / FGK_TRI, p = o - s * FGK_TRI;
            float sum = 0.f;
            for (int el = sStart[s]; el < sEnd[s]; ++el) {
                const float* tb = (el < 16) ? sTriA : sTriB;
                sum += tb[(el & 15) * FGK_TRI + p];
            }
            atomicAdd(&fnAcc[(size_t)sDstSlot[s] * FGK_TRI + p], sum);
        }
    }
}

// one thread per node: fully-unrolled register Cholesky solve of (F_n+I) x = s_n
// 64-thread blocks: 313 workgroups spread over all 256 CUs
#define TA(i, j) a[(i) * ((i) + 1) / 2 + (j)]
__global__ void __launch_bounds__(64)
fgkSolve(const float* __restrict__ snAcc,
         const float* __restrict__ fnAcc,
         float* __restrict__ mleOut)
{
    int n = blockIdx.x * blockDim.x + threadIdx.x;
    if (n >= FGK_NN) return;
    float a[FGK_TRI];
    const float4* src = (const float4*)(fnAcc + (size_t)n * FGK_TRI);
#pragma unroll
    for (int p = 0; p < FGK_TRI / 4; ++p) {
        float4 v = src[p];
        a[p * 4] = v.x; a[p * 4 + 1] = v.y; a[p * 4 + 2] = v.z; a[p * 4 + 3] = v.w;
    }
#pragma unroll
    for (int i = 0; i < 16; ++i) TA(i, i) += 1.f;
#pragma unroll
    for (int k = 0; k < 16; ++k) {
        float d = sqrtf(TA(k, k));
        float inv = 1.f / d;
        TA(k, k) = d;
#pragma unroll
        for (int i = k + 1; i < 16; ++i) TA(i, k) *= inv;
#pragma unroll
        for (int j = k + 1; j < 16; ++j) {
            float ajk = TA(j, k);
#pragma unroll
            for (int i = j; i < 16; ++i) TA(i, j) -= TA(i, k) * ajk;
        }
    }
    const float* sp = snAcc + (size_t)n * FGK_P;
    float y[16], x[16];
#pragma unroll
    for (int i = 0; i < 16; ++i) {
        float acc = sp[i];
#pragma unroll
        for (int k = 0; k < 16; ++k) if (k < i) acc -= TA(i, k) * y[k];
        y[i] = acc / TA(i, i);
    }
#pragma unroll
    for (int i = 15; i >= 0; --i) {
        float acc = y[i];
#pragma unroll
        for (int k = 0; k < 16; ++k) if (k > i) acc -= TA(k, i) * x[k];
        x[i] = acc / TA(i, i);
    }
    float4* dst = (float4*)(mleOut + (size_t)n * FGK_P);
#pragma unroll
    for (int p = 0; p < 4; ++p) dst[p] = make_float4(x[p * 4], x[p * 4 + 1], x[p * 4 + 2], x[p * 4 + 3]);
}
#undef TA

// node (16 nodes/block): a2+res -> m1 MFMA -> LN -> m2 MFMA -> hout
// + fused next-layer relu(LN(hout)) -> hinNext f32 + bf16 (doNext)
// HI-ONLY fragments (A-hi x B-hi, single MFMA): ~25 KB LDS, 1/3 the MFMA
__global__ void __launch_bounds__(256)
fgkNode(const float* __restrict__ hin,
        const float* __restrict__ mleIn,
        const float* __restrict__ a2w, const float* __restrict__ a2b,
        const unsigned short* __restrict__ m1H, const unsigned short* __restrict__ m1L,
        const float* __restrict__ m1b,
        const float* __restrict__ gamma, const float* __restrict__ beta,
        const unsigned short* __restrict__ m2H, const unsigned short* __restrict__ m2L,
        const float* __restrict__ m2b,
        float* __restrict__ hout, int addres,
        float* __restrict__ hinNext, unsigned short* __restrict__ hinNextB,
        const float* __restrict__ gN, const float* __restrict__ bN, int doNext)
{
    __shared__ char uniN[8192];                // ovH (4 KB) then t2H (8 KB)
    __shared__ float sT[16][260];
    __shared__ float stats[16][2];
    unsigned short* ovH = (unsigned short*)uniN;   // 2048 us
    unsigned short* t2H = (unsigned short*)uniN;   // 4096 us (after reuse)
    int t = threadIdx.x, lane = t & 63, wave = t >> 6;
    int n0 = blockIdx.x * 16;

    // ---- a2 matvec + residual -> bf16 hi frags (one pass, vectorized) ----
    {
        int node = t >> 4, cg = t & 15;            // 8 cols per thread
        const float4* m4 = (const float4*)(mleIn + (size_t)(n0 + node) * FGK_P);
        float4 q0 = m4[0], q1 = m4[1], q2 = m4[2], q3 = m4[3];
        float mv[16] = {q0.x, q0.y, q0.z, q0.w, q1.x, q1.y, q1.z, q1.w,
                        q2.x, q2.y, q2.z, q2.w, q3.x, q3.y, q3.z, q3.w};
        const float4* bp = (const float4*)(a2b + cg * 8);
        float4 b0 = bp[0], b1 = bp[1];
        const float4* hp = (const float4*)(hin + (size_t)(n0 + node) * FGK_H + cg * 8);
        float4 h0 = hp[0], h1 = hp[1];
        float acc[8] = {b0.x + h0.x, b0.y + h0.y, b0.z + h0.z, b0.w + h0.w,
                        b1.x + h1.x, b1.y + h1.y, b1.z + h1.z, b1.w + h1.w};
#pragma unroll
        for (int k = 0; k < 16; ++k) {
            const float4* wp = (const float4*)(a2w + k * FGK_H + cg * 8);
            float4 w0 = wp[0], w1 = wp[1];
            acc[0] += mv[k] * w0.x; acc[1] += mv[k] * w0.y;
            acc[2] += mv[k] * w0.z; acc[3] += mv[k] * w0.w;
            acc[4] += mv[k] * w1.x; acc[5] += mv[k] * w1.y;
            acc[6] += mv[k] * w1.z; acc[7] += mv[k] * w1.w;
        }
        s16x8 hb;
#pragma unroll
        for (int jj = 0; jj < 8; ++jj) hb[jj] = (short)fgk_f2b(acc[jj]);
        int idx = fgk_sw(cg * 16 + node) * 8;      // u = c*64+16g+node = 16*cg+node
        *(s16x8*)&ovH[idx] = hb;
    }
    __syncthreads();

    // ---- m1 = A-hi @ m1H (single MFMA per c) ----
    {
        s16x8 ah[4];
#pragma unroll
        for (int c = 0; c < 4; ++c) {
            int idx = fgk_sw(c * 64 + lane) * 8;
            ah[c] = *(const s16x8*)&ovH[idx];
        }
        int n = lane & 15, qd = lane >> 4;
#pragma unroll
        for (int i4 = 0; i4 < 4; ++i4) {
            int nt = wave + i4 * 4;
            f32x4 acc = {0.f, 0.f, 0.f, 0.f};
#pragma unroll
            for (int c = 0; c < 4; ++c) {
                size_t bidx = ((size_t)(nt * 4 + c) * 64 + lane) * 8;
                s16x8 bh = *(const s16x8*)(m1H + bidx);
                acc = __builtin_amdgcn_mfma_f32_16x16x32_bf16(ah[c], bh, acc, 0, 0, 0);
            }
            int j = nt * 16 + n;
            float bias = m1b[j];
#pragma unroll
            for (int reg = 0; reg < 4; ++reg)
                sT[4 * qd + reg][j] = acc[reg] + bias;
        }
    }
    __syncthreads();

    {
        int node = t >> 4, seg = t & 15;
        const float* rowp = &sT[node][seg * 16];
        float s1 = 0.f, s2 = 0.f;
#pragma unroll
        for (int k = 0; k < 16; ++k) { float v = rowp[k]; s1 += v; s2 += v * v; }
#pragma unroll
        for (int off = 8; off; off >>= 1) {
            s1 += __shfl_down(s1, off, 16);
            s2 += __shfl_down(s2, off, 16);
        }
        if (seg == 0) {
            float mu = s1 * (1.f / 256.f);
            float var = s2 * (1.f / 256.f) - mu * mu;
            stats[node][0] = mu;
            stats[node][1] = rsqrtf(var + 1e-5f);
        }
    }
    __syncthreads();

    // ---- LN + relu -> bf16 hi frags (vectorized, swizzled b128 stores) ----
    {
        int node = t >> 4;
        float mu = stats[node][0], rstd = stats[node][1];
#pragma unroll
        for (int h = 0; h < 2; ++h) {
            int cg = (t & 15) + 16 * h;            // 0..31, 8 cols each
            const float4* rp = (const float4*)&sT[node][cg * 8];
            float4 v0 = rp[0], v1 = rp[1];
            const float4* gp = (const float4*)(gamma + cg * 8);
            float4 g0 = gp[0], g1 = gp[1];
            const float4* bb = (const float4*)(beta + cg * 8);
            float4 e0 = bb[0], e1 = bb[1];
            float vv[8] = {v0.x, v0.y, v0.z, v0.w, v1.x, v1.y, v1.z, v1.w};
            float gg[8] = {g0.x, g0.y, g0.z, g0.w, g1.x, g1.y, g1.z, g1.w};
            float ee[8] = {e0.x, e0.y, e0.z, e0.w, e1.x, e1.y, e1.z, e1.w};
            s16x8 hb;
#pragma unroll
            for (int jj = 0; jj < 8; ++jj) {
                float tv = fmaxf((vv[jj] - mu) * rstd * gg[jj] + ee[jj], 0.f);
                hb[jj] = (short)fgk_f2b(tv);
            }
            int idx = fgk_sw(cg * 16 + node) * 8;
            *(s16x8*)&t2H[idx] = hb;
        }
    }
    __syncthreads();

    // ---- m2 = A-hi @ m2H (single MFMA per c) ----
    {
        s16x8 ah[8];
#pragma unroll
        for (int c = 0; c < 8; ++c) {
            int idx = fgk_sw(c * 64 + lane) * 8;
            ah[c] = *(const s16x8*)&t2H[idx];
        }
        int n = lane & 15, qd = lane >> 4;
#pragma unroll
        for (int i2 = 0; i2 < 2; ++i2) {
            int nt = wave * 2 + i2;
            f32x4 acc = {0.f, 0.f, 0.f, 0.f};
#pragma unroll
            for (int c = 0; c < 8; ++c) {
                size_t bidx = ((size_t)(nt * 8 + c) * 64 + lane) * 8;
                s16x8 bh = *(const s16x8*)(m2H + bidx);
                acc = __builtin_amdgcn_mfma_f32_16x16x32_bf16(ah[c], bh, acc, 0, 0, 0);
            }
            int j = nt * 16 + n;
            float bias = m2b[j];
#pragma unroll
            for (int reg = 0; reg < 4; ++reg) {
                int node = 4 * qd + reg;
                size_t idx = (size_t)(n0 + node) * FGK_H + j;
                float val = acc[reg] + bias;
                float nv = addres ? (hout[idx] + val) : val;
                hout[idx] = nv;
                sT[node][j] = nv;          // park for fused next-layer LN
            }
        }
    }
    if (doNext) {                          // hinNext = relu(LN(hout, gN, bN))
        __syncthreads();
        int node = t >> 4, seg = t & 15;
        const float* rowp = &sT[node][seg * 8];
        float s1 = 0.f, s2 = 0.f;
#pragma unroll
        for (int k = 0; k < 8; ++k) { float v = rowp[k]; s1 += v; s2 += v * v; }
#pragma unroll
        for (int off = 8; off; off >>= 1) {
            s1 += __shfl_down(s1, off, 16);
            s2 += __shfl_down(s2, off, 16);
        }
        if (seg == 0) {
            float mu = s1 * (1.f / 128.f);
            float var = s2 * (1.f / 128.f) - mu * mu;
            stats[node][0] = mu;
            stats[node][1] = rsqrtf(var + 1e-5f);
        }
        __syncthreads();
        float mu = stats[node][0], rstd = stats[node][1];
#pragma unroll
        for (int kk = 0; kk < 8; ++kk) {
            int k = seg * 8 + kk;
            float v = sT[node][k];
            float nv = fmaxf((v - mu) * rstd * gN[k] + bN[k], 0.f);
            size_t oidx = (size_t)(n0 + node) * FGK_H + k;
            hinNext[oidx] = nv;
            hinNextB[oidx] = fgk_f2b(nv);
        }
    }
}

// out = relu(LN(h, g0, b0)) @ lin_w + lin_b   (f32 out)
__global__ void fgkFinal(const float* __restrict__ hsrc,
                         const float* __restrict__ gamma,
                         const float* __restrict__ beta,
                         const float* __restrict__ lw,
                         const float* __restrict__ lb,
                         float* __restrict__ outp)
{
    int n = blockIdx.x, t = threadIdx.x;   // block = 128
    __shared__ float tt[FGK_H];
    __shared__ float red[4];
    float v = hsrc[(size_t)n * FGK_H + t];
    float s1 = v, s2 = v * v;
#pragma unroll
    for (int off = 32; off; off >>= 1) { s1 += __shfl_down(s1, off); s2 += __shfl_down(s2, off); }
    int wid = t >> 6, lane = t & 63;
    if (lane == 0) { red[wid] = s1; red[2 + wid] = s2; }
    __syncthreads();
    float mu = (red[0] + red[1]) * (1.f / FGK_H);
    float var = (red[2] + red[3]) * (1.f / FGK_H) - mu * mu;
    float rstd = rsqrtf(var + 1e-5f);
    tt[t] = fmaxf((v - mu) * rstd * gamma[t] + beta[t], 0.f);
    __syncthreads();
    if (t < 112) {
        float acc = lb[t];
        for (int k = 0; k < FGK_H; k++) acc += tt[k] * lw[k * 112 + t];
        outp[(size_t)n * 112 + t] = acc;
    }
}

extern "C" void kernel_launch(void* const* d_in, const int* in_sizes, int n_in,
                              void* d_out, int out_size, void* d_ws, size_t ws_size,
                              hipStream_t stream)
{
    const float* xin  = (const float*)d_in[0];
    const float* eatt = (const float*)d_in[1];
    const int*   eidx = (const int*)d_in[2];
    const float* nEw  = (const float*)d_in[3];
    const float* nEb  = (const float*)d_in[4];
    const float* eEw  = (const float*)d_in[5];
    const float* eEb  = (const float*)d_in[6];
    const float* a1w  = (const float*)d_in[7];
    const float* a1b  = (const float*)d_in[8];
    const float* a2w  = (const float*)d_in[9];
    const float* a2b  = (const float*)d_in[10];
    const float* m1w  = (const float*)d_in[11];
    const float* m1b  = (const float*)d_in[12];
    const float* lng  = (const float*)d_in[13];
    const float* lnb  = (const float*)d_in[14];
    const float* m2w  = (const float*)d_in[15];
    const float* m2b  = (const float*)d_in[16];
    const float* ng   = (const float*)d_in[17];
    const float* nb   = (const float*)d_in[18];
    const float* lw   = (const float*)d_in[19];
    const float* lb   = (const float*)d_in[20];
    float* outp = (float*)d_out;
    const int* srcIdx = eidx;
    const int* dstIdx = eidx + FGK_NE;

    float* ws   = (float*)d_ws;
    float* hAcc = ws;                                    // NN*128
    float* hin  = hAcc + (size_t)FGK_NN * FGK_H;         // NN*128
    float* snA  = hin  + (size_t)FGK_NN * FGK_H;         // NN*16
    float* fnA  = snA  + (size_t)FGK_NN * FGK_P;         // NN*136
    float* mle  = fnA  + (size_t)FGK_NN * FGK_TRI;       // NN*16
    unsigned short* wsU = (unsigned short*)(mle + (size_t)FGK_NN * FGK_P);
    const int A1F = 40 * 512, M1F = 64 * 512, M2F = 64 * 512;
    unsigned short* a1Hi = wsU;
    unsigned short* a1Lo = a1Hi + 3 * A1F;
    unsigned short* m1Hi = a1Lo + 3 * A1F;
    unsigned short* m1Lo = m1Hi + 3 * M1F;
    unsigned short* m2Hi = m1Lo + 3 * M1F;
    unsigned short* m2Lo = m2Hi + 3 * M2F;
    int* cursor = (int*)(m2Lo + 3 * M2F);                // NN ints
    int* perm   = cursor + FGK_NN;                       // NE ints
    int* srcP   = perm + FGK_NE;                         // NE ints (perm-ordered src)
    int* dstP   = srcP + FGK_NE;                         // NE ints (perm-ordered dst)
    unsigned short* hinB = (unsigned short*)(dstP + FGK_NE);   // NN*128 bf16
    unsigned short* eaP  = hinB + (size_t)FGK_NN * FGK_H;      // NE*128 bf16 (82 MB)

    // dst-sorted edge permutation (edge_index constant; rebuilt every launch)
    fgkZeroI<<<(FGK_NN + 255) / 256, 256, 0, stream>>>(cursor, FGK_NN);
    fgkHist<<<(FGK_NE + 255) / 256, 256, 0, stream>>>(dstIdx, cursor);
    fgkScan<<<1, 1024, 0, stream>>>(cursor, cursor);     // in-place exclusive scan
    fgkScatterE<<<(FGK_NE + 255) / 256, 256, 0, stream>>>(dstIdx, srcIdx, cursor,
                                                          perm, srcP, dstP);
    // one-time layer-invariant edge encoding, perm-ordered bf16
    fgkEncE<<<FGK_NE / 16, 256, 0, stream>>>(eatt, perm, eEw, eEb, eaP);

    for (int l = 0; l < 3; l++) {
        fgkPrepW<<<40, 64, 0, stream>>>(a1w + (size_t)l * FGK_H * FGK_F, 128, 152,
                                        a1Hi + l * A1F, a1Lo + l * A1F);
        fgkPrepW<<<64, 64, 0, stream>>>(m1w + (size_t)l * FGK_H * 256, 128, 256,
                                        m1Hi + l * M1F, m1Lo + l * M1F);
        fgkPrepW<<<64, 64, 0, stream>>>(m2w + (size_t)l * 256 * FGK_H, 256, 128,
                                        m2Hi + l * M2F, m2Lo + l * M2F);
    }
    fgkEnc<<<(FGK_NN * FGK_H + 255) / 256, 256, 0, stream>>>(xin, nEw, nEb, hin, hinB);
    for (int l = 0; l < 3; l++) {
        fgkZero<<<(FGK_NN * (FGK_P + FGK_TRI) + 255) / 256, 256, 0, stream>>>(snA);
        fgkEdge<<<FGK_NE / FGK_EPB, 512, 0, stream>>>(srcP, dstP, eaP,
            a1Hi + l * A1F, a1Lo + l * A1F, a1b + (size_t)l * FGK_F, hinB, snA, fnA);
        fgkSolve<<<(FGK_NN + 63) / 64, 64, 0, stream>>>(snA, fnA, mle);
        fgkNode<<<FGK_NN / 16, 256, 0, stream>>>(hin, mle,
            a2w + (size_t)l * FGK_P * FGK_H, a2b + (size_t)l * FGK_H,
            m1Hi + l * M1F, m1Lo + l * M1F, m1b + (size_t)l * 256,
            lng + (size_t)l * 256, lnb + (size_t)l * 256,
            m2Hi + l * M2F, m2Lo + l * M2F, m2b + (size_t)l * FGK_H,
            hAcc, l > 0 ? 1 : 0,
            hin, hinB, ng + (l + 1) * FGK_H, nb + (l + 1) * FGK_H, l < 2 ? 1 : 0);
    }
    fgkFinal<<<FGK_NN, FGK_H, 0, stream>>>(hAcc, ng, nb, lw, lb, outp);
}

// Round 16
// 664.168 us; speedup vs baseline: 1.2580x; 1.0499x over previous
//
#include <hip/hip_runtime.h>
#include <cmath>
#include <cstddef>

#define FGK_NN   20000
#define FGK_NE   320000
#define FGK_H    128
#define FGK_P    16
#define FGK_TRI  136
#define FGK_F    152
#define FGK_EPB  32
#define FGK_YP   156          // sY row stride (>=152, 16B-aligned rows, 28 mod 32)

typedef short  s16x8 __attribute__((ext_vector_type(8)));
typedef float  f32x4 __attribute__((ext_vector_type(4)));

__device__ __forceinline__ unsigned short fgk_f2b(float f) {   // RNE f32->bf16 (native cvt)
    __bf16 b = (__bf16)f;
    return __builtin_bit_cast(unsigned short, b);
}
__device__ __forceinline__ float fgk_u2f(unsigned short u) {
    return __uint_as_float(((unsigned int)u) << 16);
}
// bank-conflict swizzles on 16B-unit index (bijective XOR of high bits into group bits)
__device__ __forceinline__ int fgk_sw(int u)  { return u ^ ((u >> 4) & 7); }  // node-kernel pattern
__device__ __forceinline__ int fgk_swL(int u) { return u ^ ((u >> 5) & 7); }  // edge-kernel pattern

__global__ void FishnetGCN_62096637165586_kernel() {}

__global__ void fgkZero(float* acc) {
    int i = blockIdx.x * blockDim.x + threadIdx.x;
    if (i < FGK_NN * (FGK_P + FGK_TRI)) acc[i] = 0.f;
}
__global__ void fgkZeroI(int* p, int n) {
    int i = blockIdx.x * blockDim.x + threadIdx.x;
    if (i < n) p[i] = 0;
}
// ---- dst-sort: histogram -> block scan -> scatter (edge_index constant) ----
__global__ void fgkHist(const int* __restrict__ dst, int* __restrict__ hist) {
    int e = blockIdx.x * blockDim.x + threadIdx.x;
    if (e < FGK_NE) atomicAdd(&hist[dst[e]], 1);
}
__global__ void fgkScan(const int* __restrict__ hist, int* __restrict__ cursor)
{
    __shared__ int sWave[16];
    __shared__ int sRun;
    int t = threadIdx.x;             // 1024
    int lane = t & 63, wv = t >> 6;
    if (t == 0) sRun = 0;
    __syncthreads();
    for (int base = 0; base < FGK_NN; base += 1024) {
        int idx = base + t;
        int v = (idx < FGK_NN) ? hist[idx] : 0;
        int sc = v;
#pragma unroll
        for (int off = 1; off < 64; off <<= 1) {
            int u = __shfl_up(sc, off);
            if (lane >= off) sc += u;
        }
        if (lane == 63) sWave[wv] = sc;
        __syncthreads();
        if (wv == 0 && lane < 16) {
            int w = sWave[lane];
#pragma unroll
            for (int off = 1; off < 16; off <<= 1) {
                int u = __shfl_up(w, off, 16);
                if (lane >= off) w += u;
            }
            sWave[lane] = w;
        }
        __syncthreads();
        int waveOff = (wv == 0) ? 0 : sWave[wv - 1];
        int run = sRun;
        if (idx < FGK_NN) cursor[idx] = run + waveOff + sc - v;   // exclusive
        __syncthreads();
        if (t == 1023) sRun = run + sWave[15];
        __syncthreads();
    }
}
// scatter + emit perm-ordered src/dst arrays (removes double-indirection later)
__global__ void fgkScatterE(const int* __restrict__ dst, const int* __restrict__ src,
                            int* __restrict__ cursor, int* __restrict__ perm,
                            int* __restrict__ srcP, int* __restrict__ dstP) {
    int e = blockIdx.x * blockDim.x + threadIdx.x;
    if (e < FGK_NE) {
        int d = dst[e];
        int pos = atomicAdd(&cursor[d], 1);
        perm[pos] = e;
        srcP[pos] = src[e];
        dstP[pos] = d;
    }
}

// One-time, layer-invariant: eaP[pos] = bf16(eatt[perm[pos]] @ eew + eeb), perm order.
// 256 threads: thread = (pos in 16-group, 8-col group)
__global__ void fgkEncE(const float* __restrict__ eatt,
                        const int* __restrict__ perm,
                        const float* __restrict__ eew,
                        const float* __restrict__ eeb,
                        unsigned short* __restrict__ eaP)
{
    int pos = blockIdx.x * 16 + (threadIdx.x >> 4);
    int b = threadIdx.x & 15;
    int e = perm[pos];
    const float4* ap = (const float4*)(eatt + (size_t)e * 8);
    float4 a0 = ap[0], a1 = ap[1];
    float av[8] = {a0.x, a0.y, a0.z, a0.w, a1.x, a1.y, a1.z, a1.w};
    const float4* bp = (const float4*)(eeb + b * 8);
    float4 b0 = bp[0], b1 = bp[1];
    float acc[8] = {b0.x, b0.y, b0.z, b0.w, b1.x, b1.y, b1.z, b1.w};
#pragma unroll
    for (int kk = 0; kk < 8; ++kk) {
        const float4* wp = (const float4*)(eew + kk * FGK_H + b * 8);
        float4 w0 = wp[0], w1 = wp[1];
        acc[0] += av[kk] * w0.x; acc[1] += av[kk] * w0.y;
        acc[2] += av[kk] * w0.z; acc[3] += av[kk] * w0.w;
        acc[4] += av[kk] * w1.x; acc[5] += av[kk] * w1.y;
        acc[6] += av[kk] * w1.z; acc[7] += av[kk] * w1.w;
    }
    s16x8 r;
#pragma unroll
    for (int jj = 0; jj < 8; ++jj) r[jj] = (short)fgk_f2b(acc[jj]);
    *(s16x8*)&eaP[(size_t)pos * FGK_H + b * 8] = r;
}

// Generic prepack of W[K,N] (row-major) into MFMA B-fragment order, bf16 hi/lo.
__global__ void fgkPrepW(const float* __restrict__ W, int K, int N,
                         unsigned short* __restrict__ hi,
                         unsigned short* __restrict__ lo)
{
    int chunks = K >> 5;
    int b = blockIdx.x;
    int nt = b / chunks, c = b - nt * chunks;
    int lane = threadIdx.x;
    int n = nt * 16 + (lane & 15);
    int g = lane >> 4;
    size_t base = ((size_t)b * 64 + lane) * 8;
#pragma unroll
    for (int j = 0; j < 8; ++j) {
        int k = c * 32 + g * 8 + j;
        float v = (n < N) ? W[(size_t)k * N + n] : 0.f;
        unsigned short hb = fgk_f2b(v);
        unsigned short lb = fgk_f2b(v - fgk_u2f(hb));
        hi[base + j] = hb;
        lo[base + j] = lb;
    }
}

// hin = x @ W[8,128] + b   (f32 + bf16 gather copy)
__global__ void fgkEnc(const float* __restrict__ xin,
                       const float* __restrict__ wenc,
                       const float* __restrict__ benc,
                       float* __restrict__ hin,
                       unsigned short* __restrict__ hinB)
{
    int idx = blockIdx.x * blockDim.x + threadIdx.x;
    if (idx >= FGK_NN * FGK_H) return;
    int n = idx >> 7, j = idx & 127;
    float acc = benc[j];
    const float* xp = xin + (size_t)n * 8;
#pragma unroll
    for (int k = 0; k < 8; k++) acc += xp[k] * wenc[k * FGK_H + j];
    hin[idx] = acc;
    hinB[idx] = fgk_f2b(acc);
}

// edge (sorted by dst), 32 edges/block, 512 threads, ~37 KB LDS (4 blocks/CU):
// msg (A hi only) ; y=MFMA (wave owns nt, both et per B-tile) ; then per-16-edge
// halves: L-build -> Fe=MFMA, sTri overlays that half's dead sY rows.  7 barriers.
__global__ void __launch_bounds__(512, 4)
fgkEdge(const int* __restrict__ srcP,
        const int* __restrict__ dstP,
        const unsigned short* __restrict__ eaP,
        const unsigned short* __restrict__ bHi,
        const unsigned short* __restrict__ bLo,
        const float* __restrict__ a1b,
        const unsigned short* __restrict__ hinB,
        float* __restrict__ snAcc,
        float* __restrict__ fnAcc)
{
    __shared__ float uni[4096];                   // 16 KB: aH (8K); lH/lL (8K+8K)
    __shared__ float sY[FGK_EPB][FGK_YP];         // 19.9 KB: y; halves -> sTri
    __shared__ int sSrc[FGK_EPB], sDst[FGK_EPB];
    __shared__ int sStart[FGK_EPB], sEnd[FGK_EPB], sDstSlot[FGK_EPB];
    __shared__ int sNS;
    unsigned short* aH = (unsigned short*)uni;            // 4096 us (8 KB)
    unsigned short* lH = (unsigned short*)uni;            // 4096 us (per-half)
    unsigned short* lL = (unsigned short*)uni + 4096;     // 4096 us (per-half)
    float* sTriA = (float*)sY;                            // 16*136 over rows 0-15
    float* sTriB = (float*)&sY[16][0];                    // 16*136 over rows 16-31
    int t = threadIdx.x;                          // 512 threads, 8 waves
    int lane = t & 63, wave = t >> 6;
    int e0 = blockIdx.x * FGK_EPB;

    if (wave == 0) {                              // meta load + parallel slot detect
        int sv = 0, dv = 0x7fffffff;
        if (lane < FGK_EPB) {
            sv = srcP[e0 + lane];
            dv = dstP[e0 + lane];
            sSrc[lane] = sv; sDst[lane] = dv;
        }
        int prev = __shfl_up(dv, 1);
        bool isStart = (lane < FGK_EPB) && (lane == 0 || dv != prev);
        unsigned long long mask = __ballot(isStart);
        int ns = __popcll(mask);
        if (isStart) {
            int s = (int)__popcll(mask & ((1ull << lane) - 1ull));
            sStart[s] = lane;
            sDstSlot[s] = dv;
            if (lane) sEnd[s - 1] = lane;
        }
        if (lane == 0) { sNS = ns; sEnd[ns - 1] = FGK_EPB; }
    }
    __syncthreads();                              // bar 1

    // ---- msg = relu(hinB[src] + eaP) + 1e-7 -> bf16 A-frags (hi only) ----
    {
        int el = t >> 4, b = t & 15;
        s16x8 hraw = *(const s16x8*)(hinB + (size_t)sSrc[el] * FGK_H + b * 8);
        s16x8 eraw = *(const s16x8*)(eaP + (size_t)(e0 + el) * FGK_H + b * 8);
        s16x8 hb;
#pragma unroll
        for (int jj = 0; jj < 8; ++jj) {
            float hv = fgk_u2f((unsigned short)hraw[jj]);
            float ev = fgk_u2f((unsigned short)eraw[jj]);
            float m = fmaxf(hv + ev, 0.f) + 1e-7f;
            hb[jj] = (short)fgk_f2b(m);
        }
        int c = b >> 2, g = b & 3;                // k = b*8+jj = 32c+8g+jj
        int idx = fgk_swL(c * 128 + 32 * g + el) * 8;
        *(s16x8*)&aH[idx] = hb;
    }
    __syncthreads();                              // bar 2

    // ---- y = msg @ a1w via MFMA: wave owns nt (waves 0,1 also nt 8,9);
    //      BOTH et against one B-tile stream (halves per-block L2 B traffic) ----
    {
        s16x8 ah[2][4];
#pragma unroll
        for (int et = 0; et < 2; ++et)
#pragma unroll
            for (int c = 0; c < 4; ++c) {
                int idx = fgk_swL(c * 128 + 32 * (lane >> 4) + 16 * et + (lane & 15)) * 8;
                ah[et][c] = *(const s16x8*)&aH[idx];
            }
        int n = lane & 15, qd = lane >> 4;
        int npass = (wave < 2) ? 2 : 1;
        for (int pass = 0; pass < npass; ++pass) {
            int nt = (pass == 0) ? wave : 8 + wave;
            f32x4 acc0 = {0.f, 0.f, 0.f, 0.f};
            f32x4 acc1 = {0.f, 0.f, 0.f, 0.f};
#pragma unroll
            for (int c = 0; c < 4; ++c) {
                size_t bidx = ((size_t)(nt * 4 + c) * 64 + lane) * 8;
                s16x8 bh = *(const s16x8*)(bHi + bidx);
                s16x8 bl = *(const s16x8*)(bLo + bidx);
                acc0 = __builtin_amdgcn_mfma_f32_16x16x32_bf16(ah[0][c], bl, acc0, 0, 0, 0);
                acc0 = __builtin_amdgcn_mfma_f32_16x16x32_bf16(ah[0][c], bh, acc0, 0, 0, 0);
                acc1 = __builtin_amdgcn_mfma_f32_16x16x32_bf16(ah[1][c], bl, acc1, 0, 0, 0);
                acc1 = __builtin_amdgcn_mfma_f32_16x16x32_bf16(ah[1][c], bh, acc1, 0, 0, 0);
            }
            int j = nt * 16 + n;
            if (j < FGK_F) {                       // GUARD: pad cols must not wrap
                float bias = a1b[j];
#pragma unroll
                for (int reg = 0; reg < 4; ++reg) {
                    sY[4 * qd + reg][j] = acc0[reg] + bias;
                    sY[16 + 4 * qd + reg][j] = acc1[reg] + bias;
                }
            }
        }
    }
    __syncthreads();                              // bar 3 (sY done; aH dead)

    // ---- P4: per-slot score reduce (reads all sY) + L-build half A (el 0-15) ----
    {
        {
            int s = t;                        // 512 slots: el16(16) x r(32)
            int el16 = s & 15;
            int r  = s >> 4;                  // 0..31
            int i  = r & 15, h = r >> 4;
            int pstart = 16 * i + 8 * h;
            float v[8];
            if (pstart < 120) {
                const float4* rp = (const float4*)&sY[el16][32 + pstart];
                float4 v0 = rp[0], v1 = rp[1];
                v[0] = v0.x; v[1] = v0.y; v[2] = v0.z; v[3] = v0.w;
                v[4] = v1.x; v[5] = v1.y; v[6] = v1.z; v[7] = v1.w;
            } else {
                const float4* rp = (const float4*)&sY[el16][264 - pstart];
                float4 v0 = rp[0], v1 = rp[1];
                v[0] = v1.w; v[1] = v1.z; v[2] = v1.y; v[3] = v1.x;
                v[4] = v0.w; v[5] = v0.z; v[6] = v0.y; v[7] = v0.x;
            }
            if (h == (i >> 3)) {              // diag elem at i&7
                int jd = i & 7;
                float d0 = v[jd];
                v[jd] = fmaxf(d0, 0.f) +
                        0.69314718f * log2f(1.f + exp2f(-1.44269504f * fabsf(d0)));
            }
            s16x8 hb, lb;
#pragma unroll
            for (int jj = 0; jj < 8; ++jj) {
                unsigned short hbv = fgk_f2b(v[jj]);
                hb[jj] = (short)hbv;
                lb[jj] = (short)fgk_f2b(v[jj] - fgk_u2f(hbv));
            }
            int idx = fgk_swL(el16 * 32 + i + 16 * h) * 8;
            *(s16x8*)&lH[idx] = hb;
            *(s16x8*)&lL[idx] = lb;
        }
        int el = t >> 4, d = t & 15;          // score reduce (sY all rows)
        if (el < sNS) {
            float sum = 0.f;
            for (int e2 = sStart[el]; e2 < sEnd[el]; ++e2) sum += sY[e2][d];
            atomicAdd(&snAcc[(size_t)sDstSlot[el] * FGK_P + d], sum);
        }
    }
    __syncthreads();                              // bar 4

    // ---- P5: Fe half A -> sTriA (overlays sY rows 0-15, now dead) ----
#pragma unroll
    for (int i2 = 0; i2 < 2; ++i2) {
        int el16 = wave * 2 + i2;             // 0..15
        s16x8 fh = {0, 0, 0, 0, 0, 0, 0, 0};
        s16x8 fl = {0, 0, 0, 0, 0, 0, 0, 0};
        if (lane < 32) {
            int idx = fgk_swL(el16 * 32 + lane) * 8;
            fh = *(const s16x8*)&lH[idx];
            fl = *(const s16x8*)&lL[idx];
        }
        f32x4 acc = {0.f, 0.f, 0.f, 0.f};
        acc = __builtin_amdgcn_mfma_f32_16x16x32_bf16(fh, fh, acc, 0, 0, 0);
        acc = __builtin_amdgcn_mfma_f32_16x16x32_bf16(fh, fl, acc, 0, 0, 0);
        acc = __builtin_amdgcn_mfma_f32_16x16x32_bf16(fl, fh, acc, 0, 0, 0);
        int j = lane & 15, qd = lane >> 4;
#pragma unroll
        for (int reg = 0; reg < 4; ++reg) {
            int ii = 4 * qd + reg;
            if (ii >= j) sTriA[el16 * FGK_TRI + ii * (ii + 1) / 2 + j] = acc[reg];
        }
    }
    __syncthreads();                              // bar 5 (lH/lL A consumed)

    // ---- P6: L-build half B (el 16-31; sY rows 16-31 still intact) ----
    {
        int s = t;
        int el16 = s & 15;
        int r  = s >> 4;
        int i  = r & 15, h = r >> 4;
        int pstart = 16 * i + 8 * h;
        float v[8];
        if (pstart < 120) {
            const float4* rp = (const float4*)&sY[16 + el16][32 + pstart];
            float4 v0 = rp[0], v1 = rp[1];
            v[0] = v0.x; v[1] = v0.y; v[2] = v0.z; v[3] = v0.w;
            v[4] = v1.x; v[5] = v1.y; v[6] = v1.z; v[7] = v1.w;
        } else {
            const float4* rp = (const float4*)&sY[16 + el16][264 - pstart];
            float4 v0 = rp[0], v1 = rp[1];
            v[0] = v1.w; v[1] = v1.z; v[2] = v1.y; v[3] = v1.x;
            v[4] = v0.w; v[5] = v0.z; v[6] = v0.y; v[7] = v0.x;
        }
        if (h == (i >> 3)) {
            int jd = i & 7;
            float d0 = v[jd];
            v[jd] = fmaxf(d0, 0.f) +
                    0.69314718f * log2f(1.f + exp2f(-1.44269504f * fabsf(d0)));
        }
        s16x8 hb, lb;
#pragma unroll
        for (int jj = 0; jj < 8; ++jj) {
            unsigned short hbv = fgk_f2b(v[jj]);
            hb[jj] = (short)hbv;
            lb[jj] = (short)fgk_f2b(v[jj] - fgk_u2f(hbv));
        }
        int idx = fgk_swL(el16 * 32 + i + 16 * h) * 8;
        *(s16x8*)&lH[idx] = hb;
        *(s16x8*)&lL[idx] = lb;
    }
    __syncthreads();                              // bar 6

    // ---- P7: Fe half B -> sTriB (overlays sY rows 16-31, now dead) ----
#pragma unroll
    for (int i2 = 0; i2 < 2; ++i2) {
        int el16 = wave * 2 + i2;
        s16x8 fh = {0, 0, 0, 0, 0, 0, 0, 0};
        s16x8 fl = {0, 0, 0, 0, 0, 0, 0, 0};
        if (lane < 32) {
            int idx = fgk_swL(el16 * 32 + lane) * 8;
            fh = *(const s16x8*)&lH[idx];
            fl = *(const s16x8*)&lL[idx];
        }
        f32x4 acc = {0.f, 0.f, 0.f, 0.f};
        acc = __builtin_amdgcn_mfma_f32_16x16x32_bf16(fh, fh, acc, 0, 0, 0);
        acc = __builtin_amdgcn_mfma_f32_16x16x32_bf16(fh, fl, acc, 0, 0, 0);
        acc = __builtin_amdgcn_mfma_f32_16x16x32_bf16(fl, fh, acc, 0, 0, 0);
        int j = lane & 15, qd = lane >> 4;
#pragma unroll
        for (int reg = 0; reg < 4; ++reg) {
            int ii = 4 * qd + reg;
            if (ii >= j) sTriB[el16 * FGK_TRI + ii * (ii + 1) / 2 + j] = acc[reg];
        }
    }
    __syncthreads();                              // bar 7

    // ---- per-slot tri reduction -> coalesced atomics ----
    {
        int nS = sNS;
        for (int o = t; o < nS * FGK_TRI; o += 512) {
            int s = o / FGK_TRI, p = o - s * FGK_TRI;
            float sum = 0.f;
            for (int el = sStart[s]; el < sEnd[s]; ++el) {
                const float* tb = (el < 16) ? sTriA : sTriB;
                sum += tb[(el & 15) * FGK_TRI + p];
            }
            atomicAdd(&fnAcc[(size_t)sDstSlot[s] * FGK_TRI + p], sum);
        }
    }
}

// one thread per node: fully-unrolled register Cholesky solve of (F_n+I) x = s_n
// 64-thread blocks: 313 workgroups spread over all 256 CUs
#define TA(i, j) a[(i) * ((i) + 1) / 2 + (j)]
__global__ void __launch_bounds__(64)
fgkSolve(const float* __restrict__ snAcc,
         const float* __restrict__ fnAcc,
         float* __restrict__ mleOut)
{
    int n = blockIdx.x * blockDim.x + threadIdx.x;
    if (n >= FGK_NN) return;
    float a[FGK_TRI];
    const float4* src = (const float4*)(fnAcc + (size_t)n * FGK_TRI);
#pragma unroll
    for (int p = 0; p < FGK_TRI / 4; ++p) {
        float4 v = src[p];
        a[p * 4] = v.x; a[p * 4 + 1] = v.y; a[p * 4 + 2] = v.z; a[p * 4 + 3] = v.w;
    }
#pragma unroll
    for (int i = 0; i < 16; ++i) TA(i, i) += 1.f;
#pragma unroll
    for (int k = 0; k < 16; ++k) {
        float d = sqrtf(TA(k, k));
        float inv = 1.f / d;
        TA(k, k) = d;
#pragma unroll
        for (int i = k + 1; i < 16; ++i) TA(i, k) *= inv;
#pragma unroll
        for (int j = k + 1; j < 16; ++j) {
            float ajk = TA(j, k);
#pragma unroll
            for (int i = j; i < 16; ++i) TA(i, j) -= TA(i, k) * ajk;
        }
    }
    const float* sp = snAcc + (size_t)n * FGK_P;
    float y[16], x[16];
#pragma unroll
    for (int i = 0; i < 16; ++i) {
        float acc = sp[i];
#pragma unroll
        for (int k = 0; k < 16; ++k) if (k < i) acc -= TA(i, k) * y[k];
        y[i] = acc / TA(i, i);
    }
#pragma unroll
    for (int i = 15; i >= 0; --i) {
        float acc = y[i];
#pragma unroll
        for (int k = 0; k < 16; ++k) if (k > i) acc -= TA(k, i) * x[k];
        x[i] = acc / TA(i, i);
    }
    float4* dst = (float4*)(mleOut + (size_t)n * FGK_P);
#pragma unroll
    for (int p = 0; p < 4; ++p) dst[p] = make_float4(x[p * 4], x[p * 4 + 1], x[p * 4 + 2], x[p * 4 + 3]);
}
#undef TA

// node (16 nodes/block): a2+res -> m1 MFMA -> LN -> m2 MFMA -> hout
// + fused next-layer relu(LN(hout)) -> hinNext (doNext)
// + fused FINAL: out = relu(LN(hout,g0,b0)) @ lin_w + lin_b (doFinal)
// HI-ONLY A fragments; lw dual-precision (streamed from global)
__global__ void __launch_bounds__(256)
fgkNode(const float* __restrict__ hin,
        const float* __restrict__ mleIn,
        const float* __restrict__ a2w, const float* __restrict__ a2b,
        const unsigned short* __restrict__ m1H,
        const float* __restrict__ m1b,
        const float* __restrict__ gamma, const float* __restrict__ beta,
        const unsigned short* __restrict__ m2H,
        const float* __restrict__ m2b,
        float* __restrict__ hout, int addres,
        float* __restrict__ hinNext, unsigned short* __restrict__ hinNextB,
        const float* __restrict__ gN, const float* __restrict__ bN, int doNext,
        const unsigned short* __restrict__ lwH, const unsigned short* __restrict__ lwL,
        const float* __restrict__ linb, float* __restrict__ outp, int doFinal)
{
    __shared__ char uniN[8192];                // ovH (4 KB) then t2H (8 KB)
    __shared__ float sT[16][260];
    __shared__ float stats[16][2];
    unsigned short* ovH = (unsigned short*)uniN;   // 2048 us
    unsigned short* t2H = (unsigned short*)uniN;   // 4096 us (after reuse)
    int t = threadIdx.x, lane = t & 63, wave = t >> 6;
    int n0 = blockIdx.x * 16;

    // ---- a2 matvec + residual -> bf16 hi frags (one pass, vectorized) ----
    {
        int node = t >> 4, cg = t & 15;            // 8 cols per thread
        const float4* m4 = (const float4*)(mleIn + (size_t)(n0 + node) * FGK_P);
        float4 q0 = m4[0], q1 = m4[1], q2 = m4[2], q3 = m4[3];
        float mv[16] = {q0.x, q0.y, q0.z, q0.w, q1.x, q1.y, q1.z, q1.w,
                        q2.x, q2.y, q2.z, q2.w, q3.x, q3.y, q3.z, q3.w};
        const float4* bp = (const float4*)(a2b + cg * 8);
        float4 b0 = bp[0], b1 = bp[1];
        const float4* hp = (const float4*)(hin + (size_t)(n0 + node) * FGK_H + cg * 8);
        float4 h0 = hp[0], h1 = hp[1];
        float acc[8] = {b0.x + h0.x, b0.y + h0.y, b0.z + h0.z, b0.w + h0.w,
                        b1.x + h1.x, b1.y + h1.y, b1.z + h1.z, b1.w + h1.w};
#pragma unroll
        for (int k = 0; k < 16; ++k) {
            const float4* wp = (const float4*)(a2w + k * FGK_H + cg * 8);
            float4 w0 = wp[0], w1 = wp[1];
            acc[0] += mv[k] * w0.x; acc[1] += mv[k] * w0.y;
            acc[2] += mv[k] * w0.z; acc[3] += mv[k] * w0.w;
            acc[4] += mv[k] * w1.x; acc[5] += mv[k] * w1.y;
            acc[6] += mv[k] * w1.z; acc[7] += mv[k] * w1.w;
        }
        s16x8 hb;
#pragma unroll
        for (int jj = 0; jj < 8; ++jj) hb[jj] = (short)fgk_f2b(acc[jj]);
        int idx = fgk_sw(cg * 16 + node) * 8;      // u = c*64+16g+node = 16*cg+node
        *(s16x8*)&ovH[idx] = hb;
    }
    __syncthreads();

    // ---- m1 = A-hi @ m1H (single MFMA per c) ----
    {
        s16x8 ah[4];
#pragma unroll
        for (int c = 0; c < 4; ++c) {
            int idx = fgk_sw(c * 64 + lane) * 8;
            ah[c] = *(const s16x8*)&ovH[idx];
        }
        int n = lane & 15, qd = lane >> 4;
#pragma unroll
        for (int i4 = 0; i4 < 4; ++i4) {
            int nt = wave + i4 * 4;
            f32x4 acc = {0.f, 0.f, 0.f, 0.f};
#pragma unroll
            for (int c = 0; c < 4; ++c) {
                size_t bidx = ((size_t)(nt * 4 + c) * 64 + lane) * 8;
                s16x8 bh = *(const s16x8*)(m1H + bidx);
                acc = __builtin_amdgcn_mfma_f32_16x16x32_bf16(ah[c], bh, acc, 0, 0, 0);
            }
            int j = nt * 16 + n;
            float bias = m1b[j];
#pragma unroll
            for (int reg = 0; reg < 4; ++reg)
                sT[4 * qd + reg][j] = acc[reg] + bias;
        }
    }
    __syncthreads();

    {
        int node = t >> 4, seg = t & 15;
        const float* rowp = &sT[node][seg * 16];
        float s1 = 0.f, s2 = 0.f;
#pragma unroll
        for (int k = 0; k < 16; ++k) { float v = rowp[k]; s1 += v; s2 += v * v; }
#pragma unroll
        for (int off = 8; off; off >>= 1) {
            s1 += __shfl_down(s1, off, 16);
            s2 += __shfl_down(s2, off, 16);
        }
        if (seg == 0) {
            float mu = s1 * (1.f / 256.f);
            float var = s2 * (1.f / 256.f) - mu * mu;
            stats[node][0] = mu;
            stats[node][1] = rsqrtf(var + 1e-5f);
        }
    }
    __syncthreads();

    // ---- LN + relu -> bf16 hi frags (vectorized, swizzled b128 stores) ----
    {
        int node = t >> 4;
        float mu = stats[node][0], rstd = stats[node][1];
#pragma unroll
        for (int h = 0; h < 2; ++h) {
            int cg = (t & 15) + 16 * h;            // 0..31, 8 cols each
            const float4* rp = (const float4*)&sT[node][cg * 8];
            float4 v0 = rp[0], v1 = rp[1];
            const float4* gp = (const float4*)(gamma + cg * 8);
            float4 g0 = gp[0], g1 = gp[1];
            const float4* bb = (const float4*)(beta + cg * 8);
            float4 e0 = bb[0], e1 = bb[1];
            float vv[8] = {v0.x, v0.y, v0.z, v0.w, v1.x, v1.y, v1.z, v1.w};
            float gg[8] = {g0.x, g0.y, g0.z, g0.w, g1.x, g1.y, g1.z, g1.w};
            float ee[8] = {e0.x, e0.y, e0.z, e0.w, e1.x, e1.y, e1.z, e1.w};
            s16x8 hb;
#pragma unroll
            for (int jj = 0; jj < 8; ++jj) {
                float tv = fmaxf((vv[jj] - mu) * rstd * gg[jj] + ee[jj], 0.f);
                hb[jj] = (short)fgk_f2b(tv);
            }
            int idx = fgk_sw(cg * 16 + node) * 8;
            *(s16x8*)&t2H[idx] = hb;
        }
    }
    __syncthreads();

    // ---- m2 = A-hi @ m2H (single MFMA per c) ----
    {
        s16x8 ah[8];
#pragma unroll
        for (int c = 0; c < 8; ++c) {
            int idx = fgk_sw(c * 64 + lane) * 8;
            ah[c] = *(const s16x8*)&t2H[idx];
        }
        int n = lane & 15, qd = lane >> 4;
#pragma unroll
        for (int i2 = 0; i2 < 2; ++i2) {
            int nt = wave * 2 + i2;
            f32x4 acc = {0.f, 0.f, 0.f, 0.f};
#pragma unroll
            for (int c = 0; c < 8; ++c) {
                size_t bidx = ((size_t)(nt * 8 + c) * 64 + lane) * 8;
                s16x8 bh = *(const s16x8*)(m2H + bidx);
                acc = __builtin_amdgcn_mfma_f32_16x16x32_bf16(ah[c], bh, acc, 0, 0, 0);
            }
            int j = nt * 16 + n;
            float bias = m2b[j];
#pragma unroll
            for (int reg = 0; reg < 4; ++reg) {
                int node = 4 * qd + reg;
                size_t idx = (size_t)(n0 + node) * FGK_H + j;
                float val = acc[reg] + bias;
                float nv = addres ? (hout[idx] + val) : val;
                hout[idx] = nv;
                sT[node][j] = nv;          // park for fused next-layer LN / final
            }
        }
    }
    if (doNext) {                          // hinNext = relu(LN(hout, gN, bN))
        __syncthreads();
        int node = t >> 4, seg = t & 15;
        const float* rowp = &sT[node][seg * 8];
        float s1 = 0.f, s2 = 0.f;
#pragma unroll
        for (int k = 0; k < 8; ++k) { float v = rowp[k]; s1 += v; s2 += v * v; }
#pragma unroll
        for (int off = 8; off; off >>= 1) {
            s1 += __shfl_down(s1, off, 16);
            s2 += __shfl_down(s2, off, 16);
        }
        if (seg == 0) {
            float mu = s1 * (1.f / 128.f);
            float var = s2 * (1.f / 128.f) - mu * mu;
            stats[node][0] = mu;
            stats[node][1] = rsqrtf(var + 1e-5f);
        }
        __syncthreads();
        float mu = stats[node][0], rstd = stats[node][1];
#pragma unroll
        for (int kk = 0; kk < 8; ++kk) {
            int k = seg * 8 + kk;
            float v = sT[node][k];
            float nv = fmaxf((v - mu) * rstd * gN[k] + bN[k], 0.f);
            size_t oidx = (size_t)(n0 + node) * FGK_H + k;
            hinNext[oidx] = nv;
            hinNextB[oidx] = fgk_f2b(nv);
        }
    } else if (doFinal) {                  // out = relu(LN(hout,g0,b0)) @ lw + lb
        __syncthreads();
        {
            int node = t >> 4, seg = t & 15;
            const float* rowp = &sT[node][seg * 8];
            float s1 = 0.f, s2 = 0.f;
#pragma unroll
            for (int k = 0; k < 8; ++k) { float v = rowp[k]; s1 += v; s2 += v * v; }
#pragma unroll
            for (int off = 8; off; off >>= 1) {
                s1 += __shfl_down(s1, off, 16);
                s2 += __shfl_down(s2, off, 16);
            }
            if (seg == 0) {
                float mu = s1 * (1.f / 128.f);
                float var = s2 * (1.f / 128.f) - mu * mu;
                stats[node][0] = mu;
                stats[node][1] = rsqrtf(var + 1e-5f);
            }
        }
        __syncthreads();
        {   // relu(LN) -> A-hi frags in t2H (2048 us used)
            int node = t >> 4, cg = t & 15;
            float mu = stats[node][0], rstd = stats[node][1];
            const float* rowp = &sT[node][cg * 8];
            s16x8 hb;
#pragma unroll
            for (int jj = 0; jj < 8; ++jj) {
                int k = cg * 8 + jj;
                float tv = fmaxf((rowp[jj] - mu) * rstd * gN[k] + bN[k], 0.f);
                hb[jj] = (short)fgk_f2b(tv);
            }
            int idx = fgk_sw(cg * 16 + node) * 8;
            *(s16x8*)&t2H[idx] = hb;
        }
        __syncthreads();
        {   // final matvec via MFMA: A hi-only, lw dual-precision (7 nt tiles)
            s16x8 ah[4];
#pragma unroll
            for (int c = 0; c < 4; ++c) {
                int idx = fgk_sw(c * 64 + lane) * 8;
                ah[c] = *(const s16x8*)&t2H[idx];
            }
            int n = lane & 15, qd = lane >> 4;
#pragma unroll
            for (int p2 = 0; p2 < 2; ++p2) {
                int nt = wave + p2 * 4;
                if (nt < 7) {
                    f32x4 acc = {0.f, 0.f, 0.f, 0.f};
#pragma unroll
                    for (int c = 0; c < 4; ++c) {
                        size_t bidx = ((size_t)(nt * 4 + c) * 64 + lane) * 8;
                        s16x8 bh = *(const s16x8*)(lwH + bidx);
                        s16x8 bl = *(const s16x8*)(lwL + bidx);
                        acc = __builtin_amdgcn_mfma_f32_16x16x32_bf16(ah[c], bl, acc, 0, 0, 0);
                        acc = __builtin_amdgcn_mfma_f32_16x16x32_bf16(ah[c], bh, acc, 0, 0, 0);
                    }
                    int j = nt * 16 + n;
                    float bias = linb[j];
#pragma unroll
                    for (int reg = 0; reg < 4; ++reg) {
                        int node = 4 * qd + reg;
                        outp[(size_t)(n0 + node) * 112 + j] = acc[reg] + bias;
                    }
                }
            }
        }
    }
}

extern "C" void kernel_launch(void* const* d_in, const int* in_sizes, int n_in,
                              void* d_out, int out_size, void* d_ws, size_t ws_size,
                              hipStream_t stream)
{
    const float* xin  = (const float*)d_in[0];
    const float* eatt = (const float*)d_in[1];
    const int*   eidx = (const int*)d_in[2];
    const float* nEw  = (const float*)d_in[3];
    const float* nEb  = (const float*)d_in[4];
    const float* eEw  = (const float*)d_in[5];
    const float* eEb  = (const float*)d_in[6];
    const float* a1w  = (const float*)d_in[7];
    const float* a1b  = (const float*)d_in[8];
    const float* a2w  = (const float*)d_in[9];
    const float* a2b  = (const float*)d_in[10];
    const float* m1w  = (const float*)d_in[11];
    const float* m1b  = (const float*)d_in[12];
    const float* lng  = (const float*)d_in[13];
    const float* lnb  = (const float*)d_in[14];
    const float* m2w  = (const float*)d_in[15];
    const float* m2b  = (const float*)d_in[16];
    const float* ng   = (const float*)d_in[17];
    const float* nb   = (const float*)d_in[18];
    const float* lw   = (const float*)d_in[19];
    const float* lb   = (const float*)d_in[20];
    float* outp = (float*)d_out;
    const int* srcIdx = eidx;
    const int* dstIdx = eidx + FGK_NE;

    float* ws   = (float*)d_ws;
    float* hAcc = ws;                                    // NN*128
    float* hin  = hAcc + (size_t)FGK_NN * FGK_H;         // NN*128
    float* snA  = hin  + (size_t)FGK_NN * FGK_H;         // NN*16
    float* fnA  = snA  + (size_t)FGK_NN * FGK_P;         // NN*136
    float* mle  = fnA  + (size_t)FGK_NN * FGK_TRI;       // NN*16
    unsigned short* wsU = (unsigned short*)(mle + (size_t)FGK_NN * FGK_P);
    const int A1F = 40 * 512, M1F = 64 * 512, M2F = 64 * 512, LWF = 28 * 512;
    unsigned short* a1Hi = wsU;
    unsigned short* a1Lo = a1Hi + 3 * A1F;
    unsigned short* m1Hi = a1Lo + 3 * A1F;
    unsigned short* m1Lo = m1Hi + 3 * M1F;
    unsigned short* m2Hi = m1Lo + 3 * M1F;
    unsigned short* m2Lo = m2Hi + 3 * M2F;
    unsigned short* lwHi = m2Lo + 3 * M2F;               // 28*512
    unsigned short* lwLo = lwHi + LWF;                   // 28*512
    int* cursor = (int*)(lwLo + LWF);                    // NN ints
    int* perm   = cursor + FGK_NN;                       // NE ints
    int* srcP   = perm + FGK_NE;                         // NE ints (perm-ordered src)
    int* dstP   = srcP + FGK_NE;                         // NE ints (perm-ordered dst)
    unsigned short* hinB = (unsigned short*)(dstP + FGK_NE);   // NN*128 bf16
    unsigned short* eaP  = hinB + (size_t)FGK_NN * FGK_H;      // NE*128 bf16 (82 MB)

    // dst-sorted edge permutation (edge_index constant; rebuilt every launch)
    fgkZeroI<<<(FGK_NN + 255) / 256, 256, 0, stream>>>(cursor, FGK_NN);
    fgkHist<<<(FGK_NE + 255) / 256, 256, 0, stream>>>(dstIdx, cursor);
    fgkScan<<<1, 1024, 0, stream>>>(cursor, cursor);     // in-place exclusive scan
    fgkScatterE<<<(FGK_NE + 255) / 256, 256, 0, stream>>>(dstIdx, srcIdx, cursor,
                                                          perm, srcP, dstP);
    // one-time layer-invariant edge encoding, perm-ordered bf16
    fgkEncE<<<FGK_NE / 16, 256, 0, stream>>>(eatt, perm, eEw, eEb, eaP);

    for (int l = 0; l < 3; l++) {
        fgkPrepW<<<40, 64, 0, stream>>>(a1w + (size_t)l * FGK_H * FGK_F, 128, 152,
                                        a1Hi + l * A1F, a1Lo + l * A1F);
        fgkPrepW<<<64, 64, 0, stream>>>(m1w + (size_t)l * FGK_H * 256, 128, 256,
                                        m1Hi + l * M1F, m1Lo + l * M1F);
        fgkPrepW<<<64, 64, 0, stream>>>(m2w + (size_t)l * 256 * FGK_H, 256, 128,
                                        m2Hi + l * M2F, m2Lo + l * M2F);
    }
    fgkPrepW<<<28, 64, 0, stream>>>(lw, 128, 112, lwHi, lwLo);
    fgkEnc<<<(FGK_NN * FGK_H + 255) / 256, 256, 0, stream>>>(xin, nEw, nEb, hin, hinB);
    for (int l = 0; l < 3; l++) {
        fgkZero<<<(FGK_NN * (FGK_P + FGK_TRI) + 255) / 256, 256, 0, stream>>>(snA);
        fgkEdge<<<FGK_NE / FGK_EPB, 512, 0, stream>>>(srcP, dstP, eaP,
            a1Hi + l * A1F, a1Lo + l * A1F, a1b + (size_t)l * FGK_F, hinB, snA, fnA);
        fgkSolve<<<(FGK_NN + 63) / 64, 64, 0, stream>>>(snA, fnA, mle);
        int isLast = (l == 2);
        fgkNode<<<FGK_NN / 16, 256, 0, stream>>>(hin, mle,
            a2w + (size_t)l * FGK_P * FGK_H, a2b + (size_t)l * FGK_H,
            m1Hi + l * M1F, m1b + (size_t)l * 256,
            lng + (size_t)l * 256, lnb + (size_t)l * 256,
            m2Hi + l * M2F, m2b + (size_t)l * FGK_H,
            hAcc, l > 0 ? 1 : 0,
            hin, hinB,
            isLast ? ng : (ng + (l + 1) * FGK_H),
            isLast ? nb : (nb + (l + 1) * FGK_H),
            isLast ? 0 : 1,
            lwHi, lwLo, lb, outp, isLast ? 1 : 0);
    }
}

// Round 17
// 663.862 us; speedup vs baseline: 1.2586x; 1.0005x over previous
//
#include <hip/hip_runtime.h>
#include <cmath>
#include <cstddef>

#define FGK_NN   20000
#define FGK_NE   320000
#define FGK_H    128
#define FGK_P    16
#define FGK_TRI  136
#define FGK_F    152
#define FGK_EPB  32
#define FGK_YP   156          // sY row stride (>=152, 16B-aligned rows, 28 mod 32)

typedef short  s16x8 __attribute__((ext_vector_type(8)));
typedef float  f32x4 __attribute__((ext_vector_type(4)));

__device__ __forceinline__ unsigned short fgk_f2b(float f) {   // RNE f32->bf16 (native cvt)
    __bf16 b = (__bf16)f;
    return __builtin_bit_cast(unsigned short, b);
}
__device__ __forceinline__ float fgk_u2f(unsigned short u) {
    return __uint_as_float(((unsigned int)u) << 16);
}
// bank-conflict swizzles on 16B-unit index (bijective XOR of high bits into group bits)
__device__ __forceinline__ int fgk_sw(int u)  { return u ^ ((u >> 4) & 7); }  // node-kernel pattern
__device__ __forceinline__ int fgk_swL(int u) { return u ^ ((u >> 5) & 7); }  // edge-kernel pattern

__global__ void FishnetGCN_62096637165586_kernel() {}

__global__ void fgkZero(float* acc) {
    int i = blockIdx.x * blockDim.x + threadIdx.x;
    if (i < FGK_NN * (FGK_P + FGK_TRI)) acc[i] = 0.f;
}
__global__ void fgkZeroI(int* p, int n) {
    int i = blockIdx.x * blockDim.x + threadIdx.x;
    if (i < n) p[i] = 0;
}
// ---- dst-sort: histogram -> block scan -> scatter (edge_index constant) ----
__global__ void fgkHist(const int* __restrict__ dst, int* __restrict__ hist) {
    int e = blockIdx.x * blockDim.x + threadIdx.x;
    if (e < FGK_NE) atomicAdd(&hist[dst[e]], 1);
}
__global__ void fgkScan(const int* __restrict__ hist, int* __restrict__ cursor)
{
    __shared__ int sWave[16];
    __shared__ int sRun;
    int t = threadIdx.x;             // 1024
    int lane = t & 63, wv = t >> 6;
    if (t == 0) sRun = 0;
    __syncthreads();
    for (int base = 0; base < FGK_NN; base += 1024) {
        int idx = base + t;
        int v = (idx < FGK_NN) ? hist[idx] : 0;
        int sc = v;
#pragma unroll
        for (int off = 1; off < 64; off <<= 1) {
            int u = __shfl_up(sc, off);
            if (lane >= off) sc += u;
        }
        if (lane == 63) sWave[wv] = sc;
        __syncthreads();
        if (wv == 0 && lane < 16) {
            int w = sWave[lane];
#pragma unroll
            for (int off = 1; off < 16; off <<= 1) {
                int u = __shfl_up(w, off, 16);
                if (lane >= off) w += u;
            }
            sWave[lane] = w;
        }
        __syncthreads();
        int waveOff = (wv == 0) ? 0 : sWave[wv - 1];
        int run = sRun;
        if (idx < FGK_NN) cursor[idx] = run + waveOff + sc - v;   // exclusive
        __syncthreads();
        if (t == 1023) sRun = run + sWave[15];
        __syncthreads();
    }
}
// scatter + emit perm-ordered src/dst arrays (removes double-indirection later)
__global__ void fgkScatterE(const int* __restrict__ dst, const int* __restrict__ src,
                            int* __restrict__ cursor, int* __restrict__ perm,
                            int* __restrict__ srcP, int* __restrict__ dstP) {
    int e = blockIdx.x * blockDim.x + threadIdx.x;
    if (e < FGK_NE) {
        int d = dst[e];
        int pos = atomicAdd(&cursor[d], 1);
        perm[pos] = e;
        srcP[pos] = src[e];
        dstP[pos] = d;
    }
}

// One-time, layer-invariant: eaP[pos] = bf16(eatt[perm[pos]] @ eew + eeb), perm order.
// 256 threads: thread = (pos in 16-group, 8-col group)
__global__ void fgkEncE(const float* __restrict__ eatt,
                        const int* __restrict__ perm,
                        const float* __restrict__ eew,
                        const float* __restrict__ eeb,
                        unsigned short* __restrict__ eaP)
{
    int pos = blockIdx.x * 16 + (threadIdx.x >> 4);
    int b = threadIdx.x & 15;
    int e = perm[pos];
    const float4* ap = (const float4*)(eatt + (size_t)e * 8);
    float4 a0 = ap[0], a1 = ap[1];
    float av[8] = {a0.x, a0.y, a0.z, a0.w, a1.x, a1.y, a1.z, a1.w};
    const float4* bp = (const float4*)(eeb + b * 8);
    float4 b0 = bp[0], b1 = bp[1];
    float acc[8] = {b0.x, b0.y, b0.z, b0.w, b1.x, b1.y, b1.z, b1.w};
#pragma unroll
    for (int kk = 0; kk < 8; ++kk) {
        const float4* wp = (const float4*)(eew + kk * FGK_H + b * 8);
        float4 w0 = wp[0], w1 = wp[1];
        acc[0] += av[kk] * w0.x; acc[1] += av[kk] * w0.y;
        acc[2] += av[kk] * w0.z; acc[3] += av[kk] * w0.w;
        acc[4] += av[kk] * w1.x; acc[5] += av[kk] * w1.y;
        acc[6] += av[kk] * w1.z; acc[7] += av[kk] * w1.w;
    }
    s16x8 r;
#pragma unroll
    for (int jj = 0; jj < 8; ++jj) r[jj] = (short)fgk_f2b(acc[jj]);
    *(s16x8*)&eaP[(size_t)pos * FGK_H + b * 8] = r;
}

// Generic prepack of W[K,N] (row-major) into MFMA B-fragment order, bf16 hi/lo.
__global__ void fgkPrepW(const float* __restrict__ W, int K, int N,
                         unsigned short* __restrict__ hi,
                         unsigned short* __restrict__ lo)
{
    int chunks = K >> 5;
    int b = blockIdx.x;
    int nt = b / chunks, c = b - nt * chunks;
    int lane = threadIdx.x;
    int n = nt * 16 + (lane & 15);
    int g = lane >> 4;
    size_t base = ((size_t)b * 64 + lane) * 8;
#pragma unroll
    for (int j = 0; j < 8; ++j) {
        int k = c * 32 + g * 8 + j;
        float v = (n < N) ? W[(size_t)k * N + n] : 0.f;
        unsigned short hb = fgk_f2b(v);
        unsigned short lb = fgk_f2b(v - fgk_u2f(hb));
        hi[base + j] = hb;
        lo[base + j] = lb;
    }
}

// hin = x @ W[8,128] + b   (f32 + bf16 gather copy)
__global__ void fgkEnc(const float* __restrict__ xin,
                       const float* __restrict__ wenc,
                       const float* __restrict__ benc,
                       float* __restrict__ hin,
                       unsigned short* __restrict__ hinB)
{
    int idx = blockIdx.x * blockDim.x + threadIdx.x;
    if (idx >= FGK_NN * FGK_H) return;
    int n = idx >> 7, j = idx & 127;
    float acc = benc[j];
    const float* xp = xin + (size_t)n * 8;
#pragma unroll
    for (int k = 0; k < 8; k++) acc += xp[k] * wenc[k * FGK_H + j];
    hin[idx] = acc;
    hinB[idx] = fgk_f2b(acc);
}

// edge (sorted by dst), 32 edges/block, 512 threads, ~37 KB LDS (4 blocks/CU):
// msg (A hi only) ; y=MFMA (wave owns nt, both et per B-tile) ; then per-16-edge
// halves: L-build -> Fe=MFMA, sTri overlays that half's dead sY rows.  7 barriers.
__global__ void __launch_bounds__(512, 4)
fgkEdge(const int* __restrict__ srcP,
        const int* __restrict__ dstP,
        const unsigned short* __restrict__ eaP,
        const unsigned short* __restrict__ bHi,
        const unsigned short* __restrict__ bLo,
        const float* __restrict__ a1b,
        const unsigned short* __restrict__ hinB,
        float* __restrict__ snAcc,
        float* __restrict__ fnAcc)
{
    __shared__ float uni[4096];                   // 16 KB: aH (8K); lH/lL (8K+8K)
    __shared__ float sY[FGK_EPB][FGK_YP];         // 19.9 KB: y; halves -> sTri
    __shared__ int sSrc[FGK_EPB], sDst[FGK_EPB];
    __shared__ int sStart[FGK_EPB], sEnd[FGK_EPB], sDstSlot[FGK_EPB];
    __shared__ int sNS;
    unsigned short* aH = (unsigned short*)uni;            // 4096 us (8 KB)
    unsigned short* lH = (unsigned short*)uni;            // 4096 us (per-half)
    unsigned short* lL = (unsigned short*)uni + 4096;     // 4096 us (per-half)
    float* sTriA = (float*)sY;                            // 16*136 over rows 0-15
    float* sTriB = (float*)&sY[16][0];                    // 16*136 over rows 16-31
    int t = threadIdx.x;                          // 512 threads, 8 waves
    int lane = t & 63, wave = t >> 6;
    int e0 = blockIdx.x * FGK_EPB;

    if (wave == 0) {                              // meta load + parallel slot detect
        int sv = 0, dv = 0x7fffffff;
        if (lane < FGK_EPB) {
            sv = srcP[e0 + lane];
            dv = dstP[e0 + lane];
            sSrc[lane] = sv; sDst[lane] = dv;
        }
        int prev = __shfl_up(dv, 1);
        bool isStart = (lane < FGK_EPB) && (lane == 0 || dv != prev);
        unsigned long long mask = __ballot(isStart);
        int ns = __popcll(mask);
        if (isStart) {
            int s = (int)__popcll(mask & ((1ull << lane) - 1ull));
            sStart[s] = lane;
            sDstSlot[s] = dv;
            if (lane) sEnd[s - 1] = lane;
        }
        if (lane == 0) { sNS = ns; sEnd[ns - 1] = FGK_EPB; }
    }
    __syncthreads();                              // bar 1

    // ---- msg = relu(hinB[src] + eaP) + 1e-7 -> bf16 A-frags (hi only) ----
    {
        int el = t >> 4, b = t & 15;
        s16x8 hraw = *(const s16x8*)(hinB + (size_t)sSrc[el] * FGK_H + b * 8);
        s16x8 eraw = *(const s16x8*)(eaP + (size_t)(e0 + el) * FGK_H + b * 8);
        s16x8 hb;
#pragma unroll
        for (int jj = 0; jj < 8; ++jj) {
            float hv = fgk_u2f((unsigned short)hraw[jj]);
            float ev = fgk_u2f((unsigned short)eraw[jj]);
            float m = fmaxf(hv + ev, 0.f) + 1e-7f;
            hb[jj] = (short)fgk_f2b(m);
        }
        int c = b >> 2, g = b & 3;                // k = b*8+jj = 32c+8g+jj
        int idx = fgk_swL(c * 128 + 32 * g + el) * 8;
        *(s16x8*)&aH[idx] = hb;
    }
    __syncthreads();                              // bar 2

    // ---- y = msg @ a1w via MFMA: wave owns nt (waves 0,1 also nt 8,9);
    //      BOTH et against one B-tile stream (halves per-block L2 B traffic) ----
    {
        s16x8 ah[2][4];
#pragma unroll
        for (int et = 0; et < 2; ++et)
#pragma unroll
            for (int c = 0; c < 4; ++c) {
                int idx = fgk_swL(c * 128 + 32 * (lane >> 4) + 16 * et + (lane & 15)) * 8;
                ah[et][c] = *(const s16x8*)&aH[idx];
            }
        int n = lane & 15, qd = lane >> 4;
        int npass = (wave < 2) ? 2 : 1;
        for (int pass = 0; pass < npass; ++pass) {
            int nt = (pass == 0) ? wave : 8 + wave;
            f32x4 acc0 = {0.f, 0.f, 0.f, 0.f};
            f32x4 acc1 = {0.f, 0.f, 0.f, 0.f};
#pragma unroll
            for (int c = 0; c < 4; ++c) {
                size_t bidx = ((size_t)(nt * 4 + c) * 64 + lane) * 8;
                s16x8 bh = *(const s16x8*)(bHi + bidx);
                s16x8 bl = *(const s16x8*)(bLo + bidx);
                acc0 = __builtin_amdgcn_mfma_f32_16x16x32_bf16(ah[0][c], bl, acc0, 0, 0, 0);
                acc0 = __builtin_amdgcn_mfma_f32_16x16x32_bf16(ah[0][c], bh, acc0, 0, 0, 0);
                acc1 = __builtin_amdgcn_mfma_f32_16x16x32_bf16(ah[1][c], bl, acc1, 0, 0, 0);
                acc1 = __builtin_amdgcn_mfma_f32_16x16x32_bf16(ah[1][c], bh, acc1, 0, 0, 0);
            }
            int j = nt * 16 + n;
            if (j < FGK_F) {                       // GUARD: pad cols must not wrap
                float bias = a1b[j];
#pragma unroll
                for (int reg = 0; reg < 4; ++reg) {
                    sY[4 * qd + reg][j] = acc0[reg] + bias;
                    sY[16 + 4 * qd + reg][j] = acc1[reg] + bias;
                }
            }
        }
    }
    __syncthreads();                              // bar 3 (sY done; aH dead)

    // ---- P4: per-slot score reduce (reads all sY) + L-build half A (el 0-15) ----
    {
        {
            int s = t;                        // 512 slots: el16(16) x r(32)
            int el16 = s & 15;
            int r  = s >> 4;                  // 0..31
            int i  = r & 15, h = r >> 4;
            int pstart = 16 * i + 8 * h;
            float v[8];
            if (pstart < 120) {
                const float4* rp = (const float4*)&sY[el16][32 + pstart];
                float4 v0 = rp[0], v1 = rp[1];
                v[0] = v0.x; v[1] = v0.y; v[2] = v0.z; v[3] = v0.w;
                v[4] = v1.x; v[5] = v1.y; v[6] = v1.z; v[7] = v1.w;
            } else {
                const float4* rp = (const float4*)&sY[el16][264 - pstart];
                float4 v0 = rp[0], v1 = rp[1];
                v[0] = v1.w; v[1] = v1.z; v[2] = v1.y; v[3] = v1.x;
                v[4] = v0.w; v[5] = v0.z; v[6] = v0.y; v[7] = v0.x;
            }
            if (h == (i >> 3)) {              // diag elem at i&7
                int jd = i & 7;
                float d0 = v[jd];
                v[jd] = fmaxf(d0, 0.f) +
                        0.69314718f * log2f(1.f + exp2f(-1.44269504f * fabsf(d0)));
            }
            s16x8 hb, lb;
#pragma unroll
            for (int jj = 0; jj < 8; ++jj) {
                unsigned short hbv = fgk_f2b(v[jj]);
                hb[jj] = (short)hbv;
                lb[jj] = (short)fgk_f2b(v[jj] - fgk_u2f(hbv));
            }
            int idx = fgk_swL(el16 * 32 + i + 16 * h) * 8;
            *(s16x8*)&lH[idx] = hb;
            *(s16x8*)&lL[idx] = lb;
        }
        int el = t >> 4, d = t & 15;          // score reduce (sY all rows)
        if (el < sNS) {
            float sum = 0.f;
            for (int e2 = sStart[el]; e2 < sEnd[el]; ++e2) sum += sY[e2][d];
            atomicAdd(&snAcc[(size_t)sDstSlot[el] * FGK_P + d], sum);
        }
    }
    __syncthreads();                              // bar 4

    // ---- P5: Fe half A -> sTriA (overlays sY rows 0-15, now dead) ----
#pragma unroll
    for (int i2 = 0; i2 < 2; ++i2) {
        int el16 = wave * 2 + i2;             // 0..15
        s16x8 fh = {0, 0, 0, 0, 0, 0, 0, 0};
        s16x8 fl = {0, 0, 0, 0, 0, 0, 0, 0};
        if (lane < 32) {
            int idx = fgk_swL(el16 * 32 + lane) * 8;
            fh = *(const s16x8*)&lH[idx];
            fl = *(const s16x8*)&lL[idx];
        }
        f32x4 acc = {0.f, 0.f, 0.f, 0.f};
        acc = __builtin_amdgcn_mfma_f32_16x16x32_bf16(fh, fh, acc, 0, 0, 0);
        acc = __builtin_amdgcn_mfma_f32_16x16x32_bf16(fh, fl, acc, 0, 0, 0);
        acc = __builtin_amdgcn_mfma_f32_16x16x32_bf16(fl, fh, acc, 0, 0, 0);
        int j = lane & 15, qd = lane >> 4;
#pragma unroll
        for (int reg = 0; reg < 4; ++reg) {
            int ii = 4 * qd + reg;
            if (ii >= j) sTriA[el16 * FGK_TRI + ii * (ii + 1) / 2 + j] = acc[reg];
        }
    }
    __syncthreads();                              // bar 5 (lH/lL A consumed)

    // ---- P6: L-build half B (el 16-31; sY rows 16-31 still intact) ----
    {
        int s = t;
        int el16 = s & 15;
        int r  = s >> 4;
        int i  = r & 15, h = r >> 4;
        int pstart = 16 * i + 8 * h;
        float v[8];
        if (pstart < 120) {
            const float4* rp = (const float4*)&sY[16 + el16][32 + pstart];
            float4 v0 = rp[0], v1 = rp[1];
            v[0] = v0.x; v[1] = v0.y; v[2] = v0.z; v[3] = v0.w;
            v[4] = v1.x; v[5] = v1.y; v[6] = v1.z; v[7] = v1.w;
        } else {
            const float4* rp = (const float4*)&sY[16 + el16][264 - pstart];
            float4 v0 = rp[0], v1 = rp[1];
            v[0] = v1.w; v[1] = v1.z; v[2] = v1.y; v[3] = v1.x;
            v[4] = v0.w; v[5] = v0.z; v[6] = v0.y; v[7] = v0.x;
        }
        if (h == (i >> 3)) {
            int jd = i & 7;
            float d0 = v[jd];
            v[jd] = fmaxf(d0, 0.f) +
                    0.69314718f * log2f(1.f + exp2f(-1.44269504f * fabsf(d0)));
        }
        s16x8 hb, lb;
#pragma unroll
        for (int jj = 0; jj < 8; ++jj) {
            unsigned short hbv = fgk_f2b(v[jj]);
            hb[jj] = (short)hbv;
            lb[jj] = (short)fgk_f2b(v[jj] - fgk_u2f(hbv));
        }
        int idx = fgk_swL(el16 * 32 + i + 16 * h) * 8;
        *(s16x8*)&lH[idx] = hb;
        *(s16x8*)&lL[idx] = lb;
    }
    __syncthreads();                              // bar 6

    // ---- P7: Fe half B -> sTriB (overlays sY rows 16-31, now dead) ----
#pragma unroll
    for (int i2 = 0; i2 < 2; ++i2) {
        int el16 = wave * 2 + i2;
        s16x8 fh = {0, 0, 0, 0, 0, 0, 0, 0};
        s16x8 fl = {0, 0, 0, 0, 0, 0, 0, 0};
        if (lane < 32) {
            int idx = fgk_swL(el16 * 32 + lane) * 8;
            fh = *(const s16x8*)&lH[idx];
            fl = *(const s16x8*)&lL[idx];
        }
        f32x4 acc = {0.f, 0.f, 0.f, 0.f};
        acc = __builtin_amdgcn_mfma_f32_16x16x32_bf16(fh, fh, acc, 0, 0, 0);
        acc = __builtin_amdgcn_mfma_f32_16x16x32_bf16(fh, fl, acc, 0, 0, 0);
        acc = __builtin_amdgcn_mfma_f32_16x16x32_bf16(fl, fh, acc, 0, 0, 0);
        int j = lane & 15, qd = lane >> 4;
#pragma unroll
        for (int reg = 0; reg < 4; ++reg) {
            int ii = 4 * qd + reg;
            if (ii >= j) sTriB[el16 * FGK_TRI + ii * (ii + 1) / 2 + j] = acc[reg];
        }
    }
    __syncthreads();                              // bar 7

    // ---- per-slot tri reduction -> coalesced atomics ----
    {
        int nS = sNS;
        for (int o = t; o < nS * FGK_TRI; o += 512) {
            int s = o / FGK_TRI, p = o - s * FGK_TRI;
            float sum = 0.f;
            for (int el = sStart[s]; el < sEnd[s]; ++el) {
                const float* tb = (el < 16) ? sTriA : sTriB;
                sum += tb[(el & 15) * FGK_TRI + p];
            }
            atomicAdd(&fnAcc[(size_t)sDstSlot[s] * FGK_TRI + p], sum);
        }
    }
}

// one thread per node: fully-unrolled register Cholesky solve of (F_n+I) x = s_n
// 64-thread blocks: 313 workgroups; optionally zeroes its own snA/fnA rows
// after loading them (prepares the accumulators for the next layer in-place)
#define TA(i, j) a[(i) * ((i) + 1) / 2 + (j)]
__global__ void __launch_bounds__(64)
fgkSolve(float* __restrict__ snAcc,
         float* __restrict__ fnAcc,
         float* __restrict__ mleOut, int doZero)
{
    int n = blockIdx.x * blockDim.x + threadIdx.x;
    if (n >= FGK_NN) return;
    float a[FGK_TRI];
    float4* src = (float4*)(fnAcc + (size_t)n * FGK_TRI);
#pragma unroll
    for (int p = 0; p < FGK_TRI / 4; ++p) {
        float4 v = src[p];
        a[p * 4] = v.x; a[p * 4 + 1] = v.y; a[p * 4 + 2] = v.z; a[p * 4 + 3] = v.w;
    }
    float4* sp4 = (float4*)(snAcc + (size_t)n * FGK_P);
    float sv[16];
#pragma unroll
    for (int p = 0; p < 4; ++p) {
        float4 v = sp4[p];
        sv[p * 4] = v.x; sv[p * 4 + 1] = v.y; sv[p * 4 + 2] = v.z; sv[p * 4 + 3] = v.w;
    }
    if (doZero) {                       // own-row zero (loads above must complete
        float4 z = make_float4(0.f, 0.f, 0.f, 0.f);   // first: same-address ordering)
#pragma unroll
        for (int p = 0; p < FGK_TRI / 4; ++p) src[p] = z;
#pragma unroll
        for (int p = 0; p < 4; ++p) sp4[p] = z;
    }
#pragma unroll
    for (int i = 0; i < 16; ++i) TA(i, i) += 1.f;
#pragma unroll
    for (int k = 0; k < 16; ++k) {
        float d = sqrtf(TA(k, k));
        float inv = 1.f / d;
        TA(k, k) = d;
#pragma unroll
        for (int i = k + 1; i < 16; ++i) TA(i, k) *= inv;
#pragma unroll
        for (int j = k + 1; j < 16; ++j) {
            float ajk = TA(j, k);
#pragma unroll
            for (int i = j; i < 16; ++i) TA(i, j) -= TA(i, k) * ajk;
        }
    }
    float y[16], x[16];
#pragma unroll
    for (int i = 0; i < 16; ++i) {
        float acc = sv[i];
#pragma unroll
        for (int k = 0; k < 16; ++k) if (k < i) acc -= TA(i, k) * y[k];
        y[i] = acc / TA(i, i);
    }
#pragma unroll
    for (int i = 15; i >= 0; --i) {
        float acc = y[i];
#pragma unroll
        for (int k = 0; k < 16; ++k) if (k > i) acc -= TA(k, i) * x[k];
        x[i] = acc / TA(i, i);
    }
    float4* dst = (float4*)(mleOut + (size_t)n * FGK_P);
#pragma unroll
    for (int p = 0; p < 4; ++p) dst[p] = make_float4(x[p * 4], x[p * 4 + 1], x[p * 4 + 2], x[p * 4 + 3]);
}
#undef TA

// node (16 nodes/block): a2+res -> m1 MFMA -> LN -> m2 MFMA -> hout
// + fused next-layer relu(LN(hout)) -> hinNext (doNext)
// + fused FINAL: out = relu(LN(hout,g0,b0)) @ lin_w + lin_b (doFinal)
// HI-ONLY A fragments; lw dual-precision (streamed from global)
__global__ void __launch_bounds__(256)
fgkNode(const float* __restrict__ hin,
        const float* __restrict__ mleIn,
        const float* __restrict__ a2w, const float* __restrict__ a2b,
        const unsigned short* __restrict__ m1H,
        const float* __restrict__ m1b,
        const float* __restrict__ gamma, const float* __restrict__ beta,
        const unsigned short* __restrict__ m2H,
        const float* __restrict__ m2b,
        float* __restrict__ hout, int addres,
        float* __restrict__ hinNext, unsigned short* __restrict__ hinNextB,
        const float* __restrict__ gN, const float* __restrict__ bN, int doNext,
        const unsigned short* __restrict__ lwH, const unsigned short* __restrict__ lwL,
        const float* __restrict__ linb, float* __restrict__ outp, int doFinal)
{
    __shared__ char uniN[8192];                // ovH (4 KB) then t2H (8 KB)
    __shared__ float sT[16][260];
    __shared__ float stats[16][2];
    unsigned short* ovH = (unsigned short*)uniN;   // 2048 us
    unsigned short* t2H = (unsigned short*)uniN;   // 4096 us (after reuse)
    int t = threadIdx.x, lane = t & 63, wave = t >> 6;
    int n0 = blockIdx.x * 16;

    // ---- a2 matvec + residual -> bf16 hi frags (one pass, vectorized) ----
    {
        int node = t >> 4, cg = t & 15;            // 8 cols per thread
        const float4* m4 = (const float4*)(mleIn + (size_t)(n0 + node) * FGK_P);
        float4 q0 = m4[0], q1 = m4[1], q2 = m4[2], q3 = m4[3];
        float mv[16] = {q0.x, q0.y, q0.z, q0.w, q1.x, q1.y, q1.z, q1.w,
                        q2.x, q2.y, q2.z, q2.w, q3.x, q3.y, q3.z, q3.w};
        const float4* bp = (const float4*)(a2b + cg * 8);
        float4 b0 = bp[0], b1 = bp[1];
        const float4* hp = (const float4*)(hin + (size_t)(n0 + node) * FGK_H + cg * 8);
        float4 h0 = hp[0], h1 = hp[1];
        float acc[8] = {b0.x + h0.x, b0.y + h0.y, b0.z + h0.z, b0.w + h0.w,
                        b1.x + h1.x, b1.y + h1.y, b1.z + h1.z, b1.w + h1.w};
#pragma unroll
        for (int k = 0; k < 16; ++k) {
            const float4* wp = (const float4*)(a2w + k * FGK_H + cg * 8);
            float4 w0 = wp[0], w1 = wp[1];
            acc[0] += mv[k] * w0.x; acc[1] += mv[k] * w0.y;
            acc[2] += mv[k] * w0.z; acc[3] += mv[k] * w0.w;
            acc[4] += mv[k] * w1.x; acc[5] += mv[k] * w1.y;
            acc[6] += mv[k] * w1.z; acc[7] += mv[k] * w1.w;
        }
        s16x8 hb;
#pragma unroll
        for (int jj = 0; jj < 8; ++jj) hb[jj] = (short)fgk_f2b(acc[jj]);
        int idx = fgk_sw(cg * 16 + node) * 8;      // u = c*64+16g+node = 16*cg+node
        *(s16x8*)&ovH[idx] = hb;
    }
    __syncthreads();

    // ---- m1 = A-hi @ m1H (single MFMA per c) ----
    {
        s16x8 ah[4];
#pragma unroll
        for (int c = 0; c < 4; ++c) {
            int idx = fgk_sw(c * 64 + lane) * 8;
            ah[c] = *(const s16x8*)&ovH[idx];
        }
        int n = lane & 15, qd = lane >> 4;
#pragma unroll
        for (int i4 = 0; i4 < 4; ++i4) {
            int nt = wave + i4 * 4;
            f32x4 acc = {0.f, 0.f, 0.f, 0.f};
#pragma unroll
            for (int c = 0; c < 4; ++c) {
                size_t bidx = ((size_t)(nt * 4 + c) * 64 + lane) * 8;
                s16x8 bh = *(const s16x8*)(m1H + bidx);
                acc = __builtin_amdgcn_mfma_f32_16x16x32_bf16(ah[c], bh, acc, 0, 0, 0);
            }
            int j = nt * 16 + n;
            float bias = m1b[j];
#pragma unroll
            for (int reg = 0; reg < 4; ++reg)
                sT[4 * qd + reg][j] = acc[reg] + bias;
        }
    }
    __syncthreads();

    {
        int node = t >> 4, seg = t & 15;
        const float* rowp = &sT[node][seg * 16];
        float s1 = 0.f, s2 = 0.f;
#pragma unroll
        for (int k = 0; k < 16; ++k) { float v = rowp[k]; s1 += v; s2 += v * v; }
#pragma unroll
        for (int off = 8; off; off >>= 1) {
            s1 += __shfl_down(s1, off, 16);
            s2 += __shfl_down(s2, off, 16);
        }
        if (seg == 0) {
            float mu = s1 * (1.f / 256.f);
            float var = s2 * (1.f / 256.f) - mu * mu;
            stats[node][0] = mu;
            stats[node][1] = rsqrtf(var + 1e-5f);
        }
    }
    __syncthreads();

    // ---- LN + relu -> bf16 hi frags (vectorized, swizzled b128 stores) ----
    {
        int node = t >> 4;
        float mu = stats[node][0], rstd = stats[node][1];
#pragma unroll
        for (int h = 0; h < 2; ++h) {
            int cg = (t & 15) + 16 * h;            // 0..31, 8 cols each
            const float4* rp = (const float4*)&sT[node][cg * 8];
            float4 v0 = rp[0], v1 = rp[1];
            const float4* gp = (const float4*)(gamma + cg * 8);
            float4 g0 = gp[0], g1 = gp[1];
            const float4* bb = (const float4*)(beta + cg * 8);
            float4 e0 = bb[0], e1 = bb[1];
            float vv[8] = {v0.x, v0.y, v0.z, v0.w, v1.x, v1.y, v1.z, v1.w};
            float gg[8] = {g0.x, g0.y, g0.z, g0.w, g1.x, g1.y, g1.z, g1.w};
            float ee[8] = {e0.x, e0.y, e0.z, e0.w, e1.x, e1.y, e1.z, e1.w};
            s16x8 hb;
#pragma unroll
            for (int jj = 0; jj < 8; ++jj) {
                float tv = fmaxf((vv[jj] - mu) * rstd * gg[jj] + ee[jj], 0.f);
                hb[jj] = (short)fgk_f2b(tv);
            }
            int idx = fgk_sw(cg * 16 + node) * 8;
            *(s16x8*)&t2H[idx] = hb;
        }
    }
    __syncthreads();

    // ---- m2 = A-hi @ m2H (single MFMA per c) ----
    {
        s16x8 ah[8];
#pragma unroll
        for (int c = 0; c < 8; ++c) {
            int idx = fgk_sw(c * 64 + lane) * 8;
            ah[c] = *(const s16x8*)&t2H[idx];
        }
        int n = lane & 15, qd = lane >> 4;
#pragma unroll
        for (int i2 = 0; i2 < 2; ++i2) {
            int nt = wave * 2 + i2;
            f32x4 acc = {0.f, 0.f, 0.f, 0.f};
#pragma unroll
            for (int c = 0; c < 8; ++c) {
                size_t bidx = ((size_t)(nt * 8 + c) * 64 + lane) * 8;
                s16x8 bh = *(const s16x8*)(m2H + bidx);
                acc = __builtin_amdgcn_mfma_f32_16x16x32_bf16(ah[c], bh, acc, 0, 0, 0);
            }
            int j = nt * 16 + n;
            float bias = m2b[j];
#pragma unroll
            for (int reg = 0; reg < 4; ++reg) {
                int node = 4 * qd + reg;
                size_t idx = (size_t)(n0 + node) * FGK_H + j;
                float val = acc[reg] + bias;
                float nv = addres ? (hout[idx] + val) : val;
                hout[idx] = nv;
                sT[node][j] = nv;          // park for fused next-layer LN / final
            }
        }
    }
    if (doNext) {                          // hinNext = relu(LN(hout, gN, bN))
        __syncthreads();
        int node = t >> 4, seg = t & 15;
        const float* rowp = &sT[node][seg * 8];
        float s1 = 0.f, s2 = 0.f;
#pragma unroll
        for (int k = 0; k < 8; ++k) { float v = rowp[k]; s1 += v; s2 += v * v; }
#pragma unroll
        for (int off = 8; off; off >>= 1) {
            s1 += __shfl_down(s1, off, 16);
            s2 += __shfl_down(s2, off, 16);
        }
        if (seg == 0) {
            float mu = s1 * (1.f / 128.f);
            float var = s2 * (1.f / 128.f) - mu * mu;
            stats[node][0] = mu;
            stats[node][1] = rsqrtf(var + 1e-5f);
        }
        __syncthreads();
        float mu = stats[node][0], rstd = stats[node][1];
#pragma unroll
        for (int kk = 0; kk < 8; ++kk) {
            int k = seg * 8 + kk;
            float v = sT[node][k];
            float nv = fmaxf((v - mu) * rstd * gN[k] + bN[k], 0.f);
            size_t oidx = (size_t)(n0 + node) * FGK_H + k;
            hinNext[oidx] = nv;
            hinNextB[oidx] = fgk_f2b(nv);
        }
    } else if (doFinal) {                  // out = relu(LN(hout,g0,b0)) @ lw + lb
        __syncthreads();
        {
            int node = t >> 4, seg = t & 15;
            const float* rowp = &sT[node][seg * 8];
            float s1 = 0.f, s2 = 0.f;
#pragma unroll
            for (int k = 0; k < 8; ++k) { float v = rowp[k]; s1 += v; s2 += v * v; }
#pragma unroll
            for (int off = 8; off; off >>= 1) {
                s1 += __shfl_down(s1, off, 16);
                s2 += __shfl_down(s2, off, 16);
            }
            if (seg == 0) {
                float mu = s1 * (1.f / 128.f);
                float var = s2 * (1.f / 128.f) - mu * mu;
                stats[node][0] = mu;
                stats[node][1] = rsqrtf(var + 1e-5f);
            }
        }
        __syncthreads();
        {   // relu(LN) -> A-hi frags in t2H (2048 us used)
            int node = t >> 4, cg = t & 15;
            float mu = stats[node][0], rstd = stats[node][1];
            const float* rowp = &sT[node][cg * 8];
            s16x8 hb;
#pragma unroll
            for (int jj = 0; jj < 8; ++jj) {
                int k = cg * 8 + jj;
                float tv = fmaxf((rowp[jj] - mu) * rstd * gN[k] + bN[k], 0.f);
                hb[jj] = (short)fgk_f2b(tv);
            }
            int idx = fgk_sw(cg * 16 + node) * 8;
            *(s16x8*)&t2H[idx] = hb;
        }
        __syncthreads();
        {   // final matvec via MFMA: A hi-only, lw dual-precision (7 nt tiles)
            s16x8 ah[4];
#pragma unroll
            for (int c = 0; c < 4; ++c) {
                int idx = fgk_sw(c * 64 + lane) * 8;
                ah[c] = *(const s16x8*)&t2H[idx];
            }
            int n = lane & 15, qd = lane >> 4;
#pragma unroll
            for (int p2 = 0; p2 < 2; ++p2) {
                int nt = wave + p2 * 4;
                if (nt < 7) {
                    f32x4 acc = {0.f, 0.f, 0.f, 0.f};
#pragma unroll
                    for (int c = 0; c < 4; ++c) {
                        size_t bidx = ((size_t)(nt * 4 + c) * 64 + lane) * 8;
                        s16x8 bh = *(const s16x8*)(lwH + bidx);
                        s16x8 bl = *(const s16x8*)(lwL + bidx);
                        acc = __builtin_amdgcn_mfma_f32_16x16x32_bf16(ah[c], bl, acc, 0, 0, 0);
                        acc = __builtin_amdgcn_mfma_f32_16x16x32_bf16(ah[c], bh, acc, 0, 0, 0);
                    }
                    int j = nt * 16 + n;
                    float bias = linb[j];
#pragma unroll
                    for (int reg = 0; reg < 4; ++reg) {
                        int node = 4 * qd + reg;
                        outp[(size_t)(n0 + node) * 112 + j] = acc[reg] + bias;
                    }
                }
            }
        }
    }
}

extern "C" void kernel_launch(void* const* d_in, const int* in_sizes, int n_in,
                              void* d_out, int out_size, void* d_ws, size_t ws_size,
                              hipStream_t stream)
{
    const float* xin  = (const float*)d_in[0];
    const float* eatt = (const float*)d_in[1];
    const int*   eidx = (const int*)d_in[2];
    const float* nEw  = (const float*)d_in[3];
    const float* nEb  = (const float*)d_in[4];
    const float* eEw  = (const float*)d_in[5];
    const float* eEb  = (const float*)d_in[6];
    const float* a1w  = (const float*)d_in[7];
    const float* a1b  = (const float*)d_in[8];
    const float* a2w  = (const float*)d_in[9];
    const float* a2b  = (const float*)d_in[10];
    const float* m1w  = (const float*)d_in[11];
    const float* m1b  = (const float*)d_in[12];
    const float* lng  = (const float*)d_in[13];
    const float* lnb  = (const float*)d_in[14];
    const float* m2w  = (const float*)d_in[15];
    const float* m2b  = (const float*)d_in[16];
    const float* ng   = (const float*)d_in[17];
    const float* nb   = (const float*)d_in[18];
    const float* lw   = (const float*)d_in[19];
    const float* lb   = (const float*)d_in[20];
    float* outp = (float*)d_out;
    const int* srcIdx = eidx;
    const int* dstIdx = eidx + FGK_NE;

    float* ws   = (float*)d_ws;
    float* hAcc = ws;                                    // NN*128
    float* hin  = hAcc + (size_t)FGK_NN * FGK_H;         // NN*128
    float* snA  = hin  + (size_t)FGK_NN * FGK_H;         // NN*16
    float* fnA  = snA  + (size_t)FGK_NN * FGK_P;         // NN*136
    float* mle  = fnA  + (size_t)FGK_NN * FGK_TRI;       // NN*16
    unsigned short* wsU = (unsigned short*)(mle + (size_t)FGK_NN * FGK_P);
    const int A1F = 40 * 512, M1F = 64 * 512, M2F = 64 * 512, LWF = 28 * 512;
    unsigned short* a1Hi = wsU;
    unsigned short* a1Lo = a1Hi + 3 * A1F;
    unsigned short* m1Hi = a1Lo + 3 * A1F;
    unsigned short* m1Lo = m1Hi + 3 * M1F;
    unsigned short* m2Hi = m1Lo + 3 * M1F;
    unsigned short* m2Lo = m2Hi + 3 * M2F;
    unsigned short* lwHi = m2Lo + 3 * M2F;               // 28*512
    unsigned short* lwLo = lwHi + LWF;                   // 28*512
    int* cursor = (int*)(lwLo + LWF);                    // NN ints
    int* perm   = cursor + FGK_NN;                       // NE ints
    int* srcP   = perm + FGK_NE;                         // NE ints (perm-ordered src)
    int* dstP   = srcP + FGK_NE;                         // NE ints (perm-ordered dst)
    unsigned short* hinB = (unsigned short*)(dstP + FGK_NE);   // NN*128 bf16
    unsigned short* eaP  = hinB + (size_t)FGK_NN * FGK_H;      // NE*128 bf16 (82 MB)

    // dst-sorted edge permutation (edge_index constant; rebuilt every launch)
    fgkZeroI<<<(FGK_NN + 255) / 256, 256, 0, stream>>>(cursor, FGK_NN);
    fgkHist<<<(FGK_NE + 255) / 256, 256, 0, stream>>>(dstIdx, cursor);
    fgkScan<<<1, 1024, 0, stream>>>(cursor, cursor);     // in-place exclusive scan
    fgkScatterE<<<(FGK_NE + 255) / 256, 256, 0, stream>>>(dstIdx, srcIdx, cursor,
                                                          perm, srcP, dstP);
    // one-time layer-invariant edge encoding, perm-ordered bf16
    fgkEncE<<<FGK_NE / 16, 256, 0, stream>>>(eatt, perm, eEw, eEb, eaP);

    for (int l = 0; l < 3; l++) {
        fgkPrepW<<<40, 64, 0, stream>>>(a1w + (size_t)l * FGK_H * FGK_F, 128, 152,
                                        a1Hi + l * A1F, a1Lo + l * A1F);
        fgkPrepW<<<64, 64, 0, stream>>>(m1w + (size_t)l * FGK_H * 256, 128, 256,
                                        m1Hi + l * M1F, m1Lo + l * M1F);
        fgkPrepW<<<64, 64, 0, stream>>>(m2w + (size_t)l * 256 * FGK_H, 256, 128,
                                        m2Hi + l * M2F, m2Lo + l * M2F);
    }
    fgkPrepW<<<28, 64, 0, stream>>>(lw, 128, 112, lwHi, lwLo);
    fgkEnc<<<(FGK_NN * FGK_H + 255) / 256, 256, 0, stream>>>(xin, nEw, nEb, hin, hinB);
    // zero snA+fnA once (contiguous NN*152 floats); fgkSolve re-zeroes in-place
    fgkZero<<<(FGK_NN * (FGK_P + FGK_TRI) + 255) / 256, 256, 0, stream>>>(snA);
    for (int l = 0; l < 3; l++) {
        fgkEdge<<<FGK_NE / FGK_EPB, 512, 0, stream>>>(srcP, dstP, eaP,
            a1Hi + l * A1F, a1Lo + l * A1F, a1b + (size_t)l * FGK_F, hinB, snA, fnA);
        fgkSolve<<<(FGK_NN + 63) / 64, 64, 0, stream>>>(snA, fnA, mle, l < 2 ? 1 : 0);
        int isLast = (l == 2);
        fgkNode<<<FGK_NN / 16, 256, 0, stream>>>(hin, mle,
            a2w + (size_t)l * FGK_P * FGK_H, a2b + (size_t)l * FGK_H,
            m1Hi + l * M1F, m1b + (size_t)l * 256,
            lng + (size_t)l * 256, lnb + (size_t)l * 256,
            m2Hi + l * M2F, m2b + (size_t)l * FGK_H,
            hAcc, l > 0 ? 1 : 0,
            hin, hinB,
            isLast ? ng : (ng + (l + 1) * FGK_H),
            isLast ? nb : (nb + (l + 1) * FGK_H),
            isLast ? 0 : 1,
            lwHi, lwLo, lb, outp, isLast ? 1 : 0);
    }
}